// Round 1
// baseline (2277.559 us; speedup 1.0000x reference)
//
#include <hip/hip_runtime.h>

// Problem constants (fixed by the reference setup_inputs)
constexpr int Nn = 100000;   // nodes
constexpr int Ee = 600000;   // edges
constexpr int Ff = 64;       // input feature dim
constexpr int Dd = 128;      // hidden dim
constexpr int Ll = 3;        // DAG layers
constexpr int Gg = 256;      // graphs
constexpr int Tt = 10;       // outputs per graph
constexpr float BN_EPS = 1e-5f;

// ---------------------------------------------------------------------------
// GEMM: C[N][128] = A[N][K] @ W[K][128] + bias, fp32 vector ALU.
// Block = 256 threads = 16x16; tile 64 rows x 128 cols; thread microtile 4x8.
// Safe to run in-place (C == A) when K == 128: each block only reads its own
// 64 rows (fully consumed into LDS before the epilogue stores).
// ---------------------------------------------------------------------------
template <int K>
__global__ __launch_bounds__(256) void gemm_bias(const float* __restrict__ A,
                                                 const float* __restrict__ W,
                                                 const float* __restrict__ bias,
                                                 float* __restrict__ C,
                                                 int nrows) {
  __shared__ float As[64][36];    // [row][k-chunk], padded 32->36
  __shared__ float Ws[32][128];   // [k][col]
  const int tid = threadIdx.x;
  const int tx = tid & 15;        // col group: 8 cols each
  const int ty = tid >> 4;        // row group: 4 rows each
  const int rowBase = blockIdx.x * 64;

  float acc[4][8];
#pragma unroll
  for (int i = 0; i < 4; ++i)
#pragma unroll
    for (int j = 0; j < 8; ++j) acc[i][j] = 0.f;

  for (int k0 = 0; k0 < K; k0 += 32) {
    // Load A chunk: 64 rows x 32 k. Thread t: row = t>>2, kk = (t&3)*8.
    {
      const int r = tid >> 2;
      const int kk = (tid & 3) * 8;
      const int grow = rowBase + r;
      float4 v0 = {0.f, 0.f, 0.f, 0.f}, v1 = {0.f, 0.f, 0.f, 0.f};
      if (grow < nrows) {
        const float* p = A + (size_t)grow * K + (k0 + kk);
        v0 = *(const float4*)p;
        v1 = *(const float4*)(p + 4);
      }
      *(float4*)&As[r][kk] = v0;
      *(float4*)&As[r][kk + 4] = v1;
    }
    // Load W chunk: rows k0..k0+31 are 4096 contiguous floats.
    {
      const float4* Wv = (const float4*)(W + (size_t)k0 * 128);
      float4* Sv = (float4*)&Ws[0][0];
#pragma unroll
      for (int j = 0; j < 4; ++j) Sv[tid + j * 256] = Wv[tid + j * 256];
    }
    __syncthreads();
#pragma unroll
    for (int kk = 0; kk < 32; ++kk) {
      float a[4];
#pragma unroll
      for (int i = 0; i < 4; ++i) a[i] = As[ty * 4 + i][kk];
      const float4 b0 = *(const float4*)&Ws[kk][tx * 8];
      const float4 b1 = *(const float4*)&Ws[kk][tx * 8 + 4];
      const float b[8] = {b0.x, b0.y, b0.z, b0.w, b1.x, b1.y, b1.z, b1.w};
#pragma unroll
      for (int i = 0; i < 4; ++i)
#pragma unroll
        for (int j = 0; j < 8; ++j) acc[i][j] = fmaf(a[i], b[j], acc[i][j]);
    }
    __syncthreads();
  }

  // Epilogue: add bias, store.
  const float4 bb0 = *(const float4*)&bias[tx * 8];
  const float4 bb1 = *(const float4*)&bias[tx * 8 + 4];
#pragma unroll
  for (int i = 0; i < 4; ++i) {
    const int grow = rowBase + ty * 4 + i;
    if (grow < nrows) {
      float* p = C + (size_t)grow * 128 + tx * 8;
      float4 o0, o1;
      o0.x = acc[i][0] + bb0.x; o0.y = acc[i][1] + bb0.y;
      o0.z = acc[i][2] + bb0.z; o0.w = acc[i][3] + bb0.w;
      o1.x = acc[i][4] + bb1.x; o1.y = acc[i][5] + bb1.y;
      o1.z = acc[i][6] + bb1.z; o1.w = acc[i][7] + bb1.w;
      *(float4*)p = o0;
      *(float4*)(p + 4) = o1;
    }
  }
}

// ---------------------------------------------------------------------------
// Column-wise sum / sumsq reduction (optionally masked by tcnt>0).
// stats[0..128) = sum, stats[128..256) = sumsq. Block handles 128 rows.
// ---------------------------------------------------------------------------
__global__ __launch_bounds__(256) void stats_kernel(const float* __restrict__ y,
                                                    const float* __restrict__ tcnt,
                                                    float* __restrict__ stats,
                                                    int nrows) {
  const int tid = threadIdx.x;
  const int col = tid & 127;
  const int h = tid >> 7;
  const int r0 = blockIdx.x * 128;
  const int rEnd = min(r0 + 128, nrows);
  float s = 0.f, q = 0.f;
  for (int r = r0 + h; r < rEnd; r += 2) {
    float m = 1.f;
    if (tcnt) m = (tcnt[r] > 0.f) ? 1.f : 0.f;
    const float v = y[(size_t)r * 128 + col] * m;
    s += v;
    q += v * v;
  }
  __shared__ float ls[256], lq[256];
  ls[tid] = s;
  lq[tid] = q;
  __syncthreads();
  if (h == 0) {
    s += ls[tid + 128];
    q += lq[tid + 128];
    atomicAdd(&stats[col], s);
    atomicAdd(&stats[128 + col], q);
  }
}

// Count of target nodes (tcnt>0) -> stats[256]
__global__ __launch_bounds__(256) void count_kernel(const float* __restrict__ tcnt,
                                                    float* __restrict__ stats,
                                                    int nrows) {
  const int i = blockIdx.x * 256 + threadIdx.x;
  float v = (i < nrows && tcnt[i] > 0.f) ? 1.f : 0.f;
  __shared__ float ls[256];
  ls[threadIdx.x] = v;
  __syncthreads();
  for (int s = 128; s > 0; s >>= 1) {
    if (threadIdx.x < s) ls[threadIdx.x] += ls[threadIdx.x + s];
    __syncthreads();
  }
  if (threadIdx.x == 0 && ls[0] != 0.f) atomicAdd(&stats[256], ls[0]);
}

// Per-column BN scale/shift: ss[0..128)=scale, ss[128..256)=shift.
// cntFixed > 0 -> use it; else use max(stats[256], 1).
__global__ void scaleshift_kernel(const float* __restrict__ stats,
                                  const float* __restrict__ g,
                                  const float* __restrict__ be,
                                  float* __restrict__ ss, float cntFixed) {
  const int c = threadIdx.x;  // 128 threads
  const float cnt = (cntFixed > 0.f) ? cntFixed : fmaxf(stats[256], 1.f);
  const float m = stats[c] / cnt;
  const float v = stats[128 + c] / cnt - m * m;
  const float sc = g[c] * rsqrtf(v + BN_EPS);
  ss[c] = sc;
  ss[128 + c] = be[c] - m * sc;
}

// out = relu(in * scale + shift), elementwise over N*128 (float4-ized)
__global__ __launch_bounds__(256) void normrelu_kernel(const float* __restrict__ in,
                                                       const float* __restrict__ ss,
                                                       float* __restrict__ out) {
  const int i4 = blockIdx.x * 256 + threadIdx.x;  // exact grid
  const int c4 = (i4 & 31) * 4;
  float4 v = ((const float4*)in)[i4];
  const float4 sc = *(const float4*)&ss[c4];
  const float4 sh = *(const float4*)&ss[128 + c4];
  float4 o;
  o.x = fmaxf(fmaf(v.x, sc.x, sh.x), 0.f);
  o.y = fmaxf(fmaf(v.y, sc.y, sh.y), 0.f);
  o.z = fmaxf(fmaf(v.z, sc.z, sh.z), 0.f);
  o.w = fmaxf(fmaf(v.w, sc.w, sh.w), 0.f);
  ((float4*)out)[i4] = o;
}

// x += (tcnt>0) * relu(in*scale+shift)
__global__ __launch_bounds__(256) void normrelu_acc_kernel(
    const float* __restrict__ in, const float* __restrict__ ss,
    const float* __restrict__ tcnt, float* __restrict__ x) {
  const int i4 = blockIdx.x * 256 + threadIdx.x;
  const int row = i4 >> 5;
  const float m = (tcnt[row] > 0.f) ? 1.f : 0.f;
  if (m == 0.f) return;
  const int c4 = (i4 & 31) * 4;
  const float4 v = ((const float4*)in)[i4];
  const float4 sc = *(const float4*)&ss[c4];
  const float4 sh = *(const float4*)&ss[128 + c4];
  float4 xo = ((const float4*)x)[i4];
  xo.x += fmaxf(fmaf(v.x, sc.x, sh.x), 0.f);
  xo.y += fmaxf(fmaf(v.y, sc.y, sh.y), 0.f);
  xo.z += fmaxf(fmaf(v.z, sc.z, sh.z), 0.f);
  xo.w += fmaxf(fmaf(v.w, sc.w, sh.w), 0.f);
  ((float4*)x)[i4] = xo;
}

// s += (tcnt>0) * (1+eps[layer]) * feature   (s holds E_X already)
__global__ __launch_bounds__(256) void addfeat_kernel(float* __restrict__ sbuf,
                                                      const float* __restrict__ feat,
                                                      const float* __restrict__ tcnt,
                                                      const float* __restrict__ deps,
                                                      int layer) {
  const int i4 = blockIdx.x * 256 + threadIdx.x;
  const int row = i4 >> 5;
  if (!(tcnt[row] > 0.f)) return;
  const float c = 1.f + deps[layer];
  const float4 f = ((const float4*)feat)[i4];
  float4 s = ((const float4*)sbuf)[i4];
  s.x = fmaf(c, f.x, s.x);
  s.y = fmaf(c, f.y, s.y);
  s.z = fmaf(c, f.z, s.z);
  s.w = fmaf(c, f.w, s.w);
  ((float4*)sbuf)[i4] = s;
}

// x[leaves[j]] = feat[leaves[j]] (32 lanes/leaf, float4 per lane)
__global__ __launch_bounds__(256) void scatter_leaves_kernel(
    const int* __restrict__ leaves, const float* __restrict__ feat,
    float* __restrict__ x, int nl) {
  const int gid = blockIdx.x * 256 + threadIdx.x;
  const int j = gid >> 5;
  if (j >= nl) return;
  const int node = leaves[j];
  const int c4 = (gid & 31) * 4;
  *(float4*)&x[(size_t)node * 128 + c4] =
      *(const float4*)&feat[(size_t)node * 128 + c4];
}

// Weighted gather-scatter over active edges; also counts active in-edges.
__global__ __launch_bounds__(256) void edge_kernel(
    const int* __restrict__ src, const int* __restrict__ dst,
    const float* __restrict__ mult, const int* __restrict__ lmask, int layer,
    const float* __restrict__ x, float* __restrict__ EX,
    float* __restrict__ tcnt) {
  const int gid = blockIdx.x * 256 + threadIdx.x;
  const int e = gid >> 5;
  if (e >= Ee) return;
  if (lmask[e] != layer) return;
  const int sN = src[e];
  const int dN = dst[e];
  const float w = mult[e];
  const int c4 = (gid & 31) * 4;
  const float4 xv = *(const float4*)&x[(size_t)sN * 128 + c4];
  float* p = &EX[(size_t)dN * 128 + c4];
  atomicAdd(p + 0, xv.x * w);
  atomicAdd(p + 1, xv.y * w);
  atomicAdd(p + 2, xv.z * w);
  atomicAdd(p + 3, xv.w * w);
  if ((gid & 31) == 0) atomicAdd(&tcnt[dN], 1.0f);
}

// Pool all heights: P[batch[node]] += x[node]
__global__ __launch_bounds__(256) void pool_kernel(const int* __restrict__ ridx,
                                                   const int* __restrict__ batch,
                                                   const float* __restrict__ x,
                                                   float* __restrict__ P,
                                                   int nIdx) {
  const int gid = blockIdx.x * 256 + threadIdx.x;
  const int j = gid >> 5;
  if (j >= nIdx) return;
  const int node = ridx[j];
  const int g = batch[node];
  const int c4 = (gid & 31) * 4;
  const float4 xv = *(const float4*)&x[(size_t)node * 128 + c4];
  float* p = &P[(size_t)g * 128 + c4];
  atomicAdd(p + 0, xv.x);
  atomicAdd(p + 1, xv.y);
  atomicAdd(p + 2, xv.z);
  atomicAdd(p + 3, xv.w);
}

// out[g][t] = 0.25 * sum_c P[g][c] * Wl[c][t] + bl[t]
__global__ void out_kernel(const float* __restrict__ P,
                           const float* __restrict__ Wl,
                           const float* __restrict__ bl,
                           float* __restrict__ out) {
  const int gid = blockIdx.x * blockDim.x + threadIdx.x;
  if (gid >= Gg * Tt) return;
  const int g = gid / Tt;
  const int t = gid - g * Tt;
  float acc = 0.f;
  for (int c = 0; c < 128; ++c) acc += P[g * 128 + c] * Wl[c * Tt + t];
  out[gid] = acc * 0.25f + bl[t];
}

extern "C" void kernel_launch(void* const* d_in, const int* in_sizes, int n_in,
                              void* d_out, int out_size, void* d_ws,
                              size_t ws_size, hipStream_t stream) {
  const float* dag_x = (const float*)d_in[0];
  const int* eidx = (const int*)d_in[1];
  const int* src = eidx;
  const int* dst = eidx + Ee;
  const float* mult = (const float*)d_in[2];
  const int* lmask = (const int*)d_in[3];
  const int* batch = (const int*)d_in[4];
  const int* leaves = (const int*)d_in[5];
  const int* readouts = (const int*)d_in[6];
  const float* W1 = (const float*)d_in[7];
  const float* b1 = (const float*)d_in[8];
  const float* g1 = (const float*)d_in[9];
  const float* be1 = (const float*)d_in[10];
  const float* W2 = (const float*)d_in[11];
  const float* b2 = (const float*)d_in[12];
  const float* g2 = (const float*)d_in[13];
  const float* be2 = (const float*)d_in[14];
  const float* dW1 = (const float*)d_in[15];
  const float* db1 = (const float*)d_in[16];
  const float* dg1 = (const float*)d_in[17];
  const float* dbe1 = (const float*)d_in[18];
  const float* dW2 = (const float*)d_in[19];
  const float* db2 = (const float*)d_in[20];
  const float* dg2 = (const float*)d_in[21];
  const float* dbe2 = (const float*)d_in[22];
  const float* deps = (const float*)d_in[23];
  const float* Wl = (const float*)d_in[24];
  const float* bl = (const float*)d_in[25];
  float* out = (float*)d_out;

  const size_t ND = (size_t)Nn * Dd;
  float* feat = (float*)d_ws;      // N*D
  float* xbuf = feat + ND;         // N*D
  float* Abuf = xbuf + ND;         // N*D temp (E_X / s / y1 / h1 / y2)
  float* tcnt = Abuf + ND;         // N
  float* stats = tcnt + Nn;        // 257 used (sum,sumsq,cnt)
  float* ss = stats + 260;         // 256 (scale, shift)
  float* P = ss + 260;             // G*D pooled accumulator

  const int nleaves = in_sizes[5];   // 50000
  const int nridx = in_sizes[6];     // (L+1)*20000 = 80000

  dim3 blk(256);
  const int gElem4 = (int)(ND / 4 / 256);      // 12500 (exact)
  const int gGemm = (Nn + 63) / 64;            // 1563
  const int gStats = (Nn + 127) / 128;         // 782
  const int gCount = (Nn + 255) / 256;         // 391

  // ---- node feature transformation: Linear-BN-ReLU x2 ----
  gemm_bias<64><<<gGemm, blk, 0, stream>>>(dag_x, W1, b1, Abuf, Nn);
  hipMemsetAsync(stats, 0, 257 * sizeof(float), stream);
  stats_kernel<<<gStats, blk, 0, stream>>>(Abuf, nullptr, stats, Nn);
  scaleshift_kernel<<<1, 128, 0, stream>>>(stats, g1, be1, ss, (float)Nn);
  normrelu_kernel<<<gElem4, blk, 0, stream>>>(Abuf, ss, Abuf);

  gemm_bias<128><<<gGemm, blk, 0, stream>>>(Abuf, W2, b2, Abuf, Nn);  // in-place
  hipMemsetAsync(stats, 0, 257 * sizeof(float), stream);
  stats_kernel<<<gStats, blk, 0, stream>>>(Abuf, nullptr, stats, Nn);
  scaleshift_kernel<<<1, 128, 0, stream>>>(stats, g2, be2, ss, (float)Nn);
  normrelu_kernel<<<gElem4, blk, 0, stream>>>(Abuf, ss, feat);

  // ---- x = zeros; x[leaves0] = feature[leaves0] ----
  hipMemsetAsync(xbuf, 0, ND * sizeof(float), stream);
  scatter_leaves_kernel<<<(nleaves * 32 + 255) / 256, blk, 0, stream>>>(
      leaves, feat, xbuf, nleaves);

  // ---- DAG layers ----
  for (int layer = 0; layer < Ll; ++layer) {
    hipMemsetAsync(Abuf, 0, ND * sizeof(float), stream);
    hipMemsetAsync(tcnt, 0, Nn * sizeof(float), stream);
    hipMemsetAsync(stats, 0, 257 * sizeof(float), stream);
    edge_kernel<<<(Ee * 32) / 256, blk, 0, stream>>>(src, dst, mult, lmask,
                                                     layer, xbuf, Abuf, tcnt);
    count_kernel<<<gCount, blk, 0, stream>>>(tcnt, stats, Nn);
    addfeat_kernel<<<gElem4, blk, 0, stream>>>(Abuf, feat, tcnt, deps, layer);

    gemm_bias<128><<<gGemm, blk, 0, stream>>>(
        Abuf, dW1 + (size_t)layer * Dd * Dd, db1 + layer * Dd, Abuf, Nn);
    stats_kernel<<<gStats, blk, 0, stream>>>(Abuf, tcnt, stats, Nn);
    scaleshift_kernel<<<1, 128, 0, stream>>>(stats, dg1 + layer * Dd,
                                             dbe1 + layer * Dd, ss, -1.f);
    normrelu_kernel<<<gElem4, blk, 0, stream>>>(Abuf, ss, Abuf);

    gemm_bias<128><<<gGemm, blk, 0, stream>>>(
        Abuf, dW2 + (size_t)layer * Dd * Dd, db2 + layer * Dd, Abuf, Nn);
    hipMemsetAsync(stats, 0, 256 * sizeof(float), stream);
    stats_kernel<<<gStats, blk, 0, stream>>>(Abuf, tcnt, stats, Nn);
    scaleshift_kernel<<<1, 128, 0, stream>>>(stats, dg2 + layer * Dd,
                                             dbe2 + layer * Dd, ss, -1.f);
    normrelu_acc_kernel<<<gElem4, blk, 0, stream>>>(Abuf, ss, tcnt, xbuf);
  }

  // ---- readout ----
  hipMemsetAsync(P, 0, (size_t)Gg * Dd * sizeof(float), stream);
  pool_kernel<<<(nridx * 32 + 255) / 256, blk, 0, stream>>>(readouts, batch,
                                                            xbuf, P, nridx);
  out_kernel<<<(Gg * Tt + 255) / 256, blk, 0, stream>>>(P, Wl, bl, out);
}

// Round 2
// 1324.805 us; speedup vs baseline: 1.7192x; 1.7192x over previous
//
#include <hip/hip_runtime.h>

constexpr int Nn = 100000;   // nodes
constexpr int Ee = 600000;   // edges
constexpr int Dd = 128;      // hidden dim
constexpr int Ll = 3;        // DAG layers
constexpr int Gg = 256;      // graphs
constexpr int Tt = 10;       // outputs per graph
constexpr float BN_EPS = 1e-5f;

// ---------------------------------------------------------------------------
// Fused GEMM: C[N][128] = op(A)[N][K] @ W[K][128] + bias
//   NORM_A:  op(a) = relu(a*ssA[k] + ssA[128+k])  (applies previous BN+ReLU)
//   epilogue: writes C raw (bias added), accumulates masked col sum/sumsq
//             into stats (strided by 8 to spread atomic contention).
// In-place safe (C==A) for K==128: block reads only its own 64 rows, all
// consumed into LDS before any store.
// ---------------------------------------------------------------------------
template <int K, bool NORM_A, bool MASKED>
__global__ __launch_bounds__(256) void gemm_fused(
    const float* __restrict__ A, const float* __restrict__ W,
    const float* __restrict__ bias, const float* __restrict__ ssA,
    const int* __restrict__ degL, float* __restrict__ C,
    float* __restrict__ stats, int nrows) {
  __shared__ float As[32][68];   // [k][row], stride 68 floats (16B aligned)
  __shared__ float Ws[32][128];  // [k][col]; reused as reduce scratch
  const int tid = threadIdx.x;
  const int tx = tid & 15;   // cols: tx*4..+3 and 64+tx*4..+3
  const int ty = tid >> 4;   // rows: ty*4..+3
  const int rowBase = blockIdx.x * 64;

  float acc[4][8];
#pragma unroll
  for (int i = 0; i < 4; ++i)
#pragma unroll
    for (int j = 0; j < 8; ++j) acc[i][j] = 0.f;

  for (int k0 = 0; k0 < K; k0 += 32) {
    // A chunk: 64 rows x 32 k; thread: row = tid>>2, k = (tid&3)*8 .. +7
    {
      const int r = tid >> 2;
      const int kk = (tid & 3) * 8;
      const int grow = rowBase + r;
      float v[8] = {0.f, 0.f, 0.f, 0.f, 0.f, 0.f, 0.f, 0.f};
      if (grow < nrows) {
        const float* p = A + (size_t)grow * K + k0 + kk;
        const float4 v0 = *(const float4*)p;
        const float4 v1 = *(const float4*)(p + 4);
        v[0] = v0.x; v[1] = v0.y; v[2] = v0.z; v[3] = v0.w;
        v[4] = v1.x; v[5] = v1.y; v[6] = v1.z; v[7] = v1.w;
      }
      if (NORM_A) {
#pragma unroll
        for (int j = 0; j < 8; ++j) {
          const int kc = k0 + kk + j;
          v[j] = fmaxf(fmaf(v[j], ssA[kc], ssA[128 + kc]), 0.f);
        }
      }
#pragma unroll
      for (int j = 0; j < 8; ++j) As[kk + j][r] = v[j];
    }
    // W chunk: 32x128 contiguous
    {
      const float4* Wv = (const float4*)(W + (size_t)k0 * 128);
      float4* Sv = (float4*)&Ws[0][0];
#pragma unroll
      for (int j = 0; j < 4; ++j) Sv[tid + j * 256] = Wv[tid + j * 256];
    }
    __syncthreads();
#pragma unroll
    for (int kk = 0; kk < 32; ++kk) {
      const float4 av = *(const float4*)&As[kk][ty * 4];
      const float4 b0 = *(const float4*)&Ws[kk][tx * 4];
      const float4 b1 = *(const float4*)&Ws[kk][64 + tx * 4];
      const float a[4] = {av.x, av.y, av.z, av.w};
      const float b[8] = {b0.x, b0.y, b0.z, b0.w, b1.x, b1.y, b1.z, b1.w};
#pragma unroll
      for (int i = 0; i < 4; ++i)
#pragma unroll
        for (int j = 0; j < 8; ++j) acc[i][j] = fmaf(a[i], b[j], acc[i][j]);
    }
    __syncthreads();  // also protects Ws reuse below
  }

  // Epilogue: bias, store, masked stats partials
  const float4 bb0 = *(const float4*)&bias[tx * 4];
  const float4 bb1 = *(const float4*)&bias[64 + tx * 4];
  const float bb[8] = {bb0.x, bb0.y, bb0.z, bb0.w, bb1.x, bb1.y, bb1.z, bb1.w};
  float psum[8] = {0.f, 0.f, 0.f, 0.f, 0.f, 0.f, 0.f, 0.f};
  float psq[8] = {0.f, 0.f, 0.f, 0.f, 0.f, 0.f, 0.f, 0.f};
#pragma unroll
  for (int i = 0; i < 4; ++i) {
    const int grow = rowBase + ty * 4 + i;
    if (grow >= nrows) continue;
    float o[8];
#pragma unroll
    for (int j = 0; j < 8; ++j) o[j] = acc[i][j] + bb[j];
    float* p = C + (size_t)grow * 128;
    float4 s0, s1;
    s0.x = o[0]; s0.y = o[1]; s0.z = o[2]; s0.w = o[3];
    s1.x = o[4]; s1.y = o[5]; s1.z = o[6]; s1.w = o[7];
    *(float4*)(p + tx * 4) = s0;
    *(float4*)(p + 64 + tx * 4) = s1;
    float m = 1.f;
    if (MASKED) m = (degL[grow] > 0) ? 1.f : 0.f;
#pragma unroll
    for (int j = 0; j < 8; ++j) {
      const float mo = m * o[j];
      psum[j] += mo;
      psq[j] += mo * o[j];
    }
  }
  // Block reduce over ty (16) in Ws scratch, then strided atomics.
  float* Ssum = &Ws[0][0];   // [16][128]
  float* Ssq = Ssum + 2048;  // [16][128]
  int cmap[8];
#pragma unroll
  for (int j = 0; j < 8; ++j) cmap[j] = (j < 4) ? (tx * 4 + j) : (64 + tx * 4 + j - 4);
#pragma unroll
  for (int j = 0; j < 8; ++j) {
    Ssum[ty * 128 + cmap[j]] = psum[j];
    Ssq[ty * 128 + cmap[j]] = psq[j];
  }
  __syncthreads();
  for (int s2 = 8; s2 > 0; s2 >>= 1) {
    if (ty < s2) {
#pragma unroll
      for (int j = 0; j < 8; ++j) {
        Ssum[ty * 128 + cmap[j]] += Ssum[(ty + s2) * 128 + cmap[j]];
        Ssq[ty * 128 + cmap[j]] += Ssq[(ty + s2) * 128 + cmap[j]];
      }
    }
    __syncthreads();
  }
  if (ty == 0) {
#pragma unroll
    for (int j = 0; j < 8; ++j) {
      atomicAdd(&stats[cmap[j] * 8], Ssum[cmap[j]]);
      atomicAdd(&stats[(128 + cmap[j]) * 8], Ssq[cmap[j]]);
    }
  }
}

// BN finalize: read strided stats, compute scale/shift, zero stats for reuse.
__global__ void scaleshift_kernel(float* __restrict__ stats,
                                  const float* __restrict__ g,
                                  const float* __restrict__ be,
                                  float* __restrict__ ss, float cntFixed,
                                  const float* __restrict__ cntPtr) {
  const int c = threadIdx.x;  // 128 threads
  const float cnt = cntPtr ? fmaxf(cntPtr[0], 1.f) : cntFixed;
  const float S = stats[c * 8];
  const float Q = stats[(128 + c) * 8];
  stats[c * 8] = 0.f;
  stats[(128 + c) * 8] = 0.f;
  const float m = S / cnt;
  const float v = Q / cnt - m * m;
  const float sc = g[c] * rsqrtf(v + BN_EPS);
  ss[c] = sc;
  ss[128 + c] = be[c] - m * sc;
}

// out = relu(in*scale+shift)
__global__ __launch_bounds__(256) void normrelu_kernel(
    const float* __restrict__ in, const float* __restrict__ ss,
    float* __restrict__ out) {
  const int i4 = blockIdx.x * 256 + threadIdx.x;
  const int c4 = (i4 & 31) * 4;
  const float4 v = ((const float4*)in)[i4];
  const float4 sc = *(const float4*)&ss[c4];
  const float4 sh = *(const float4*)&ss[128 + c4];
  float4 o;
  o.x = fmaxf(fmaf(v.x, sc.x, sh.x), 0.f);
  o.y = fmaxf(fmaf(v.y, sc.y, sh.y), 0.f);
  o.z = fmaxf(fmaf(v.z, sc.z, sh.z), 0.f);
  o.w = fmaxf(fmaf(v.w, sc.w, sh.w), 0.f);
  ((float4*)out)[i4] = o;
}

// x += (deg>0) * relu(in*scale+shift)
__global__ __launch_bounds__(256) void normrelu_acc_kernel(
    const float* __restrict__ in, const float* __restrict__ ss,
    const int* __restrict__ degL, float* __restrict__ x) {
  const int i4 = blockIdx.x * 256 + threadIdx.x;
  const int row = i4 >> 5;
  if (degL[row] <= 0) return;
  const int c4 = (i4 & 31) * 4;
  const float4 v = ((const float4*)in)[i4];
  const float4 sc = *(const float4*)&ss[c4];
  const float4 sh = *(const float4*)&ss[128 + c4];
  float4 xo = ((const float4*)x)[i4];
  xo.x += fmaxf(fmaf(v.x, sc.x, sh.x), 0.f);
  xo.y += fmaxf(fmaf(v.y, sc.y, sh.y), 0.f);
  xo.z += fmaxf(fmaf(v.z, sc.z, sh.z), 0.f);
  xo.w += fmaxf(fmaf(v.w, sc.w, sh.w), 0.f);
  ((float4*)x)[i4] = xo;
}

// x[leaves[j]] = feat[leaves[j]]
__global__ __launch_bounds__(256) void scatter_leaves_kernel(
    const int* __restrict__ leaves, const float* __restrict__ feat,
    float* __restrict__ x, int nl) {
  const int gid = blockIdx.x * 256 + threadIdx.x;
  const int j = gid >> 5;
  if (j >= nl) return;
  const int node = leaves[j];
  const int c4 = (gid & 31) * 4;
  *(float4*)&x[(size_t)node * 128 + c4] =
      *(const float4*)&feat[(size_t)node * 128 + c4];
}

// ---------------- CSR build (per call; edge topo is a runtime input) --------
__global__ __launch_bounds__(256) void deg_count_kernel(
    const int* __restrict__ dst, const int* __restrict__ lmask,
    int* __restrict__ deg) {
  const int e = blockIdx.x * 256 + threadIdx.x;
  if (e >= Ee) return;
  atomicAdd(&deg[lmask[e] * Nn + dst[e]], 1);
}

__global__ __launch_bounds__(256) void scan1_kernel(const int* __restrict__ in,
                                                    int* __restrict__ out,
                                                    int* __restrict__ bsum,
                                                    int n) {
  __shared__ int lds[256];
  const int tid = threadIdx.x;
  const int base = blockIdx.x * 2048 + tid * 8;
  int vals[8];
  int tsum = 0;
#pragma unroll
  for (int j = 0; j < 8; ++j) {
    const int v = (base + j < n) ? in[base + j] : 0;
    vals[j] = tsum;
    tsum += v;
  }
  lds[tid] = tsum;
  __syncthreads();
  for (int off = 1; off < 256; off <<= 1) {
    const int y = (tid >= off) ? lds[tid - off] : 0;
    __syncthreads();
    lds[tid] += y;
    __syncthreads();
  }
  const int texcl = (tid > 0) ? lds[tid - 1] : 0;
#pragma unroll
  for (int j = 0; j < 8; ++j)
    if (base + j < n) out[base + j] = texcl + vals[j];
  if (tid == 255) bsum[blockIdx.x] = lds[255];
}

__global__ void scan2_kernel(int* __restrict__ bsum, int nb) {
  __shared__ int lds[256];
  const int tid = threadIdx.x;
  const int v = (tid < nb) ? bsum[tid] : 0;
  lds[tid] = v;
  __syncthreads();
  for (int off = 1; off < 256; off <<= 1) {
    const int y = (tid >= off) ? lds[tid - off] : 0;
    __syncthreads();
    lds[tid] += y;
    __syncthreads();
  }
  if (tid < nb) bsum[tid] = lds[tid] - v;  // exclusive
}

__global__ __launch_bounds__(256) void scan3_kernel(int* __restrict__ out,
                                                    int* __restrict__ cursor,
                                                    const int* __restrict__ bsum,
                                                    int n) {
  const int i = blockIdx.x * 256 + threadIdx.x;
  if (i >= n) return;
  const int v = out[i] + bsum[i >> 11];
  out[i] = v;
  cursor[i] = v;
}

__global__ __launch_bounds__(256) void csr_fill_kernel(
    const int* __restrict__ dst, const int* __restrict__ lmask,
    int* __restrict__ cursor, int* __restrict__ csr) {
  const int e = blockIdx.x * 256 + threadIdx.x;
  if (e >= Ee) return;
  const int slot = atomicAdd(&cursor[lmask[e] * Nn + dst[e]], 1);
  csr[slot] = e;
}

// target count for one layer: #nodes with deg>0 -> tslot
__global__ __launch_bounds__(256) void tcount_kernel(
    const int* __restrict__ degBase, float* __restrict__ tslot) {
  const int i = blockIdx.x * 256 + threadIdx.x;
  float v = (i < Nn && degBase[i] > 0) ? 1.f : 0.f;
  __shared__ float l[256];
  l[threadIdx.x] = v;
  __syncthreads();
  for (int s = 128; s > 0; s >>= 1) {
    if (threadIdx.x < s) l[threadIdx.x] += l[threadIdx.x + s];
    __syncthreads();
  }
  if (threadIdx.x == 0 && l[0] != 0.f) atomicAdd(tslot, l[0]);
}

// CSR aggregation: s[node] = sum_in-edges w*x[src] + (deg>0)*(1+eps)*feat[node]
// One 64-lane wave per node, float2 per lane (128 cols). Writes every row.
__global__ __launch_bounds__(256) void agg_kernel(
    const int* __restrict__ offs, const int* __restrict__ csr,
    const int* __restrict__ src, const float* __restrict__ mult,
    const float* __restrict__ x, const float* __restrict__ feat,
    const float* __restrict__ deps, int layer, float* __restrict__ sbuf) {
  const int node = blockIdx.x * 4 + (threadIdx.x >> 6);
  const int lane = threadIdx.x & 63;
  const int gi = layer * Nn + node;
  const int o0 = offs[gi];
  const int o1 = (gi + 1 < 3 * Nn) ? offs[gi + 1] : Ee;
  float2 acc = {0.f, 0.f};
  for (int p = o0; p < o1; ++p) {
    const int e = csr[p];
    const int sN = src[e];
    const float w = mult[e];
    const float2 xv = *(const float2*)&x[(size_t)sN * 128 + lane * 2];
    acc.x = fmaf(w, xv.x, acc.x);
    acc.y = fmaf(w, xv.y, acc.y);
  }
  if (o1 > o0) {
    const float c = 1.f + deps[layer];
    const float2 f = *(const float2*)&feat[(size_t)node * 128 + lane * 2];
    acc.x = fmaf(c, f.x, acc.x);
    acc.y = fmaf(c, f.y, acc.y);
  }
  *(float2*)&sbuf[(size_t)node * 128 + lane * 2] = acc;
}

// ---------------- fallback path (small ws): atomic scatter -----------------
__global__ __launch_bounds__(256) void edge_kernel(
    const int* __restrict__ src, const int* __restrict__ dst,
    const float* __restrict__ mult, const int* __restrict__ lmask, int layer,
    const float* __restrict__ x, float* __restrict__ EX,
    int* __restrict__ deg) {
  const int gid = blockIdx.x * 256 + threadIdx.x;
  const int e = gid >> 5;
  if (e >= Ee) return;
  if (lmask[e] != layer) return;
  const int sN = src[e];
  const int dN = dst[e];
  const float w = mult[e];
  const int c4 = (gid & 31) * 4;
  const float4 xv = *(const float4*)&x[(size_t)sN * 128 + c4];
  float* p = &EX[(size_t)dN * 128 + c4];
  atomicAdd(p + 0, xv.x * w);
  atomicAdd(p + 1, xv.y * w);
  atomicAdd(p + 2, xv.z * w);
  atomicAdd(p + 3, xv.w * w);
  if ((gid & 31) == 0) atomicAdd(&deg[dN], 1);
}

__global__ __launch_bounds__(256) void addfeat_kernel(
    float* __restrict__ sbuf, const float* __restrict__ feat,
    const int* __restrict__ degL, const float* __restrict__ deps, int layer) {
  const int i4 = blockIdx.x * 256 + threadIdx.x;
  const int row = i4 >> 5;
  if (degL[row] <= 0) return;
  const float c = 1.f + deps[layer];
  const float4 f = ((const float4*)feat)[i4];
  float4 s = ((const float4*)sbuf)[i4];
  s.x = fmaf(c, f.x, s.x);
  s.y = fmaf(c, f.y, s.y);
  s.z = fmaf(c, f.z, s.z);
  s.w = fmaf(c, f.w, s.w);
  ((float4*)sbuf)[i4] = s;
}

// ---------------- readout --------------------------------------------------
__global__ __launch_bounds__(256) void pool_kernel(
    const int* __restrict__ ridx, const int* __restrict__ batch,
    const float* __restrict__ x, float* __restrict__ P, int nIdx) {
  const int gid = blockIdx.x * 256 + threadIdx.x;
  const int j = gid >> 5;
  if (j >= nIdx) return;
  const int node = ridx[j];
  const int g = batch[node];
  const int c4 = (gid & 31) * 4;
  const float4 xv = *(const float4*)&x[(size_t)node * 128 + c4];
  float* p = &P[(size_t)g * 128 + c4];
  atomicAdd(p + 0, xv.x);
  atomicAdd(p + 1, xv.y);
  atomicAdd(p + 2, xv.z);
  atomicAdd(p + 3, xv.w);
}

__global__ void out_kernel(const float* __restrict__ P,
                           const float* __restrict__ Wl,
                           const float* __restrict__ bl,
                           float* __restrict__ out) {
  const int gid = blockIdx.x * blockDim.x + threadIdx.x;
  if (gid >= Gg * Tt) return;
  const int g = gid / Tt;
  const int t = gid - g * Tt;
  float acc = 0.f;
  for (int c = 0; c < 128; ++c) acc += P[g * 128 + c] * Wl[c * Tt + t];
  out[gid] = acc * 0.25f + bl[t];
}

extern "C" void kernel_launch(void* const* d_in, const int* in_sizes, int n_in,
                              void* d_out, int out_size, void* d_ws,
                              size_t ws_size, hipStream_t stream) {
  const float* dag_x = (const float*)d_in[0];
  const int* eidx = (const int*)d_in[1];
  const int* src = eidx;
  const int* dst = eidx + Ee;
  const float* mult = (const float*)d_in[2];
  const int* lmask = (const int*)d_in[3];
  const int* batch = (const int*)d_in[4];
  const int* leaves = (const int*)d_in[5];
  const int* readouts = (const int*)d_in[6];
  const float* W1 = (const float*)d_in[7];
  const float* b1 = (const float*)d_in[8];
  const float* g1 = (const float*)d_in[9];
  const float* be1 = (const float*)d_in[10];
  const float* W2 = (const float*)d_in[11];
  const float* b2 = (const float*)d_in[12];
  const float* g2 = (const float*)d_in[13];
  const float* be2 = (const float*)d_in[14];
  const float* dW1 = (const float*)d_in[15];
  const float* db1 = (const float*)d_in[16];
  const float* dg1 = (const float*)d_in[17];
  const float* dbe1 = (const float*)d_in[18];
  const float* dW2 = (const float*)d_in[19];
  const float* db2 = (const float*)d_in[20];
  const float* dg2 = (const float*)d_in[21];
  const float* dbe2 = (const float*)d_in[22];
  const float* deps = (const float*)d_in[23];
  const float* Wl = (const float*)d_in[24];
  const float* bl = (const float*)d_in[25];
  float* out = (float*)d_out;

  const size_t ND = (size_t)Nn * Dd;
  float* feat = (float*)d_ws;     // N*D
  float* xbuf = feat + ND;        // N*D
  float* Abuf = xbuf + ND;        // N*D
  float* stats = Abuf + ND;       // 2048 (strided sum/sumsq)
  float* ss = stats + 2048;       // 256 (scale, shift)
  float* tcountf = ss + 256;      // 4
  int* ibase = (int*)(tcountf + 4);
  float* P = Abuf;                // Abuf is dead by readout time

  int* deg3 = ibase;              // pathA: [3N]  / pathB: [N] per-layer
  int* offs = ibase + 3 * Nn;     // [3N]
  int* csr = ibase + 6 * Nn;      // [E]
  int* cursor = (int*)xbuf;       // transient during build (xbuf written later)
  int* bsum = cursor + 3 * Nn;    // transient

  const size_t needA = (size_t)((char*)(csr + Ee) - (char*)d_ws);
  const bool pathA = ws_size >= needA;

  const int nleaves = in_sizes[5];  // 50000
  const int nridx = in_sizes[6];    // 80000

  dim3 blk(256);
  hipMemsetAsync(stats, 0, 2048 * sizeof(float), stream);
  hipMemsetAsync(tcountf, 0, 4 * sizeof(float), stream);

  if (pathA) {
    hipMemsetAsync(deg3, 0, 3 * Nn * sizeof(int), stream);
    deg_count_kernel<<<2344, blk, 0, stream>>>(dst, lmask, deg3);
    for (int l = 0; l < Ll; ++l)
      tcount_kernel<<<391, blk, 0, stream>>>(deg3 + l * Nn, tcountf + l);
    scan1_kernel<<<147, blk, 0, stream>>>(deg3, offs, bsum, 3 * Nn);
    scan2_kernel<<<1, blk, 0, stream>>>(bsum, 147);
    scan3_kernel<<<1172, blk, 0, stream>>>(offs, cursor, bsum, 3 * Nn);
    csr_fill_kernel<<<2344, blk, 0, stream>>>(dst, lmask, cursor, csr);
  }

  // ---- node feature transform: (Linear+BN-stats) -> ss -> (next GEMM) ----
  gemm_fused<64, false, false><<<1563, blk, 0, stream>>>(
      dag_x, W1, b1, nullptr, nullptr, Abuf, stats, Nn);
  scaleshift_kernel<<<1, 128, 0, stream>>>(stats, g1, be1, ss, (float)Nn, nullptr);
  gemm_fused<128, true, false><<<1563, blk, 0, stream>>>(
      Abuf, W2, b2, ss, nullptr, Abuf, stats, Nn);
  scaleshift_kernel<<<1, 128, 0, stream>>>(stats, g2, be2, ss, (float)Nn, nullptr);
  normrelu_kernel<<<12500, blk, 0, stream>>>(Abuf, ss, feat);

  hipMemsetAsync(xbuf, 0, ND * sizeof(float), stream);
  scatter_leaves_kernel<<<6250, blk, 0, stream>>>(leaves, feat, xbuf, nleaves);

  // ---- DAG layers ----
  for (int layer = 0; layer < Ll; ++layer) {
    int* degL = pathA ? (deg3 + layer * Nn) : deg3;
    if (pathA) {
      agg_kernel<<<25000, blk, 0, stream>>>(offs, csr, src, mult, xbuf, feat,
                                            deps, layer, Abuf);
    } else {
      hipMemsetAsync(Abuf, 0, ND * sizeof(float), stream);
      hipMemsetAsync(degL, 0, Nn * sizeof(int), stream);
      edge_kernel<<<75000, blk, 0, stream>>>(src, dst, mult, lmask, layer,
                                             xbuf, Abuf, degL);
      tcount_kernel<<<391, blk, 0, stream>>>(degL, tcountf + layer);
      addfeat_kernel<<<12500, blk, 0, stream>>>(Abuf, feat, degL, deps, layer);
    }
    const size_t wo = (size_t)layer * Dd * Dd;
    const int po = layer * Dd;
    gemm_fused<128, false, true><<<1563, blk, 0, stream>>>(
        Abuf, dW1 + wo, db1 + po, nullptr, degL, Abuf, stats, Nn);
    scaleshift_kernel<<<1, 128, 0, stream>>>(stats, dg1 + po, dbe1 + po, ss,
                                             -1.f, tcountf + layer);
    gemm_fused<128, true, true><<<1563, blk, 0, stream>>>(
        Abuf, dW2 + wo, db2 + po, ss, degL, Abuf, stats, Nn);
    scaleshift_kernel<<<1, 128, 0, stream>>>(stats, dg2 + po, dbe2 + po, ss,
                                             -1.f, tcountf + layer);
    normrelu_acc_kernel<<<12500, blk, 0, stream>>>(Abuf, ss, degL, xbuf);
  }

  // ---- readout ----
  hipMemsetAsync(P, 0, (size_t)Gg * Dd * sizeof(float), stream);
  pool_kernel<<<10000, blk, 0, stream>>>(readouts, batch, xbuf, P, nridx);
  out_kernel<<<10, blk, 0, stream>>>(P, Wl, bl, out);
}

// Round 3
// 864.119 us; speedup vs baseline: 2.6357x; 1.5331x over previous
//
#include <hip/hip_runtime.h>

constexpr int Nn = 100000;   // nodes
constexpr int Ee = 600000;   // edges
constexpr int Dd = 128;      // hidden dim
constexpr int Ll = 3;        // DAG layers
constexpr int Gg = 256;      // graphs
constexpr int Tt = 10;       // outputs per graph
constexpr float BN_EPS = 1e-5f;

typedef __attribute__((ext_vector_type(8))) short short8v;
typedef __attribute__((ext_vector_type(4))) float f32x4;

__device__ inline ushort bf_hi(float f) {
  unsigned u = __float_as_uint(f);
  unsigned r = (u + 0x7FFFu + ((u >> 16) & 1u)) >> 16;
  return (ushort)r;
}
__device__ inline float bf_f(ushort h) {
  return __uint_as_float(((unsigned)h) << 16);
}

// ---------------------------------------------------------------------------
// Split-bf16 MFMA GEMM: C[N][128] = op(A)[N][K] @ W[K][128] + bias
// A split to hi/lo bf16 in staging; C = Ah*Bh + Al*Bh + Ah*Bl (fp32 acc).
// Tile 128 rows x 128 cols, 4 waves (each 32 rows), K-chunks of 32.
// W passed pre-transposed+split: WTh/WTl row-major [col][K].
// NORM_A: apply relu(a*ssA[k]+ssA[128+k]) to A in staging.
// Epilogue: +bias, store, masked col sum/sumsq -> stats (strided by 8).
// In-place safe (C==A): block reads only its own 128 rows, all staged
// through LDS before any store.
// ---------------------------------------------------------------------------
template <int K, bool NORM_A, bool MASKED>
__global__ __launch_bounds__(256, 2) void gemm_mfma(
    const float* __restrict__ A, const ushort* __restrict__ WTh,
    const ushort* __restrict__ WTl, const float* __restrict__ bias,
    const float* __restrict__ ssA, const int* __restrict__ tmask,
    float* __restrict__ C, float* __restrict__ stats, int nrows) {
  __shared__ ushort Ah[128][40];  // padded k-stride 40 shorts (80 B)
  __shared__ ushort Al[128][40];
  __shared__ ushort Bh[128][40];  // [col][k]
  __shared__ ushort Bl[128][40];
  const int tid = threadIdx.x;
  const int w = tid >> 6;
  const int lane = tid & 63;
  const int lr = lane & 15;
  const int lg = lane >> 4;
  const int lk = lg * 8;
  const int rowBase = blockIdx.x * 128;

  const f32x4 fzero = {0.f, 0.f, 0.f, 0.f};
  f32x4 acc[2][8];
#pragma unroll
  for (int i = 0; i < 2; ++i)
#pragma unroll
    for (int j = 0; j < 8; ++j) acc[i][j] = fzero;

  for (int k0 = 0; k0 < K; k0 += 32) {
    // ---- stage A (fp32 -> hi/lo bf16) ----
    {
      const int r = tid >> 1;
      const int ks = (tid & 1) * 16;
      const int grow = rowBase + r;
      float v[16];
      if (grow < nrows) {
        const float* p = A + (size_t)grow * K + k0 + ks;
#pragma unroll
        for (int j = 0; j < 16; j += 4) {
          const float4 t4 = *(const float4*)(p + j);
          v[j] = t4.x; v[j + 1] = t4.y; v[j + 2] = t4.z; v[j + 3] = t4.w;
        }
      } else {
#pragma unroll
        for (int j = 0; j < 16; ++j) v[j] = 0.f;
      }
      if (NORM_A) {
#pragma unroll
        for (int j = 0; j < 16; ++j) {
          const int kc = k0 + ks + j;
          v[j] = fmaxf(fmaf(v[j], ssA[kc], ssA[128 + kc]), 0.f);
        }
      }
      short8v h0, h1, l0, l1;
#pragma unroll
      for (int j = 0; j < 8; ++j) {
        const ushort hh = bf_hi(v[j]);
        h0[j] = (short)hh;
        l0[j] = (short)bf_hi(v[j] - bf_f(hh));
      }
#pragma unroll
      for (int j = 0; j < 8; ++j) {
        const ushort hh = bf_hi(v[8 + j]);
        h1[j] = (short)hh;
        l1[j] = (short)bf_hi(v[8 + j] - bf_f(hh));
      }
      *(short8v*)&Ah[r][ks] = h0;
      *(short8v*)&Ah[r][ks + 8] = h1;
      *(short8v*)&Al[r][ks] = l0;
      *(short8v*)&Al[r][ks + 8] = l1;
    }
    // ---- stage B (pre-split, [col][K] row-major) ----
    {
      const int c = tid >> 1;
      const int ks = (tid & 1) * 16;
      const ushort* ph = WTh + (size_t)c * K + k0 + ks;
      const ushort* pl = WTl + (size_t)c * K + k0 + ks;
      *(short8v*)&Bh[c][ks] = *(const short8v*)ph;
      *(short8v*)&Bh[c][ks + 8] = *(const short8v*)(ph + 8);
      *(short8v*)&Bl[c][ks] = *(const short8v*)pl;
      *(short8v*)&Bl[c][ks + 8] = *(const short8v*)(pl + 8);
    }
    __syncthreads();
    const short8v a0h = *(const short8v*)&Ah[w * 32 + lr][lk];
    const short8v a0l = *(const short8v*)&Al[w * 32 + lr][lk];
    const short8v a1h = *(const short8v*)&Ah[w * 32 + 16 + lr][lk];
    const short8v a1l = *(const short8v*)&Al[w * 32 + 16 + lr][lk];
#pragma unroll
    for (int nf = 0; nf < 8; ++nf) {
      const short8v bh = *(const short8v*)&Bh[nf * 16 + lr][lk];
      const short8v bl = *(const short8v*)&Bl[nf * 16 + lr][lk];
      acc[0][nf] = __builtin_amdgcn_mfma_f32_16x16x32_bf16(a0h, bh, acc[0][nf], 0, 0, 0);
      acc[1][nf] = __builtin_amdgcn_mfma_f32_16x16x32_bf16(a1h, bh, acc[1][nf], 0, 0, 0);
      acc[0][nf] = __builtin_amdgcn_mfma_f32_16x16x32_bf16(a0l, bh, acc[0][nf], 0, 0, 0);
      acc[1][nf] = __builtin_amdgcn_mfma_f32_16x16x32_bf16(a1l, bh, acc[1][nf], 0, 0, 0);
      acc[0][nf] = __builtin_amdgcn_mfma_f32_16x16x32_bf16(a0h, bl, acc[0][nf], 0, 0, 0);
      acc[1][nf] = __builtin_amdgcn_mfma_f32_16x16x32_bf16(a1h, bl, acc[1][nf], 0, 0, 0);
    }
    __syncthreads();
  }

  // ---- epilogue: bias, store, masked stats ----
  float mrow[2][4];
#pragma unroll
  for (int mf = 0; mf < 2; ++mf)
#pragma unroll
    for (int r = 0; r < 4; ++r) {
      const int row = rowBase + w * 32 + mf * 16 + lg * 4 + r;
      float m = 0.f;
      if (row < nrows) m = MASKED ? ((tmask[row] > 0) ? 1.f : 0.f) : 1.f;
      mrow[mf][r] = m;
    }
  float* Sred = (float*)&Ah[0][0];  // [4][128]
  float* Sq = Sred + 512;           // [4][128]
#pragma unroll
  for (int nf = 0; nf < 8; ++nf) {
    const int col = nf * 16 + lr;
    const float bcol = bias[col];
    float ps = 0.f, pq = 0.f;
#pragma unroll
    for (int mf = 0; mf < 2; ++mf) {
      const f32x4 vv = acc[mf][nf];
#pragma unroll
      for (int r = 0; r < 4; ++r) {
        const float o = vv[r] + bcol;
        const int row = rowBase + w * 32 + mf * 16 + lg * 4 + r;
        if (row < nrows) C[(size_t)row * 128 + col] = o;
        const float mo = mrow[mf][r] * o;
        ps += mo;
        pq += mo * o;
      }
    }
    ps += __shfl_xor(ps, 16);
    ps += __shfl_xor(ps, 32);
    pq += __shfl_xor(pq, 16);
    pq += __shfl_xor(pq, 32);
    if (lg == 0) {
      Sred[w * 128 + col] = ps;
      Sq[w * 128 + col] = pq;
    }
  }
  __syncthreads();
  {
    const int col = tid & 127;
    float s = 0.f;
    if ((tid >> 7) == 0) {
#pragma unroll
      for (int q = 0; q < 4; ++q) s += Sred[q * 128 + col];
      atomicAdd(&stats[col * 8], s);
    } else {
#pragma unroll
      for (int q = 0; q < 4; ++q) s += Sq[q * 128 + col];
      atomicAdd(&stats[(128 + col) * 8], s);
    }
  }
}

// Weight transpose + hi/lo split: 8 slots of 32768 ushorts (hi, then lo@+16384)
__global__ __launch_bounds__(256) void wsplit_kernel(
    const float* __restrict__ W1, const float* __restrict__ W2,
    const float* __restrict__ dW1, const float* __restrict__ dW2,
    ushort* __restrict__ wsT) {
  const int t = blockIdx.x * 256 + threadIdx.x;
  const int slot = t >> 14;
  const int idx = t & 16383;
  if (slot >= 8) return;
  const int Ks = (slot == 0) ? 64 : 128;
  if (idx >= 128 * Ks) return;
  const int c = idx / Ks;
  const int k = idx - c * Ks;
  float v;
  if (slot == 0) v = W1[k * 128 + c];
  else if (slot == 1) v = W2[k * 128 + c];
  else if (slot < 5) v = dW1[(slot - 2) * 16384 + k * 128 + c];
  else v = dW2[(slot - 5) * 16384 + k * 128 + c];
  const ushort h = bf_hi(v);
  const ushort l = bf_hi(v - bf_f(h));
  wsT[slot * 32768 + c * Ks + k] = h;
  wsT[slot * 32768 + 16384 + c * Ks + k] = l;
}

// BN finalize: read strided stats, compute scale/shift, zero stats for reuse.
__global__ void scaleshift_kernel(float* __restrict__ stats,
                                  const float* __restrict__ g,
                                  const float* __restrict__ be,
                                  float* __restrict__ ss, float cntFixed,
                                  const float* __restrict__ cntPtr) {
  const int c = threadIdx.x;  // 128 threads
  const float cnt = cntPtr ? fmaxf(cntPtr[0], 1.f) : cntFixed;
  const float S = stats[c * 8];
  const float Q = stats[(128 + c) * 8];
  stats[c * 8] = 0.f;
  stats[(128 + c) * 8] = 0.f;
  const float m = S / cnt;
  const float v = Q / cnt - m * m;
  const float sc = g[c] * rsqrtf(v + BN_EPS);
  ss[c] = sc;
  ss[128 + c] = be[c] - m * sc;
}

__global__ __launch_bounds__(256) void normrelu_kernel(
    const float* __restrict__ in, const float* __restrict__ ss,
    float* __restrict__ out) {
  const int i4 = blockIdx.x * 256 + threadIdx.x;
  const int c4 = (i4 & 31) * 4;
  const float4 v = ((const float4*)in)[i4];
  const float4 sc = *(const float4*)&ss[c4];
  const float4 sh = *(const float4*)&ss[128 + c4];
  float4 o;
  o.x = fmaxf(fmaf(v.x, sc.x, sh.x), 0.f);
  o.y = fmaxf(fmaf(v.y, sc.y, sh.y), 0.f);
  o.z = fmaxf(fmaf(v.z, sc.z, sh.z), 0.f);
  o.w = fmaxf(fmaf(v.w, sc.w, sh.w), 0.f);
  ((float4*)out)[i4] = o;
}

__global__ __launch_bounds__(256) void normrelu_acc_kernel(
    const float* __restrict__ in, const float* __restrict__ ss,
    const int* __restrict__ tmask, float* __restrict__ x) {
  const int i4 = blockIdx.x * 256 + threadIdx.x;
  const int row = i4 >> 5;
  if (tmask[row] <= 0) return;
  const int c4 = (i4 & 31) * 4;
  const float4 v = ((const float4*)in)[i4];
  const float4 sc = *(const float4*)&ss[c4];
  const float4 sh = *(const float4*)&ss[128 + c4];
  float4 xo = ((const float4*)x)[i4];
  xo.x += fmaxf(fmaf(v.x, sc.x, sh.x), 0.f);
  xo.y += fmaxf(fmaf(v.y, sc.y, sh.y), 0.f);
  xo.z += fmaxf(fmaf(v.z, sc.z, sh.z), 0.f);
  xo.w += fmaxf(fmaf(v.w, sc.w, sh.w), 0.f);
  ((float4*)x)[i4] = xo;
}

__global__ __launch_bounds__(256) void scatter_leaves_kernel(
    const int* __restrict__ leaves, const float* __restrict__ feat,
    float* __restrict__ x, int nl) {
  const int gid = blockIdx.x * 256 + threadIdx.x;
  const int j = gid >> 5;
  if (j >= nl) return;
  const int node = leaves[j];
  const int c4 = (gid & 31) * 4;
  *(float4*)&x[(size_t)node * 128 + c4] =
      *(const float4*)&feat[(size_t)node * 128 + c4];
}

// ---------------- CSR build ----------------
__global__ __launch_bounds__(256) void deg_count_kernel(
    const int* __restrict__ dst, const int* __restrict__ lmask,
    int* __restrict__ cnts) {
  const int e = blockIdx.x * 256 + threadIdx.x;
  if (e >= Ee) return;
  atomicAdd(&cnts[lmask[e] * Nn + dst[e]], 1);
}

__global__ __launch_bounds__(256) void scan1_kernel(const int* __restrict__ in,
                                                    int* __restrict__ out,
                                                    int* __restrict__ bsum,
                                                    int n) {
  __shared__ int lds[256];
  const int tid = threadIdx.x;
  const int base = blockIdx.x * 2048 + tid * 8;
  int vals[8];
  int tsum = 0;
#pragma unroll
  for (int j = 0; j < 8; ++j) {
    const int v = (base + j < n) ? in[base + j] : 0;
    vals[j] = tsum;
    tsum += v;
  }
  lds[tid] = tsum;
  __syncthreads();
  for (int off = 1; off < 256; off <<= 1) {
    const int y = (tid >= off) ? lds[tid - off] : 0;
    __syncthreads();
    lds[tid] += y;
    __syncthreads();
  }
  const int texcl = (tid > 0) ? lds[tid - 1] : 0;
#pragma unroll
  for (int j = 0; j < 8; ++j)
    if (base + j < n) out[base + j] = texcl + vals[j];
  if (tid == 255) bsum[blockIdx.x] = lds[255];
}

__global__ void scan2_kernel(int* __restrict__ bsum, int nb) {
  __shared__ int lds[256];
  const int tid = threadIdx.x;
  const int v = (tid < nb) ? bsum[tid] : 0;
  lds[tid] = v;
  __syncthreads();
  for (int off = 1; off < 256; off <<= 1) {
    const int y = (tid >= off) ? lds[tid - off] : 0;
    __syncthreads();
    lds[tid] += y;
    __syncthreads();
  }
  if (tid < nb) bsum[tid] = lds[tid] - v;  // exclusive
}

__global__ __launch_bounds__(256) void scan3_kernel(int* __restrict__ out,
                                                    int* __restrict__ cursor,
                                                    const int* __restrict__ bsum,
                                                    int n, int etot) {
  const int i = blockIdx.x * 256 + threadIdx.x;
  if (i >= n) return;
  const int v = out[i] + bsum[i >> 11];
  out[i] = v;
  cursor[i] = v;
  if (i == n - 1) out[n] = etot;
}

__global__ __launch_bounds__(256) void csr_fill_kernel(
    const int* __restrict__ dst, const int* __restrict__ lmask,
    int* __restrict__ cursor, int* __restrict__ csr) {
  const int e = blockIdx.x * 256 + threadIdx.x;
  if (e >= Ee) return;
  const int slot = atomicAdd(&cursor[lmask[e] * Nn + dst[e]], 1);
  csr[slot] = e;
}

__global__ __launch_bounds__(256) void tcount_kernel(
    const int* __restrict__ degBase, float* __restrict__ tslot) {
  const int i = blockIdx.x * 256 + threadIdx.x;
  float v = (i < Nn && degBase[i] > 0) ? 1.f : 0.f;
  __shared__ float l[256];
  l[threadIdx.x] = v;
  __syncthreads();
  for (int s = 128; s > 0; s >>= 1) {
    if (threadIdx.x < s) l[threadIdx.x] += l[threadIdx.x + s];
    __syncthreads();
  }
  if (threadIdx.x == 0 && l[0] != 0.f) atomicAdd(tslot, l[0]);
}

// CSR aggregation; also emits tmask (target = has active in-edge this layer)
__global__ __launch_bounds__(256) void agg_kernel(
    const int* __restrict__ offs, const int* __restrict__ csr,
    const int* __restrict__ src, const float* __restrict__ mult,
    const float* __restrict__ x, const float* __restrict__ feat,
    const float* __restrict__ deps, int layer, float* __restrict__ sbuf,
    int* __restrict__ tmask) {
  const int node = blockIdx.x * 4 + (threadIdx.x >> 6);
  const int lane = threadIdx.x & 63;
  const int gi = layer * Nn + node;
  const int o0 = offs[gi];
  const int o1 = offs[gi + 1];
  float2 acc = {0.f, 0.f};
  for (int p = o0; p < o1; ++p) {
    const int e = csr[p];
    const int sN = src[e];
    const float w = mult[e];
    const float2 xv = *(const float2*)&x[(size_t)sN * 128 + lane * 2];
    acc.x = fmaf(w, xv.x, acc.x);
    acc.y = fmaf(w, xv.y, acc.y);
  }
  if (o1 > o0) {
    const float c = 1.f + deps[layer];
    const float2 f = *(const float2*)&feat[(size_t)node * 128 + lane * 2];
    acc.x = fmaf(c, f.x, acc.x);
    acc.y = fmaf(c, f.y, acc.y);
  }
  *(float2*)&sbuf[(size_t)node * 128 + lane * 2] = acc;
  if (lane == 0) tmask[node] = (o1 > o0) ? 1 : 0;
}

// ---------------- fallback (small ws): atomic scatter ----------------
__global__ __launch_bounds__(256) void edge_kernel(
    const int* __restrict__ src, const int* __restrict__ dst,
    const float* __restrict__ mult, const int* __restrict__ lmask, int layer,
    const float* __restrict__ x, float* __restrict__ EX,
    int* __restrict__ tmask) {
  const int gid = blockIdx.x * 256 + threadIdx.x;
  const int e = gid >> 5;
  if (e >= Ee) return;
  if (lmask[e] != layer) return;
  const int sN = src[e];
  const int dN = dst[e];
  const float w = mult[e];
  const int c4 = (gid & 31) * 4;
  const float4 xv = *(const float4*)&x[(size_t)sN * 128 + c4];
  float* p = &EX[(size_t)dN * 128 + c4];
  atomicAdd(p + 0, xv.x * w);
  atomicAdd(p + 1, xv.y * w);
  atomicAdd(p + 2, xv.z * w);
  atomicAdd(p + 3, xv.w * w);
  if ((gid & 31) == 0) atomicAdd(&tmask[dN], 1);
}

__global__ __launch_bounds__(256) void addfeat_kernel(
    float* __restrict__ sbuf, const float* __restrict__ feat,
    const int* __restrict__ tmask, const float* __restrict__ deps, int layer) {
  const int i4 = blockIdx.x * 256 + threadIdx.x;
  const int row = i4 >> 5;
  if (tmask[row] <= 0) return;
  const float c = 1.f + deps[layer];
  const float4 f = ((const float4*)feat)[i4];
  float4 s = ((const float4*)sbuf)[i4];
  s.x = fmaf(c, f.x, s.x);
  s.y = fmaf(c, f.y, s.y);
  s.z = fmaf(c, f.z, s.z);
  s.w = fmaf(c, f.w, s.w);
  ((float4*)sbuf)[i4] = s;
}

// ---------------- readout: counting-sort pool (no float atomics) ----------
__global__ __launch_bounds__(256) void phist_kernel(const int* __restrict__ ridx,
                                                    const int* __restrict__ batch,
                                                    int* __restrict__ cnt, int n) {
  const int i = blockIdx.x * 256 + threadIdx.x;
  if (i >= n) return;
  atomicAdd(&cnt[batch[ridx[i]]], 1);
}

__global__ void pscan_kernel(int* __restrict__ cnt, int* __restrict__ cur) {
  __shared__ int l[256];
  const int t = threadIdx.x;
  const int v = cnt[t];
  l[t] = v;
  __syncthreads();
  for (int off = 1; off < 256; off <<= 1) {
    const int y = (t >= off) ? l[t - off] : 0;
    __syncthreads();
    l[t] += y;
    __syncthreads();
  }
  const int e = l[t] - v;  // exclusive
  cnt[t] = e;
  cur[t] = e;
}

__global__ __launch_bounds__(256) void pfill_kernel(const int* __restrict__ ridx,
                                                    const int* __restrict__ batch,
                                                    int* __restrict__ cur,
                                                    int* __restrict__ sorted,
                                                    int n) {
  const int i = blockIdx.x * 256 + threadIdx.x;
  if (i >= n) return;
  const int node = ridx[i];
  const int slot = atomicAdd(&cur[batch[node]], 1);
  sorted[slot] = node;
}

__global__ __launch_bounds__(256) void ppool_kernel(const int* __restrict__ sorted,
                                                    const int* __restrict__ offs,
                                                    const float* __restrict__ x,
                                                    float* __restrict__ P, int n) {
  __shared__ float part[4][256];
  const int g = blockIdx.x;
  const int w = threadIdx.x >> 6;
  const int lane = threadIdx.x & 63;
  const int o0 = offs[g];
  const int o1 = (g < Gg - 1) ? offs[g + 1] : n;
  float2 a = {0.f, 0.f};
  for (int p = o0 + w; p < o1; p += 4) {
    const int node = sorted[p];
    const float2 xv = *(const float2*)&x[(size_t)node * 128 + lane * 2];
    a.x += xv.x;
    a.y += xv.y;
  }
  part[w][lane * 2] = a.x;
  part[w][lane * 2 + 1] = a.y;
  __syncthreads();
  if (threadIdx.x < 128) {
    const int c = threadIdx.x;
    P[(size_t)g * 128 + c] = part[0][c] + part[1][c] + part[2][c] + part[3][c];
  }
}

__global__ void out_kernel(const float* __restrict__ P,
                           const float* __restrict__ Wl,
                           const float* __restrict__ bl,
                           float* __restrict__ out) {
  const int gid = blockIdx.x * blockDim.x + threadIdx.x;
  if (gid >= Gg * Tt) return;
  const int g = gid / Tt;
  const int t = gid - g * Tt;
  float acc = 0.f;
  for (int c = 0; c < 128; ++c) acc += P[g * 128 + c] * Wl[c * Tt + t];
  out[gid] = acc * 0.25f + bl[t];
}

extern "C" void kernel_launch(void* const* d_in, const int* in_sizes, int n_in,
                              void* d_out, int out_size, void* d_ws,
                              size_t ws_size, hipStream_t stream) {
  const float* dag_x = (const float*)d_in[0];
  const int* eidx = (const int*)d_in[1];
  const int* src = eidx;
  const int* dst = eidx + Ee;
  const float* mult = (const float*)d_in[2];
  const int* lmask = (const int*)d_in[3];
  const int* batch = (const int*)d_in[4];
  const int* leaves = (const int*)d_in[5];
  const int* readouts = (const int*)d_in[6];
  const float* W1 = (const float*)d_in[7];
  const float* b1 = (const float*)d_in[8];
  const float* g1 = (const float*)d_in[9];
  const float* be1 = (const float*)d_in[10];
  const float* W2 = (const float*)d_in[11];
  const float* b2 = (const float*)d_in[12];
  const float* g2 = (const float*)d_in[13];
  const float* be2 = (const float*)d_in[14];
  const float* dW1 = (const float*)d_in[15];
  const float* db1 = (const float*)d_in[16];
  const float* dg1 = (const float*)d_in[17];
  const float* dbe1 = (const float*)d_in[18];
  const float* dW2 = (const float*)d_in[19];
  const float* db2 = (const float*)d_in[20];
  const float* dg2 = (const float*)d_in[21];
  const float* dbe2 = (const float*)d_in[22];
  const float* deps = (const float*)d_in[23];
  const float* Wl = (const float*)d_in[24];
  const float* bl = (const float*)d_in[25];
  float* out = (float*)d_out;

  const size_t ND = (size_t)Nn * Dd;
  float* feat = (float*)d_ws;          // N*D
  float* xbuf = feat + ND;             // N*D
  float* Abuf = xbuf + ND;             // N*D
  float* stats = Abuf + ND;            // 2048 (strided sum/sumsq)
  float* ss = stats + 2048;            // 256
  float* tcountf = ss + 256;           // 8 (4 used)
  int* tmask = (int*)(tcountf + 8);    // N
  ushort* wsT = (ushort*)(tmask + Nn); // 262144 (8 weight slots, hi+lo)
  int* offs = (int*)(wsT + 262144);    // 3N+4
  int* csr = offs + 3 * Nn + 4;        // E

  // transient overlays (xbuf before it's initialized):
  int* cnts = (int*)xbuf;              // 3N
  int* cursor = cnts + 3 * Nn;         // 3N
  int* bsum = cursor + 3 * Nn;         // 147
  const int nridx = in_sizes[6];       // 80000
  const int nleaves = in_sizes[5];     // 50000
  // pool overlays (Abuf is dead by readout):
  int* pcnt = (int*)Abuf;              // 256 (becomes offsets)
  int* pcur = pcnt + 256;              // 256
  int* sorted = pcur + 256;            // nridx
  float* P = (float*)(sorted + nridx); // G*D

  const size_t needA = (size_t)((char*)(csr + Ee) - (char*)d_ws);
  const bool pathA = ws_size >= needA;

  dim3 blk(256);
  hipMemsetAsync(stats, 0, 2048 * sizeof(float), stream);
  hipMemsetAsync(tcountf, 0, 8 * sizeof(float), stream);
  wsplit_kernel<<<512, blk, 0, stream>>>(W1, W2, dW1, dW2, wsT);

  if (pathA) {
    hipMemsetAsync(cnts, 0, 3 * Nn * sizeof(int), stream);
    deg_count_kernel<<<2344, blk, 0, stream>>>(dst, lmask, cnts);
    for (int l = 0; l < Ll; ++l)
      tcount_kernel<<<391, blk, 0, stream>>>(cnts + l * Nn, tcountf + l);
    scan1_kernel<<<147, blk, 0, stream>>>(cnts, offs, bsum, 3 * Nn);
    scan2_kernel<<<1, blk, 0, stream>>>(bsum, 147);
    scan3_kernel<<<1172, blk, 0, stream>>>(offs, cursor, bsum, 3 * Nn, Ee);
    csr_fill_kernel<<<2344, blk, 0, stream>>>(dst, lmask, cursor, csr);
  }

  // ---- node feature transform ----
  gemm_mfma<64, false, false><<<782, blk, 0, stream>>>(
      dag_x, wsT, wsT + 16384, b1, nullptr, nullptr, Abuf, stats, Nn);
  scaleshift_kernel<<<1, 128, 0, stream>>>(stats, g1, be1, ss, (float)Nn, nullptr);
  gemm_mfma<128, true, false><<<782, blk, 0, stream>>>(
      Abuf, wsT + 32768, wsT + 32768 + 16384, b2, ss, nullptr, Abuf, stats, Nn);
  scaleshift_kernel<<<1, 128, 0, stream>>>(stats, g2, be2, ss, (float)Nn, nullptr);
  normrelu_kernel<<<12500, blk, 0, stream>>>(Abuf, ss, feat);

  hipMemsetAsync(xbuf, 0, ND * sizeof(float), stream);
  scatter_leaves_kernel<<<6250, blk, 0, stream>>>(leaves, feat, xbuf, nleaves);

  // ---- DAG layers ----
  for (int layer = 0; layer < Ll; ++layer) {
    if (pathA) {
      agg_kernel<<<25000, blk, 0, stream>>>(offs, csr, src, mult, xbuf, feat,
                                            deps, layer, Abuf, tmask);
    } else {
      hipMemsetAsync(Abuf, 0, ND * sizeof(float), stream);
      hipMemsetAsync(tmask, 0, Nn * sizeof(int), stream);
      edge_kernel<<<75000, blk, 0, stream>>>(src, dst, mult, lmask, layer,
                                             xbuf, Abuf, tmask);
      tcount_kernel<<<391, blk, 0, stream>>>(tmask, tcountf + layer);
      addfeat_kernel<<<12500, blk, 0, stream>>>(Abuf, feat, tmask, deps, layer);
    }
    const int so1 = (2 + layer) * 32768;
    const int so2 = (5 + layer) * 32768;
    const int po = layer * Dd;
    gemm_mfma<128, false, true><<<782, blk, 0, stream>>>(
        Abuf, wsT + so1, wsT + so1 + 16384, db1 + po, nullptr, tmask, Abuf,
        stats, Nn);
    scaleshift_kernel<<<1, 128, 0, stream>>>(stats, dg1 + po, dbe1 + po, ss,
                                             -1.f, tcountf + layer);
    gemm_mfma<128, true, true><<<782, blk, 0, stream>>>(
        Abuf, wsT + so2, wsT + so2 + 16384, db2 + po, ss, tmask, Abuf, stats,
        Nn);
    scaleshift_kernel<<<1, 128, 0, stream>>>(stats, dg2 + po, dbe2 + po, ss,
                                             -1.f, tcountf + layer);
    normrelu_acc_kernel<<<12500, blk, 0, stream>>>(Abuf, ss, tmask, xbuf);
  }

  // ---- readout (counting sort, no float atomics) ----
  hipMemsetAsync(pcnt, 0, 512 * sizeof(int), stream);
  const int gIdx = (nridx + 255) / 256;
  phist_kernel<<<gIdx, blk, 0, stream>>>(readouts, batch, pcnt, nridx);
  pscan_kernel<<<1, blk, 0, stream>>>(pcnt, pcur);
  pfill_kernel<<<gIdx, blk, 0, stream>>>(readouts, batch, pcur, sorted, nridx);
  ppool_kernel<<<Gg, blk, 0, stream>>>(sorted, pcnt, xbuf, P, nridx);
  out_kernel<<<10, blk, 0, stream>>>(P, Wl, bl, out);
}

// Round 4
// 834.880 us; speedup vs baseline: 2.7280x; 1.0350x over previous
//
#include <hip/hip_runtime.h>

constexpr int Nn = 100000;   // nodes
constexpr int Ee = 600000;   // edges
constexpr int Dd = 128;      // hidden dim
constexpr int Ll = 3;        // DAG layers
constexpr int Gg = 256;      // graphs
constexpr int Tt = 10;       // outputs per graph
constexpr float BN_EPS = 1e-5f;

typedef __attribute__((ext_vector_type(8))) short short8v;
typedef __attribute__((ext_vector_type(4))) float f32x4;

__device__ inline ushort bf_hi(float f) {
  unsigned u = __float_as_uint(f);
  unsigned r = (u + 0x7FFFu + ((u >> 16) & 1u)) >> 16;
  return (ushort)r;
}
__device__ inline float bf_f(ushort h) {
  return __uint_as_float(((unsigned)h) << 16);
}

// ---------------------------------------------------------------------------
// Split-bf16 MFMA GEMM, software-pipelined A staging.
// C[N][128] = op(A)[N][K] @ W[K][128] + bias;  C = Ah*Bh + Al*Bh + Ah*Bl.
// Tile 128 rows x 128 cols, 4 waves, K-chunks of 32, register-prefetch of
// the next A chunk so HBM latency hides under convert+MFMA of the current.
// W pre-transposed+split: WTh/WTl row-major [col][K].
// NORM_A: relu(a*ss[k]+ss[128+k]) applied in staging (ss cached in LDS).
// Epilogue: +bias, store, masked col sum/sumsq -> stats (strided by 8).
// In-place safe (C==A): block reads only its own 128 rows, fully staged
// before any store.
// ---------------------------------------------------------------------------
template <int K, bool NORM_A, bool MASKED>
__global__ __launch_bounds__(256, 2) void gemm_mfma(
    const float* __restrict__ A, const ushort* __restrict__ WTh,
    const ushort* __restrict__ WTl, const float* __restrict__ bias,
    const float* __restrict__ ssA, const int* __restrict__ tmask,
    float* __restrict__ C, float* __restrict__ stats, int nrows) {
  __shared__ ushort Ah[128][40];  // padded k-stride 40 shorts (80 B)
  __shared__ ushort Al[128][40];
  __shared__ ushort Bh[128][40];  // [col][k]
  __shared__ ushort Bl[128][40];
  __shared__ float ssS[256];
  const int tid = threadIdx.x;
  const int w = tid >> 6;
  const int lane = tid & 63;
  const int lr = lane & 15;
  const int lg = lane >> 4;
  const int lk = lg * 8;
  const int rowBase = blockIdx.x * 128;

  constexpr int NC = K / 32;

  // staging geometry (A and B share it): r/c = tid>>1, ks = (tid&1)*16
  const int r = tid >> 1;
  const int ks = (tid & 1) * 16;
  const int grow = rowBase + r;
  const bool rowOK = grow < nrows;
  const float* aRow = A + (size_t)grow * K + ks;
  const ushort* bRowH = WTh + (size_t)r * K + ks;
  const ushort* bRowL = WTl + (size_t)r * K + ks;

  if (NORM_A) ssS[tid] = ssA[tid];

  const f32x4 fzero = {0.f, 0.f, 0.f, 0.f};
  f32x4 acc[2][8];
#pragma unroll
  for (int i = 0; i < 2; ++i)
#pragma unroll
    for (int j = 0; j < 8; ++j) acc[i][j] = fzero;

  float vbuf[2][16];
  // prologue: chunk 0 A-load into regs
  {
#pragma unroll
    for (int j = 0; j < 16; j += 4) {
      float4 t = rowOK ? *(const float4*)(aRow + j)
                       : make_float4(0.f, 0.f, 0.f, 0.f);
      vbuf[0][j] = t.x; vbuf[0][j + 1] = t.y;
      vbuf[0][j + 2] = t.z; vbuf[0][j + 3] = t.w;
    }
  }
  if (NORM_A) __syncthreads();  // ssS visible before first convert

#pragma unroll
  for (int c = 0; c < NC; ++c) {
    const int k0 = c * 32;
    // ---- issue next-chunk A loads early (independent regs) ----
    if (c + 1 < NC) {
#pragma unroll
      for (int j = 0; j < 16; j += 4) {
        float4 t = rowOK ? *(const float4*)(aRow + (c + 1) * 32 + j)
                         : make_float4(0.f, 0.f, 0.f, 0.f);
        vbuf[(c + 1) & 1][j] = t.x; vbuf[(c + 1) & 1][j + 1] = t.y;
        vbuf[(c + 1) & 1][j + 2] = t.z; vbuf[(c + 1) & 1][j + 3] = t.w;
      }
    }
    // ---- stage B chunk c ----
    {
      *(short8v*)&Bh[r][ks] = *(const short8v*)(bRowH + k0);
      *(short8v*)&Bh[r][ks + 8] = *(const short8v*)(bRowH + k0 + 8);
      *(short8v*)&Bl[r][ks] = *(const short8v*)(bRowL + k0);
      *(short8v*)&Bl[r][ks + 8] = *(const short8v*)(bRowL + k0 + 8);
    }
    // ---- convert current chunk regs -> LDS (hi/lo split) ----
    {
      float v[16];
#pragma unroll
      for (int j = 0; j < 16; ++j) {
        float x = vbuf[c & 1][j];
        if (NORM_A) {
          const int kc = k0 + ks + j;
          x = fmaxf(fmaf(x, ssS[kc], ssS[128 + kc]), 0.f);
        }
        v[j] = x;
      }
      short8v h0, h1, l0, l1;
#pragma unroll
      for (int j = 0; j < 8; ++j) {
        const ushort hh = bf_hi(v[j]);
        h0[j] = (short)hh;
        l0[j] = (short)bf_hi(v[j] - bf_f(hh));
      }
#pragma unroll
      for (int j = 0; j < 8; ++j) {
        const ushort hh = bf_hi(v[8 + j]);
        h1[j] = (short)hh;
        l1[j] = (short)bf_hi(v[8 + j] - bf_f(hh));
      }
      *(short8v*)&Ah[r][ks] = h0;
      *(short8v*)&Ah[r][ks + 8] = h1;
      *(short8v*)&Al[r][ks] = l0;
      *(short8v*)&Al[r][ks + 8] = l1;
    }
    __syncthreads();
    const short8v a0h = *(const short8v*)&Ah[w * 32 + lr][lk];
    const short8v a0l = *(const short8v*)&Al[w * 32 + lr][lk];
    const short8v a1h = *(const short8v*)&Ah[w * 32 + 16 + lr][lk];
    const short8v a1l = *(const short8v*)&Al[w * 32 + 16 + lr][lk];
#pragma unroll
    for (int nf = 0; nf < 8; ++nf) {
      const short8v bh = *(const short8v*)&Bh[nf * 16 + lr][lk];
      const short8v bl = *(const short8v*)&Bl[nf * 16 + lr][lk];
      acc[0][nf] = __builtin_amdgcn_mfma_f32_16x16x32_bf16(a0h, bh, acc[0][nf], 0, 0, 0);
      acc[1][nf] = __builtin_amdgcn_mfma_f32_16x16x32_bf16(a1h, bh, acc[1][nf], 0, 0, 0);
      acc[0][nf] = __builtin_amdgcn_mfma_f32_16x16x32_bf16(a0l, bh, acc[0][nf], 0, 0, 0);
      acc[1][nf] = __builtin_amdgcn_mfma_f32_16x16x32_bf16(a1l, bh, acc[1][nf], 0, 0, 0);
      acc[0][nf] = __builtin_amdgcn_mfma_f32_16x16x32_bf16(a0h, bl, acc[0][nf], 0, 0, 0);
      acc[1][nf] = __builtin_amdgcn_mfma_f32_16x16x32_bf16(a1h, bl, acc[1][nf], 0, 0, 0);
    }
    __syncthreads();
  }

  // ---- epilogue: bias, store, masked stats ----
  float mrow[2][4];
#pragma unroll
  for (int mf = 0; mf < 2; ++mf)
#pragma unroll
    for (int rr = 0; rr < 4; ++rr) {
      const int row = rowBase + w * 32 + mf * 16 + lg * 4 + rr;
      float m = 0.f;
      if (row < nrows) m = MASKED ? ((tmask[row] > 0) ? 1.f : 0.f) : 1.f;
      mrow[mf][rr] = m;
    }
  float* Sred = (float*)&Ah[0][0];  // [4][128]
  float* Sq = Sred + 512;           // [4][128]
#pragma unroll
  for (int nf = 0; nf < 8; ++nf) {
    const int col = nf * 16 + lr;
    const float bcol = bias[col];
    float ps = 0.f, pq = 0.f;
#pragma unroll
    for (int mf = 0; mf < 2; ++mf) {
      const f32x4 vv = acc[mf][nf];
#pragma unroll
      for (int rr = 0; rr < 4; ++rr) {
        const float o = vv[rr] + bcol;
        const int row = rowBase + w * 32 + mf * 16 + lg * 4 + rr;
        if (row < nrows) C[(size_t)row * 128 + col] = o;
        const float mo = mrow[mf][rr] * o;
        ps += mo;
        pq += mo * o;
      }
    }
    ps += __shfl_xor(ps, 16);
    ps += __shfl_xor(ps, 32);
    pq += __shfl_xor(pq, 16);
    pq += __shfl_xor(pq, 32);
    if (lg == 0) {
      Sred[w * 128 + col] = ps;
      Sq[w * 128 + col] = pq;
    }
  }
  __syncthreads();
  {
    const int col = tid & 127;
    float s = 0.f;
    if ((tid >> 7) == 0) {
#pragma unroll
      for (int q = 0; q < 4; ++q) s += Sred[q * 128 + col];
      atomicAdd(&stats[col * 8], s);
    } else {
#pragma unroll
      for (int q = 0; q < 4; ++q) s += Sq[q * 128 + col];
      atomicAdd(&stats[(128 + col) * 8], s);
    }
  }
}

// Weight transpose + hi/lo split: 8 slots of 32768 ushorts (hi, then lo@+16384)
__global__ __launch_bounds__(256) void wsplit_kernel(
    const float* __restrict__ W1, const float* __restrict__ W2,
    const float* __restrict__ dW1, const float* __restrict__ dW2,
    ushort* __restrict__ wsT) {
  const int t = blockIdx.x * 256 + threadIdx.x;
  const int slot = t >> 14;
  const int idx = t & 16383;
  if (slot >= 8) return;
  const int Ks = (slot == 0) ? 64 : 128;
  if (idx >= 128 * Ks) return;
  const int c = idx / Ks;
  const int k = idx - c * Ks;
  float v;
  if (slot == 0) v = W1[k * 128 + c];
  else if (slot == 1) v = W2[k * 128 + c];
  else if (slot < 5) v = dW1[(slot - 2) * 16384 + k * 128 + c];
  else v = dW2[(slot - 5) * 16384 + k * 128 + c];
  const ushort h = bf_hi(v);
  const ushort l = bf_hi(v - bf_f(h));
  wsT[slot * 32768 + c * Ks + k] = h;
  wsT[slot * 32768 + 16384 + c * Ks + k] = l;
}

// BN finalize: read strided stats, compute scale/shift, zero stats for reuse.
__global__ void scaleshift_kernel(float* __restrict__ stats,
                                  const float* __restrict__ g,
                                  const float* __restrict__ be,
                                  float* __restrict__ ss, float cntFixed,
                                  const float* __restrict__ cntPtr) {
  const int c = threadIdx.x;  // 128 threads
  const float cnt = cntPtr ? fmaxf(cntPtr[0], 1.f) : cntFixed;
  const float S = stats[c * 8];
  const float Q = stats[(128 + c) * 8];
  stats[c * 8] = 0.f;
  stats[(128 + c) * 8] = 0.f;
  const float m = S / cnt;
  const float v = Q / cnt - m * m;
  const float sc = g[c] * rsqrtf(v + BN_EPS);
  ss[c] = sc;
  ss[128 + c] = be[c] - m * sc;
}

__global__ __launch_bounds__(256) void normrelu_kernel(
    const float* __restrict__ in, const float* __restrict__ ss,
    float* __restrict__ out) {
  const int i4 = blockIdx.x * 256 + threadIdx.x;
  const int c4 = (i4 & 31) * 4;
  const float4 v = ((const float4*)in)[i4];
  const float4 sc = *(const float4*)&ss[c4];
  const float4 sh = *(const float4*)&ss[128 + c4];
  float4 o;
  o.x = fmaxf(fmaf(v.x, sc.x, sh.x), 0.f);
  o.y = fmaxf(fmaf(v.y, sc.y, sh.y), 0.f);
  o.z = fmaxf(fmaf(v.z, sc.z, sh.z), 0.f);
  o.w = fmaxf(fmaf(v.w, sc.w, sh.w), 0.f);
  ((float4*)out)[i4] = o;
}

__global__ __launch_bounds__(256) void normrelu_acc_kernel(
    const float* __restrict__ in, const float* __restrict__ ss,
    const int* __restrict__ tmask, float* __restrict__ x) {
  const int i4 = blockIdx.x * 256 + threadIdx.x;
  const int row = i4 >> 5;
  if (tmask[row] <= 0) return;
  const int c4 = (i4 & 31) * 4;
  const float4 v = ((const float4*)in)[i4];
  const float4 sc = *(const float4*)&ss[c4];
  const float4 sh = *(const float4*)&ss[128 + c4];
  float4 xo = ((const float4*)x)[i4];
  xo.x += fmaxf(fmaf(v.x, sc.x, sh.x), 0.f);
  xo.y += fmaxf(fmaf(v.y, sc.y, sh.y), 0.f);
  xo.z += fmaxf(fmaf(v.z, sc.z, sh.z), 0.f);
  xo.w += fmaxf(fmaf(v.w, sc.w, sh.w), 0.f);
  ((float4*)x)[i4] = xo;
}

__global__ __launch_bounds__(256) void scatter_leaves_kernel(
    const int* __restrict__ leaves, const float* __restrict__ feat,
    float* __restrict__ x, int nl) {
  const int gid = blockIdx.x * 256 + threadIdx.x;
  const int j = gid >> 5;
  if (j >= nl) return;
  const int node = leaves[j];
  const int c4 = (gid & 31) * 4;
  *(float4*)&x[(size_t)node * 128 + c4] =
      *(const float4*)&feat[(size_t)node * 128 + c4];
}

// ---------------- CSR build ----------------
__global__ __launch_bounds__(256) void deg_count_kernel(
    const int* __restrict__ dst, const int* __restrict__ lmask,
    int* __restrict__ cnts) {
  const int e = blockIdx.x * 256 + threadIdx.x;
  if (e >= Ee) return;
  atomicAdd(&cnts[lmask[e] * Nn + dst[e]], 1);
}

__global__ __launch_bounds__(256) void scan1_kernel(const int* __restrict__ in,
                                                    int* __restrict__ out,
                                                    int* __restrict__ bsum,
                                                    int n) {
  __shared__ int lds[256];
  const int tid = threadIdx.x;
  const int base = blockIdx.x * 2048 + tid * 8;
  int vals[8];
  int tsum = 0;
#pragma unroll
  for (int j = 0; j < 8; ++j) {
    const int v = (base + j < n) ? in[base + j] : 0;
    vals[j] = tsum;
    tsum += v;
  }
  lds[tid] = tsum;
  __syncthreads();
  for (int off = 1; off < 256; off <<= 1) {
    const int y = (tid >= off) ? lds[tid - off] : 0;
    __syncthreads();
    lds[tid] += y;
    __syncthreads();
  }
  const int texcl = (tid > 0) ? lds[tid - 1] : 0;
#pragma unroll
  for (int j = 0; j < 8; ++j)
    if (base + j < n) out[base + j] = texcl + vals[j];
  if (tid == 255) bsum[blockIdx.x] = lds[255];
}

__global__ void scan2_kernel(int* __restrict__ bsum, int nb) {
  __shared__ int lds[256];
  const int tid = threadIdx.x;
  const int v = (tid < nb) ? bsum[tid] : 0;
  lds[tid] = v;
  __syncthreads();
  for (int off = 1; off < 256; off <<= 1) {
    const int y = (tid >= off) ? lds[tid - off] : 0;
    __syncthreads();
    lds[tid] += y;
    __syncthreads();
  }
  if (tid < nb) bsum[tid] = lds[tid] - v;  // exclusive
}

__global__ __launch_bounds__(256) void scan3_kernel(int* __restrict__ out,
                                                    int* __restrict__ cursor,
                                                    const int* __restrict__ bsum,
                                                    int n, int etot) {
  const int i = blockIdx.x * 256 + threadIdx.x;
  if (i >= n) return;
  const int v = out[i] + bsum[i >> 11];
  out[i] = v;
  cursor[i] = v;
  if (i == n - 1) out[n] = etot;
}

__global__ __launch_bounds__(256) void csr_fill_kernel(
    const int* __restrict__ dst, const int* __restrict__ lmask,
    int* __restrict__ cursor, int* __restrict__ csr) {
  const int e = blockIdx.x * 256 + threadIdx.x;
  if (e >= Ee) return;
  const int slot = atomicAdd(&cursor[lmask[e] * Nn + dst[e]], 1);
  csr[slot] = e;
}

__global__ __launch_bounds__(256) void tcount_kernel(
    const int* __restrict__ degBase, float* __restrict__ tslot) {
  const int i = blockIdx.x * 256 + threadIdx.x;
  float v = (i < Nn && degBase[i] > 0) ? 1.f : 0.f;
  __shared__ float l[256];
  l[threadIdx.x] = v;
  __syncthreads();
  for (int s = 128; s > 0; s >>= 1) {
    if (threadIdx.x < s) l[threadIdx.x] += l[threadIdx.x + s];
    __syncthreads();
  }
  if (threadIdx.x == 0 && l[0] != 0.f) atomicAdd(tslot, l[0]);
}

// CSR aggregation; also emits tmask (target = has active in-edge this layer)
__global__ __launch_bounds__(256) void agg_kernel(
    const int* __restrict__ offs, const int* __restrict__ csr,
    const int* __restrict__ src, const float* __restrict__ mult,
    const float* __restrict__ x, const float* __restrict__ feat,
    const float* __restrict__ deps, int layer, float* __restrict__ sbuf,
    int* __restrict__ tmask) {
  const int node = blockIdx.x * 4 + (threadIdx.x >> 6);
  const int lane = threadIdx.x & 63;
  const int gi = layer * Nn + node;
  const int o0 = offs[gi];
  const int o1 = offs[gi + 1];
  float2 acc = {0.f, 0.f};
  for (int p = o0; p < o1; ++p) {
    const int e = csr[p];
    const int sN = src[e];
    const float w = mult[e];
    const float2 xv = *(const float2*)&x[(size_t)sN * 128 + lane * 2];
    acc.x = fmaf(w, xv.x, acc.x);
    acc.y = fmaf(w, xv.y, acc.y);
  }
  if (o1 > o0) {
    const float c = 1.f + deps[layer];
    const float2 f = *(const float2*)&feat[(size_t)node * 128 + lane * 2];
    acc.x = fmaf(c, f.x, acc.x);
    acc.y = fmaf(c, f.y, acc.y);
  }
  *(float2*)&sbuf[(size_t)node * 128 + lane * 2] = acc;
  if (lane == 0) tmask[node] = (o1 > o0) ? 1 : 0;
}

// ---------------- fallback (small ws): atomic scatter ----------------
__global__ __launch_bounds__(256) void edge_kernel(
    const int* __restrict__ src, const int* __restrict__ dst,
    const float* __restrict__ mult, const int* __restrict__ lmask, int layer,
    const float* __restrict__ x, float* __restrict__ EX,
    int* __restrict__ tmask) {
  const int gid = blockIdx.x * 256 + threadIdx.x;
  const int e = gid >> 5;
  if (e >= Ee) return;
  if (lmask[e] != layer) return;
  const int sN = src[e];
  const int dN = dst[e];
  const float w = mult[e];
  const int c4 = (gid & 31) * 4;
  const float4 xv = *(const float4*)&x[(size_t)sN * 128 + c4];
  float* p = &EX[(size_t)dN * 128 + c4];
  atomicAdd(p + 0, xv.x * w);
  atomicAdd(p + 1, xv.y * w);
  atomicAdd(p + 2, xv.z * w);
  atomicAdd(p + 3, xv.w * w);
  if ((gid & 31) == 0) atomicAdd(&tmask[dN], 1);
}

__global__ __launch_bounds__(256) void addfeat_kernel(
    float* __restrict__ sbuf, const float* __restrict__ feat,
    const int* __restrict__ tmask, const float* __restrict__ deps, int layer) {
  const int i4 = blockIdx.x * 256 + threadIdx.x;
  const int row = i4 >> 5;
  if (tmask[row] <= 0) return;
  const float c = 1.f + deps[layer];
  const float4 f = ((const float4*)feat)[i4];
  float4 s = ((const float4*)sbuf)[i4];
  s.x = fmaf(c, f.x, s.x);
  s.y = fmaf(c, f.y, s.y);
  s.z = fmaf(c, f.z, s.z);
  s.w = fmaf(c, f.w, s.w);
  ((float4*)sbuf)[i4] = s;
}

// ---------------- readout: counting-sort pool (no float atomics) ----------
__global__ __launch_bounds__(256) void phist_kernel(const int* __restrict__ ridx,
                                                    const int* __restrict__ batch,
                                                    int* __restrict__ cnt, int n) {
  const int i = blockIdx.x * 256 + threadIdx.x;
  if (i >= n) return;
  atomicAdd(&cnt[batch[ridx[i]]], 1);
}

__global__ void pscan_kernel(int* __restrict__ cnt, int* __restrict__ cur) {
  __shared__ int l[256];
  const int t = threadIdx.x;
  const int v = cnt[t];
  l[t] = v;
  __syncthreads();
  for (int off = 1; off < 256; off <<= 1) {
    const int y = (t >= off) ? l[t - off] : 0;
    __syncthreads();
    l[t] += y;
    __syncthreads();
  }
  const int e = l[t] - v;  // exclusive
  cnt[t] = e;
  cur[t] = e;
}

__global__ __launch_bounds__(256) void pfill_kernel(const int* __restrict__ ridx,
                                                    const int* __restrict__ batch,
                                                    int* __restrict__ cur,
                                                    int* __restrict__ sorted,
                                                    int n) {
  const int i = blockIdx.x * 256 + threadIdx.x;
  if (i >= n) return;
  const int node = ridx[i];
  const int slot = atomicAdd(&cur[batch[node]], 1);
  sorted[slot] = node;
}

__global__ __launch_bounds__(256) void ppool_kernel(const int* __restrict__ sorted,
                                                    const int* __restrict__ offs,
                                                    const float* __restrict__ x,
                                                    float* __restrict__ P, int n) {
  __shared__ float part[4][256];
  const int g = blockIdx.x;
  const int w = threadIdx.x >> 6;
  const int lane = threadIdx.x & 63;
  const int o0 = offs[g];
  const int o1 = (g < Gg - 1) ? offs[g + 1] : n;
  float2 a = {0.f, 0.f};
  for (int p = o0 + w; p < o1; p += 4) {
    const int node = sorted[p];
    const float2 xv = *(const float2*)&x[(size_t)node * 128 + lane * 2];
    a.x += xv.x;
    a.y += xv.y;
  }
  part[w][lane * 2] = a.x;
  part[w][lane * 2 + 1] = a.y;
  __syncthreads();
  if (threadIdx.x < 128) {
    const int c = threadIdx.x;
    P[(size_t)g * 128 + c] = part[0][c] + part[1][c] + part[2][c] + part[3][c];
  }
}

__global__ void out_kernel(const float* __restrict__ P,
                           const float* __restrict__ Wl,
                           const float* __restrict__ bl,
                           float* __restrict__ out) {
  const int gid = blockIdx.x * blockDim.x + threadIdx.x;
  if (gid >= Gg * Tt) return;
  const int g = gid / Tt;
  const int t = gid - g * Tt;
  float acc = 0.f;
  for (int c = 0; c < 128; ++c) acc += P[g * 128 + c] * Wl[c * Tt + t];
  out[gid] = acc * 0.25f + bl[t];
}

extern "C" void kernel_launch(void* const* d_in, const int* in_sizes, int n_in,
                              void* d_out, int out_size, void* d_ws,
                              size_t ws_size, hipStream_t stream) {
  const float* dag_x = (const float*)d_in[0];
  const int* eidx = (const int*)d_in[1];
  const int* src = eidx;
  const int* dst = eidx + Ee;
  const float* mult = (const float*)d_in[2];
  const int* lmask = (const int*)d_in[3];
  const int* batch = (const int*)d_in[4];
  const int* leaves = (const int*)d_in[5];
  const int* readouts = (const int*)d_in[6];
  const float* W1 = (const float*)d_in[7];
  const float* b1 = (const float*)d_in[8];
  const float* g1 = (const float*)d_in[9];
  const float* be1 = (const float*)d_in[10];
  const float* W2 = (const float*)d_in[11];
  const float* b2 = (const float*)d_in[12];
  const float* g2 = (const float*)d_in[13];
  const float* be2 = (const float*)d_in[14];
  const float* dW1 = (const float*)d_in[15];
  const float* db1 = (const float*)d_in[16];
  const float* dg1 = (const float*)d_in[17];
  const float* dbe1 = (const float*)d_in[18];
  const float* dW2 = (const float*)d_in[19];
  const float* db2 = (const float*)d_in[20];
  const float* dg2 = (const float*)d_in[21];
  const float* dbe2 = (const float*)d_in[22];
  const float* deps = (const float*)d_in[23];
  const float* Wl = (const float*)d_in[24];
  const float* bl = (const float*)d_in[25];
  float* out = (float*)d_out;

  const size_t ND = (size_t)Nn * Dd;
  float* feat = (float*)d_ws;          // N*D
  float* xbuf = feat + ND;             // N*D
  float* Abuf = xbuf + ND;             // N*D
  float* stats = Abuf + ND;            // 2048 (strided sum/sumsq)
  float* ss = stats + 2048;            // 256
  float* tcountf = ss + 256;           // 8 (4 used)
  int* tmask = (int*)(tcountf + 8);    // N
  ushort* wsT = (ushort*)(tmask + Nn); // 262144 (8 weight slots, hi+lo)
  int* offs = (int*)(wsT + 262144);    // 3N+4
  int* csr = offs + 3 * Nn + 4;        // E

  // transient overlays (xbuf before it's initialized):
  int* cnts = (int*)xbuf;              // 3N
  int* cursor = cnts + 3 * Nn;         // 3N
  int* bsum = cursor + 3 * Nn;         // 147
  const int nridx = in_sizes[6];       // 80000
  const int nleaves = in_sizes[5];     // 50000
  // pool overlays (Abuf is dead by readout):
  int* pcnt = (int*)Abuf;              // 256 (becomes offsets)
  int* pcur = pcnt + 256;              // 256
  int* sorted = pcur + 256;            // nridx
  float* P = (float*)(sorted + nridx); // G*D

  const size_t needA = (size_t)((char*)(csr + Ee) - (char*)d_ws);
  const bool pathA = ws_size >= needA;

  dim3 blk(256);
  hipMemsetAsync(stats, 0, 2048 * sizeof(float), stream);
  hipMemsetAsync(tcountf, 0, 8 * sizeof(float), stream);
  wsplit_kernel<<<512, blk, 0, stream>>>(W1, W2, dW1, dW2, wsT);

  if (pathA) {
    hipMemsetAsync(cnts, 0, 3 * Nn * sizeof(int), stream);
    deg_count_kernel<<<2344, blk, 0, stream>>>(dst, lmask, cnts);
    for (int l = 0; l < Ll; ++l)
      tcount_kernel<<<391, blk, 0, stream>>>(cnts + l * Nn, tcountf + l);
    scan1_kernel<<<147, blk, 0, stream>>>(cnts, offs, bsum, 3 * Nn);
    scan2_kernel<<<1, blk, 0, stream>>>(bsum, 147);
    scan3_kernel<<<1172, blk, 0, stream>>>(offs, cursor, bsum, 3 * Nn, Ee);
    csr_fill_kernel<<<2344, blk, 0, stream>>>(dst, lmask, cursor, csr);
  }

  // ---- node feature transform ----
  gemm_mfma<64, false, false><<<782, blk, 0, stream>>>(
      dag_x, wsT, wsT + 16384, b1, nullptr, nullptr, Abuf, stats, Nn);
  scaleshift_kernel<<<1, 128, 0, stream>>>(stats, g1, be1, ss, (float)Nn, nullptr);
  gemm_mfma<128, true, false><<<782, blk, 0, stream>>>(
      Abuf, wsT + 32768, wsT + 32768 + 16384, b2, ss, nullptr, Abuf, stats, Nn);
  scaleshift_kernel<<<1, 128, 0, stream>>>(stats, g2, be2, ss, (float)Nn, nullptr);
  normrelu_kernel<<<12500, blk, 0, stream>>>(Abuf, ss, feat);

  hipMemsetAsync(xbuf, 0, ND * sizeof(float), stream);
  scatter_leaves_kernel<<<6250, blk, 0, stream>>>(leaves, feat, xbuf, nleaves);

  // ---- DAG layers ----
  for (int layer = 0; layer < Ll; ++layer) {
    if (pathA) {
      agg_kernel<<<25000, blk, 0, stream>>>(offs, csr, src, mult, xbuf, feat,
                                            deps, layer, Abuf, tmask);
    } else {
      hipMemsetAsync(Abuf, 0, ND * sizeof(float), stream);
      hipMemsetAsync(tmask, 0, Nn * sizeof(int), stream);
      edge_kernel<<<75000, blk, 0, stream>>>(src, dst, mult, lmask, layer,
                                             xbuf, Abuf, tmask);
      tcount_kernel<<<391, blk, 0, stream>>>(tmask, tcountf + layer);
      addfeat_kernel<<<12500, blk, 0, stream>>>(Abuf, feat, tmask, deps, layer);
    }
    const int so1 = (2 + layer) * 32768;
    const int so2 = (5 + layer) * 32768;
    const int po = layer * Dd;
    gemm_mfma<128, false, true><<<782, blk, 0, stream>>>(
        Abuf, wsT + so1, wsT + so1 + 16384, db1 + po, nullptr, tmask, Abuf,
        stats, Nn);
    scaleshift_kernel<<<1, 128, 0, stream>>>(stats, dg1 + po, dbe1 + po, ss,
                                             -1.f, tcountf + layer);
    gemm_mfma<128, true, true><<<782, blk, 0, stream>>>(
        Abuf, wsT + so2, wsT + so2 + 16384, db2 + po, ss, tmask, Abuf, stats,
        Nn);
    scaleshift_kernel<<<1, 128, 0, stream>>>(stats, dg2 + po, dbe2 + po, ss,
                                             -1.f, tcountf + layer);
    normrelu_acc_kernel<<<12500, blk, 0, stream>>>(Abuf, ss, tmask, xbuf);
  }

  // ---- readout (counting sort, no float atomics) ----
  hipMemsetAsync(pcnt, 0, 512 * sizeof(int), stream);
  const int gIdx = (nridx + 255) / 256;
  phist_kernel<<<gIdx, blk, 0, stream>>>(readouts, batch, pcnt, nridx);
  pscan_kernel<<<1, blk, 0, stream>>>(pcnt, pcur);
  pfill_kernel<<<gIdx, blk, 0, stream>>>(readouts, batch, pcur, sorted, nridx);
  ppool_kernel<<<Gg, blk, 0, stream>>>(sorted, pcnt, xbuf, P, nridx);
  out_kernel<<<10, blk, 0, stream>>>(P, Wl, bl, out);
}

// Round 5
// 710.576 us; speedup vs baseline: 3.2052x; 1.1749x over previous
//
#include <hip/hip_runtime.h>

constexpr int Nn = 100000;   // nodes
constexpr int Ee = 600000;   // edges
constexpr int Dd = 128;      // hidden dim
constexpr int Ll = 3;        // DAG layers
constexpr int Gg = 256;      // graphs
constexpr int Tt = 10;       // outputs per graph
constexpr float BN_EPS = 1e-5f;

typedef __attribute__((ext_vector_type(8))) short short8v;
typedef __attribute__((ext_vector_type(4))) float f32x4;

__device__ inline ushort bf_hi(float f) {
  unsigned u = __float_as_uint(f);
  unsigned r = (u + 0x7FFFu + ((u >> 16) & 1u)) >> 16;
  return (ushort)r;
}
__device__ inline float bf_f(ushort h) {
  return __uint_as_float(((unsigned)h) << 16);
}

// ---------------------------------------------------------------------------
// GEMM #1 only: fp32 A (dag_x), K=64, split-bf16 (3-MFMA) emulation.
// C stored as bf16. Epilogue: +bias, store, unmasked col stats.
// ---------------------------------------------------------------------------
__global__ __launch_bounds__(256, 2) void gemm_f32a(
    const float* __restrict__ A, const ushort* __restrict__ WTh,
    const ushort* __restrict__ WTl, const float* __restrict__ bias,
    ushort* __restrict__ C, float* __restrict__ stats, int nrows) {
  constexpr int K = 64, NC = 2;
  __shared__ ushort Ah[128][40];
  __shared__ ushort Al[128][40];
  __shared__ ushort Bh[128][40];
  __shared__ ushort Bl[128][40];
  const int tid = threadIdx.x;
  const int w = tid >> 6;
  const int lane = tid & 63;
  const int lr = lane & 15;
  const int lg = lane >> 4;
  const int lk = lg * 8;
  const int rowBase = blockIdx.x * 128;

  const int r = tid >> 1;
  const int ks = (tid & 1) * 16;
  const int grow = rowBase + r;
  const bool rowOK = grow < nrows;
  const float* aRow = A + (size_t)grow * K + ks;
  const ushort* bRowH = WTh + (size_t)r * K + ks;
  const ushort* bRowL = WTl + (size_t)r * K + ks;

  const f32x4 fzero = {0.f, 0.f, 0.f, 0.f};
  f32x4 acc[2][8];
#pragma unroll
  for (int i = 0; i < 2; ++i)
#pragma unroll
    for (int j = 0; j < 8; ++j) acc[i][j] = fzero;

  float vbuf[2][16];
#pragma unroll
  for (int j = 0; j < 16; j += 4) {
    float4 t = rowOK ? *(const float4*)(aRow + j) : make_float4(0.f, 0.f, 0.f, 0.f);
    vbuf[0][j] = t.x; vbuf[0][j + 1] = t.y; vbuf[0][j + 2] = t.z; vbuf[0][j + 3] = t.w;
  }

#pragma unroll
  for (int c = 0; c < NC; ++c) {
    const int k0 = c * 32;
    // B regs for this chunk (issue first: longest latency)
    const short8v bh0 = *(const short8v*)(bRowH + k0);
    const short8v bh1 = *(const short8v*)(bRowH + k0 + 8);
    const short8v bl0 = *(const short8v*)(bRowL + k0);
    const short8v bl1 = *(const short8v*)(bRowL + k0 + 8);
    if (c + 1 < NC) {
#pragma unroll
      for (int j = 0; j < 16; j += 4) {
        float4 t = rowOK ? *(const float4*)(aRow + (c + 1) * 32 + j)
                         : make_float4(0.f, 0.f, 0.f, 0.f);
        vbuf[(c + 1) & 1][j] = t.x; vbuf[(c + 1) & 1][j + 1] = t.y;
        vbuf[(c + 1) & 1][j + 2] = t.z; vbuf[(c + 1) & 1][j + 3] = t.w;
      }
    }
    {
      short8v h0, h1, l0, l1;
#pragma unroll
      for (int j = 0; j < 8; ++j) {
        const float v = vbuf[c & 1][j];
        const ushort hh = bf_hi(v);
        h0[j] = (short)hh;
        l0[j] = (short)bf_hi(v - bf_f(hh));
      }
#pragma unroll
      for (int j = 0; j < 8; ++j) {
        const float v = vbuf[c & 1][8 + j];
        const ushort hh = bf_hi(v);
        h1[j] = (short)hh;
        l1[j] = (short)bf_hi(v - bf_f(hh));
      }
      *(short8v*)&Ah[r][ks] = h0;
      *(short8v*)&Ah[r][ks + 8] = h1;
      *(short8v*)&Al[r][ks] = l0;
      *(short8v*)&Al[r][ks + 8] = l1;
      *(short8v*)&Bh[r][ks] = bh0;
      *(short8v*)&Bh[r][ks + 8] = bh1;
      *(short8v*)&Bl[r][ks] = bl0;
      *(short8v*)&Bl[r][ks + 8] = bl1;
    }
    __syncthreads();
    const short8v a0h = *(const short8v*)&Ah[w * 32 + lr][lk];
    const short8v a0l = *(const short8v*)&Al[w * 32 + lr][lk];
    const short8v a1h = *(const short8v*)&Ah[w * 32 + 16 + lr][lk];
    const short8v a1l = *(const short8v*)&Al[w * 32 + 16 + lr][lk];
#pragma unroll
    for (int nf = 0; nf < 8; ++nf) {
      const short8v bh = *(const short8v*)&Bh[nf * 16 + lr][lk];
      const short8v bl = *(const short8v*)&Bl[nf * 16 + lr][lk];
      acc[0][nf] = __builtin_amdgcn_mfma_f32_16x16x32_bf16(a0h, bh, acc[0][nf], 0, 0, 0);
      acc[1][nf] = __builtin_amdgcn_mfma_f32_16x16x32_bf16(a1h, bh, acc[1][nf], 0, 0, 0);
      acc[0][nf] = __builtin_amdgcn_mfma_f32_16x16x32_bf16(a0l, bh, acc[0][nf], 0, 0, 0);
      acc[1][nf] = __builtin_amdgcn_mfma_f32_16x16x32_bf16(a1l, bh, acc[1][nf], 0, 0, 0);
      acc[0][nf] = __builtin_amdgcn_mfma_f32_16x16x32_bf16(a0h, bl, acc[0][nf], 0, 0, 0);
      acc[1][nf] = __builtin_amdgcn_mfma_f32_16x16x32_bf16(a1h, bl, acc[1][nf], 0, 0, 0);
    }
    __syncthreads();
  }

  // epilogue: bias, bf16 store, stats
  float* Sred = (float*)&Ah[0][0];  // [4][128]
  float* Sq = Sred + 512;           // [4][128]
#pragma unroll
  for (int nf = 0; nf < 8; ++nf) {
    const int col = nf * 16 + lr;
    const float bcol = bias[col];
    float ps = 0.f, pq = 0.f;
#pragma unroll
    for (int mf = 0; mf < 2; ++mf) {
      const f32x4 vv = acc[mf][nf];
#pragma unroll
      for (int rr = 0; rr < 4; ++rr) {
        const float o = vv[rr] + bcol;
        const int row = rowBase + w * 32 + mf * 16 + lg * 4 + rr;
        if (row < nrows) {
          C[(size_t)row * 128 + col] = bf_hi(o);
          ps += o;
          pq += o * o;
        }
      }
    }
    ps += __shfl_xor(ps, 16);
    ps += __shfl_xor(ps, 32);
    pq += __shfl_xor(pq, 16);
    pq += __shfl_xor(pq, 32);
    if (lg == 0) {
      Sred[w * 128 + col] = ps;
      Sq[w * 128 + col] = pq;
    }
  }
  __syncthreads();
  {
    const int col = tid & 127;
    float s = 0.f;
    if ((tid >> 7) == 0) {
#pragma unroll
      for (int q = 0; q < 4; ++q) s += Sred[q * 128 + col];
      atomicAdd(&stats[col * 8], s);
    } else {
#pragma unroll
      for (int q = 0; q < 4; ++q) s += Sq[q * 128 + col];
      atomicAdd(&stats[(128 + col) * 8], s);
    }
  }
}

// ---------------------------------------------------------------------------
// bf16-A GEMM: C[N][128] = op(A)[N][128] @ W + bias; A bf16, B hi/lo split
// (2 MFMAs per fragment). NORM_A: relu(a*ss+sh) applied in staging.
// C stored bf16. Epilogue: masked col stats. In-place safe (C==A).
// ---------------------------------------------------------------------------
template <bool NORM_A, bool MASKED>
__global__ __launch_bounds__(256, 3) void gemm_bf16(
    const ushort* __restrict__ A, const ushort* __restrict__ WTh,
    const ushort* __restrict__ WTl, const float* __restrict__ bias,
    const float* __restrict__ ssA, const int* __restrict__ tmask,
    ushort* __restrict__ C, float* __restrict__ stats, int nrows) {
  constexpr int K = 128, NC = 4;
  __shared__ ushort Ah[128][40];
  __shared__ ushort Bh[128][40];
  __shared__ ushort Bl[128][40];
  __shared__ float ssS[256];
  const int tid = threadIdx.x;
  const int w = tid >> 6;
  const int lane = tid & 63;
  const int lr = lane & 15;
  const int lg = lane >> 4;
  const int lk = lg * 8;
  const int rowBase = blockIdx.x * 128;

  const int r = tid >> 1;
  const int ks = (tid & 1) * 16;
  const int grow = rowBase + r;
  const bool rowOK = grow < nrows;
  const ushort* aRow = A + (size_t)grow * K + ks;
  const ushort* bRowH = WTh + (size_t)r * K + ks;
  const ushort* bRowL = WTl + (size_t)r * K + ks;

  if (NORM_A) ssS[tid] = ssA[tid];

  const f32x4 fzero = {0.f, 0.f, 0.f, 0.f};
  f32x4 acc[2][8];
#pragma unroll
  for (int i = 0; i < 2; ++i)
#pragma unroll
    for (int j = 0; j < 8; ++j) acc[i][j] = fzero;

  const short8v szero = {0, 0, 0, 0, 0, 0, 0, 0};
  short8v av[2][2];
  av[0][0] = rowOK ? *(const short8v*)(aRow) : szero;
  av[0][1] = rowOK ? *(const short8v*)(aRow + 8) : szero;
  if (NORM_A) __syncthreads();

#pragma unroll
  for (int c = 0; c < NC; ++c) {
    const int k0 = c * 32;
    const short8v bh0 = *(const short8v*)(bRowH + k0);
    const short8v bh1 = *(const short8v*)(bRowH + k0 + 8);
    const short8v bl0 = *(const short8v*)(bRowL + k0);
    const short8v bl1 = *(const short8v*)(bRowL + k0 + 8);
    if (c + 1 < NC) {
      av[(c + 1) & 1][0] = rowOK ? *(const short8v*)(aRow + (c + 1) * 32) : szero;
      av[(c + 1) & 1][1] = rowOK ? *(const short8v*)(aRow + (c + 1) * 32 + 8) : szero;
    }
    {
      short8v h0 = av[c & 1][0];
      short8v h1 = av[c & 1][1];
      if (NORM_A) {
        float v[16];
#pragma unroll
        for (int j = 0; j < 8; ++j) v[j] = bf_f((ushort)h0[j]);
#pragma unroll
        for (int j = 0; j < 8; ++j) v[8 + j] = bf_f((ushort)h1[j]);
#pragma unroll
        for (int j = 0; j < 16; ++j) {
          const int kc = k0 + ks + j;
          v[j] = fmaxf(fmaf(v[j], ssS[kc], ssS[128 + kc]), 0.f);
        }
#pragma unroll
        for (int j = 0; j < 8; ++j) h0[j] = (short)bf_hi(v[j]);
#pragma unroll
        for (int j = 0; j < 8; ++j) h1[j] = (short)bf_hi(v[8 + j]);
      }
      *(short8v*)&Ah[r][ks] = h0;
      *(short8v*)&Ah[r][ks + 8] = h1;
      *(short8v*)&Bh[r][ks] = bh0;
      *(short8v*)&Bh[r][ks + 8] = bh1;
      *(short8v*)&Bl[r][ks] = bl0;
      *(short8v*)&Bl[r][ks + 8] = bl1;
    }
    __syncthreads();
    const short8v a0 = *(const short8v*)&Ah[w * 32 + lr][lk];
    const short8v a1 = *(const short8v*)&Ah[w * 32 + 16 + lr][lk];
#pragma unroll
    for (int nf = 0; nf < 8; ++nf) {
      const short8v bh = *(const short8v*)&Bh[nf * 16 + lr][lk];
      const short8v bl = *(const short8v*)&Bl[nf * 16 + lr][lk];
      acc[0][nf] = __builtin_amdgcn_mfma_f32_16x16x32_bf16(a0, bh, acc[0][nf], 0, 0, 0);
      acc[1][nf] = __builtin_amdgcn_mfma_f32_16x16x32_bf16(a1, bh, acc[1][nf], 0, 0, 0);
      acc[0][nf] = __builtin_amdgcn_mfma_f32_16x16x32_bf16(a0, bl, acc[0][nf], 0, 0, 0);
      acc[1][nf] = __builtin_amdgcn_mfma_f32_16x16x32_bf16(a1, bl, acc[1][nf], 0, 0, 0);
    }
    __syncthreads();
  }

  // epilogue
  float mrow[2][4];
#pragma unroll
  for (int mf = 0; mf < 2; ++mf)
#pragma unroll
    for (int rr = 0; rr < 4; ++rr) {
      const int row = rowBase + w * 32 + mf * 16 + lg * 4 + rr;
      float m = 0.f;
      if (row < nrows) m = MASKED ? ((tmask[row] > 0) ? 1.f : 0.f) : 1.f;
      mrow[mf][rr] = m;
    }
  float* Sred = (float*)&Ah[0][0];  // [4][128]
  float* Sq = Sred + 512;           // [4][128]
#pragma unroll
  for (int nf = 0; nf < 8; ++nf) {
    const int col = nf * 16 + lr;
    const float bcol = bias[col];
    float ps = 0.f, pq = 0.f;
#pragma unroll
    for (int mf = 0; mf < 2; ++mf) {
      const f32x4 vv = acc[mf][nf];
#pragma unroll
      for (int rr = 0; rr < 4; ++rr) {
        const float o = vv[rr] + bcol;
        const int row = rowBase + w * 32 + mf * 16 + lg * 4 + rr;
        if (row < nrows) C[(size_t)row * 128 + col] = bf_hi(o);
        const float mo = mrow[mf][rr] * o;
        ps += mo;
        pq += mo * o;
      }
    }
    ps += __shfl_xor(ps, 16);
    ps += __shfl_xor(ps, 32);
    pq += __shfl_xor(pq, 16);
    pq += __shfl_xor(pq, 32);
    if (lg == 0) {
      Sred[w * 128 + col] = ps;
      Sq[w * 128 + col] = pq;
    }
  }
  __syncthreads();
  {
    const int col = tid & 127;
    float s = 0.f;
    if ((tid >> 7) == 0) {
#pragma unroll
      for (int q = 0; q < 4; ++q) s += Sred[q * 128 + col];
      atomicAdd(&stats[col * 8], s);
    } else {
#pragma unroll
      for (int q = 0; q < 4; ++q) s += Sq[q * 128 + col];
      atomicAdd(&stats[(128 + col) * 8], s);
    }
  }
}

// Weight transpose + hi/lo split: 8 slots of 32768 ushorts (hi, then lo@+16384)
__global__ __launch_bounds__(256) void wsplit_kernel(
    const float* __restrict__ W1, const float* __restrict__ W2,
    const float* __restrict__ dW1, const float* __restrict__ dW2,
    ushort* __restrict__ wsT) {
  const int t = blockIdx.x * 256 + threadIdx.x;
  const int slot = t >> 14;
  const int idx = t & 16383;
  if (slot >= 8) return;
  const int Ks = (slot == 0) ? 64 : 128;
  if (idx >= 128 * Ks) return;
  const int c = idx / Ks;
  const int k = idx - c * Ks;
  float v;
  if (slot == 0) v = W1[k * 128 + c];
  else if (slot == 1) v = W2[k * 128 + c];
  else if (slot < 5) v = dW1[(slot - 2) * 16384 + k * 128 + c];
  else v = dW2[(slot - 5) * 16384 + k * 128 + c];
  const ushort h = bf_hi(v);
  const ushort l = bf_hi(v - bf_f(h));
  wsT[slot * 32768 + c * Ks + k] = h;
  wsT[slot * 32768 + 16384 + c * Ks + k] = l;
}

__global__ void scaleshift_kernel(float* __restrict__ stats,
                                  const float* __restrict__ g,
                                  const float* __restrict__ be,
                                  float* __restrict__ ss, float cntFixed,
                                  const float* __restrict__ cntPtr) {
  const int c = threadIdx.x;  // 128 threads
  const float cnt = cntPtr ? fmaxf(cntPtr[0], 1.f) : cntFixed;
  const float S = stats[c * 8];
  const float Q = stats[(128 + c) * 8];
  stats[c * 8] = 0.f;
  stats[(128 + c) * 8] = 0.f;
  const float m = S / cnt;
  const float v = Q / cnt - m * m;
  const float sc = g[c] * rsqrtf(v + BN_EPS);
  ss[c] = sc;
  ss[128 + c] = be[c] - m * sc;
}

// feat = relu(y*sc+sh)  (bf16 in/out; thread handles 4 cols)
__global__ __launch_bounds__(256) void normrelu_kernel(
    const ushort* __restrict__ in, const float* __restrict__ ss,
    ushort* __restrict__ out) {
  const int i4 = blockIdx.x * 256 + threadIdx.x;
  const int c4 = (i4 & 31) * 4;
  const ushort4 v = ((const ushort4*)in)[i4];
  const float4 sc = *(const float4*)&ss[c4];
  const float4 sh = *(const float4*)&ss[128 + c4];
  ushort4 o;
  o.x = bf_hi(fmaxf(fmaf(bf_f(v.x), sc.x, sh.x), 0.f));
  o.y = bf_hi(fmaxf(fmaf(bf_f(v.y), sc.y, sh.y), 0.f));
  o.z = bf_hi(fmaxf(fmaf(bf_f(v.z), sc.z, sh.z), 0.f));
  o.w = bf_hi(fmaxf(fmaf(bf_f(v.w), sc.w, sh.w), 0.f));
  ((ushort4*)out)[i4] = o;
}

// x += (tmask>0) * relu(y*sc+sh)
__global__ __launch_bounds__(256) void normrelu_acc_kernel(
    const ushort* __restrict__ in, const float* __restrict__ ss,
    const int* __restrict__ tmask, ushort* __restrict__ x) {
  const int i4 = blockIdx.x * 256 + threadIdx.x;
  const int row = i4 >> 5;
  if (tmask[row] <= 0) return;
  const int c4 = (i4 & 31) * 4;
  const ushort4 v = ((const ushort4*)in)[i4];
  const float4 sc = *(const float4*)&ss[c4];
  const float4 sh = *(const float4*)&ss[128 + c4];
  ushort4 xo = ((const ushort4*)x)[i4];
  xo.x = bf_hi(bf_f(xo.x) + fmaxf(fmaf(bf_f(v.x), sc.x, sh.x), 0.f));
  xo.y = bf_hi(bf_f(xo.y) + fmaxf(fmaf(bf_f(v.y), sc.y, sh.y), 0.f));
  xo.z = bf_hi(bf_f(xo.z) + fmaxf(fmaf(bf_f(v.z), sc.z, sh.z), 0.f));
  xo.w = bf_hi(bf_f(xo.w) + fmaxf(fmaf(bf_f(v.w), sc.w, sh.w), 0.f));
  ((ushort4*)x)[i4] = xo;
}

__global__ __launch_bounds__(256) void scatter_leaves_kernel(
    const int* __restrict__ leaves, const ushort* __restrict__ feat,
    ushort* __restrict__ x, int nl) {
  const int gid = blockIdx.x * 256 + threadIdx.x;
  const int j = gid >> 5;
  if (j >= nl) return;
  const int node = leaves[j];
  const int c4 = (gid & 31) * 4;
  *(ushort4*)&x[(size_t)node * 128 + c4] =
      *(const ushort4*)&feat[(size_t)node * 128 + c4];
}

// ---------------- CSR build (pairs = packed (src, mult)) ----------------
__global__ __launch_bounds__(256) void deg_count_kernel(
    const int* __restrict__ dst, const int* __restrict__ lmask,
    int* __restrict__ cnts) {
  const int e = blockIdx.x * 256 + threadIdx.x;
  if (e >= Ee) return;
  atomicAdd(&cnts[lmask[e] * Nn + dst[e]], 1);
}

__global__ __launch_bounds__(256) void scan1_kernel(const int* __restrict__ in,
                                                    int* __restrict__ out,
                                                    int* __restrict__ bsum,
                                                    int n) {
  __shared__ int lds[256];
  const int tid = threadIdx.x;
  const int base = blockIdx.x * 2048 + tid * 8;
  int vals[8];
  int tsum = 0;
#pragma unroll
  for (int j = 0; j < 8; ++j) {
    const int v = (base + j < n) ? in[base + j] : 0;
    vals[j] = tsum;
    tsum += v;
  }
  lds[tid] = tsum;
  __syncthreads();
  for (int off = 1; off < 256; off <<= 1) {
    const int y = (tid >= off) ? lds[tid - off] : 0;
    __syncthreads();
    lds[tid] += y;
    __syncthreads();
  }
  const int texcl = (tid > 0) ? lds[tid - 1] : 0;
#pragma unroll
  for (int j = 0; j < 8; ++j)
    if (base + j < n) out[base + j] = texcl + vals[j];
  if (tid == 255) bsum[blockIdx.x] = lds[255];
}

__global__ void scan2_kernel(int* __restrict__ bsum, int nb) {
  __shared__ int lds[256];
  const int tid = threadIdx.x;
  const int v = (tid < nb) ? bsum[tid] : 0;
  lds[tid] = v;
  __syncthreads();
  for (int off = 1; off < 256; off <<= 1) {
    const int y = (tid >= off) ? lds[tid - off] : 0;
    __syncthreads();
    lds[tid] += y;
    __syncthreads();
  }
  if (tid < nb) bsum[tid] = lds[tid] - v;  // exclusive
}

__global__ __launch_bounds__(256) void scan3_kernel(int* __restrict__ out,
                                                    int* __restrict__ cursor,
                                                    const int* __restrict__ bsum,
                                                    int n, int etot) {
  const int i = blockIdx.x * 256 + threadIdx.x;
  if (i >= n) return;
  const int v = out[i] + bsum[i >> 11];
  out[i] = v;
  cursor[i] = v;
  if (i == n - 1) out[n] = etot;
}

__global__ __launch_bounds__(256) void csr_fill_kernel(
    const int* __restrict__ src, const int* __restrict__ dst,
    const float* __restrict__ mult, const int* __restrict__ lmask,
    int* __restrict__ cursor, int2* __restrict__ pairs) {
  const int e = blockIdx.x * 256 + threadIdx.x;
  if (e >= Ee) return;
  const int slot = atomicAdd(&cursor[lmask[e] * Nn + dst[e]], 1);
  pairs[slot] = make_int2(src[e], __float_as_int(mult[e]));
}

__global__ __launch_bounds__(256) void tcount_kernel(
    const int* __restrict__ degBase, float* __restrict__ tslot) {
  const int i = blockIdx.x * 256 + threadIdx.x;
  float v = (i < Nn && degBase[i] > 0) ? 1.f : 0.f;
  __shared__ float l[256];
  l[threadIdx.x] = v;
  __syncthreads();
  for (int s = 128; s > 0; s >>= 1) {
    if (threadIdx.x < s) l[threadIdx.x] += l[threadIdx.x + s];
    __syncthreads();
  }
  if (threadIdx.x == 0 && l[0] != 0.f) atomicAdd(tslot, l[0]);
}

// CSR aggregation (bf16): s = sum w*x[src] + (deg>0)(1+eps)feat; emits tmask.
// One 64-lane wave per node, ushort2/lane, 2-wide unrolled edge loop.
__global__ __launch_bounds__(256) void agg_kernel(
    const int* __restrict__ offs, const int2* __restrict__ pairs,
    const ushort* __restrict__ x, const ushort* __restrict__ feat,
    const float* __restrict__ deps, int layer, ushort* __restrict__ sbuf,
    int* __restrict__ tmask) {
  const int node = blockIdx.x * 4 + (threadIdx.x >> 6);
  const int lane = threadIdx.x & 63;
  const int gi = layer * Nn + node;
  const int o0 = offs[gi];
  const int o1 = offs[gi + 1];
  ushort2 fv = make_ushort2(0, 0);
  if (o1 > o0) fv = *(const ushort2*)&feat[(size_t)node * 128 + lane * 2];
  float ax = 0.f, ay = 0.f;
  for (int p = o0; p < o1; p += 2) {
    const int2 pr0 = pairs[p];
    const int2 pr1 = (p + 1 < o1) ? pairs[p + 1] : make_int2(0, 0);
    const ushort2 x0 = *(const ushort2*)&x[(size_t)pr0.x * 128 + lane * 2];
    const ushort2 x1 = *(const ushort2*)&x[(size_t)pr1.x * 128 + lane * 2];
    const float w0 = __int_as_float(pr0.y);
    const float w1 = __int_as_float(pr1.y);
    ax = fmaf(w0, bf_f(x0.x), ax);
    ay = fmaf(w0, bf_f(x0.y), ay);
    ax = fmaf(w1, bf_f(x1.x), ax);
    ay = fmaf(w1, bf_f(x1.y), ay);
  }
  if (o1 > o0) {
    const float c = 1.f + deps[layer];
    ax = fmaf(c, bf_f(fv.x), ax);
    ay = fmaf(c, bf_f(fv.y), ay);
  }
  ushort2 o;
  o.x = bf_hi(ax);
  o.y = bf_hi(ay);
  *(ushort2*)&sbuf[(size_t)node * 128 + lane * 2] = o;
  if (lane == 0) tmask[node] = (o1 > o0) ? 1 : 0;
}

// ---------------- readout: counting-sort pool ----------------
__global__ __launch_bounds__(256) void phist_kernel(const int* __restrict__ ridx,
                                                    const int* __restrict__ batch,
                                                    int* __restrict__ cnt, int n) {
  const int i = blockIdx.x * 256 + threadIdx.x;
  if (i >= n) return;
  atomicAdd(&cnt[batch[ridx[i]]], 1);
}

__global__ void pscan_kernel(int* __restrict__ cnt, int* __restrict__ cur) {
  __shared__ int l[256];
  const int t = threadIdx.x;
  const int v = cnt[t];
  l[t] = v;
  __syncthreads();
  for (int off = 1; off < 256; off <<= 1) {
    const int y = (t >= off) ? l[t - off] : 0;
    __syncthreads();
    l[t] += y;
    __syncthreads();
  }
  const int e = l[t] - v;  // exclusive
  cnt[t] = e;
  cur[t] = e;
}

__global__ __launch_bounds__(256) void pfill_kernel(const int* __restrict__ ridx,
                                                    const int* __restrict__ batch,
                                                    int* __restrict__ cur,
                                                    int* __restrict__ sorted,
                                                    int n) {
  const int i = blockIdx.x * 256 + threadIdx.x;
  if (i >= n) return;
  const int node = ridx[i];
  const int slot = atomicAdd(&cur[batch[node]], 1);
  sorted[slot] = node;
}

__global__ __launch_bounds__(256) void ppool_kernel(const int* __restrict__ sorted,
                                                    const int* __restrict__ offs,
                                                    const ushort* __restrict__ x,
                                                    float* __restrict__ P, int n) {
  __shared__ float part[4][256];
  const int g = blockIdx.x;
  const int w = threadIdx.x >> 6;
  const int lane = threadIdx.x & 63;
  const int o0 = offs[g];
  const int o1 = (g < Gg - 1) ? offs[g + 1] : n;
  float ax = 0.f, ay = 0.f;
  for (int p = o0 + w; p < o1; p += 4) {
    const int node = sorted[p];
    const ushort2 xv = *(const ushort2*)&x[(size_t)node * 128 + lane * 2];
    ax += bf_f(xv.x);
    ay += bf_f(xv.y);
  }
  part[w][lane * 2] = ax;
  part[w][lane * 2 + 1] = ay;
  __syncthreads();
  if (threadIdx.x < 128) {
    const int c = threadIdx.x;
    P[(size_t)g * 128 + c] = part[0][c] + part[1][c] + part[2][c] + part[3][c];
  }
}

__global__ void out_kernel(const float* __restrict__ P,
                           const float* __restrict__ Wl,
                           const float* __restrict__ bl,
                           float* __restrict__ out) {
  const int gid = blockIdx.x * blockDim.x + threadIdx.x;
  if (gid >= Gg * Tt) return;
  const int g = gid / Tt;
  const int t = gid - g * Tt;
  float acc = 0.f;
  for (int c = 0; c < 128; ++c) acc += P[g * 128 + c] * Wl[c * Tt + t];
  out[gid] = acc * 0.25f + bl[t];
}

extern "C" void kernel_launch(void* const* d_in, const int* in_sizes, int n_in,
                              void* d_out, int out_size, void* d_ws,
                              size_t ws_size, hipStream_t stream) {
  const float* dag_x = (const float*)d_in[0];
  const int* eidx = (const int*)d_in[1];
  const int* src = eidx;
  const int* dst = eidx + Ee;
  const float* mult = (const float*)d_in[2];
  const int* lmask = (const int*)d_in[3];
  const int* batch = (const int*)d_in[4];
  const int* leaves = (const int*)d_in[5];
  const int* readouts = (const int*)d_in[6];
  const float* W1 = (const float*)d_in[7];
  const float* b1 = (const float*)d_in[8];
  const float* g1 = (const float*)d_in[9];
  const float* be1 = (const float*)d_in[10];
  const float* W2 = (const float*)d_in[11];
  const float* b2 = (const float*)d_in[12];
  const float* g2 = (const float*)d_in[13];
  const float* be2 = (const float*)d_in[14];
  const float* dW1 = (const float*)d_in[15];
  const float* db1 = (const float*)d_in[16];
  const float* dg1 = (const float*)d_in[17];
  const float* dbe1 = (const float*)d_in[18];
  const float* dW2 = (const float*)d_in[19];
  const float* db2 = (const float*)d_in[20];
  const float* dg2 = (const float*)d_in[21];
  const float* dbe2 = (const float*)d_in[22];
  const float* deps = (const float*)d_in[23];
  const float* Wl = (const float*)d_in[24];
  const float* bl = (const float*)d_in[25];
  float* out = (float*)d_out;

  const size_t ND = (size_t)Nn * Dd;
  ushort* feat = (ushort*)d_ws;          // ND bf16
  ushort* xbuf = feat + ND;              // ND bf16
  ushort* Abuf = xbuf + ND;              // ND bf16
  float* stats = (float*)(Abuf + ND);    // 2048 (strided sum/sumsq)
  float* ss = stats + 2048;              // 256
  float* tcountf = ss + 256;             // 8 (4 used)
  int* tmask = (int*)(tcountf + 8);      // N
  ushort* wsT = (ushort*)(tmask + Nn);   // 262144 (8 weight slots, hi+lo)
  int* offs = (int*)(wsT + 262144);      // 3N+4
  int2* pairs = (int2*)(offs + 3 * Nn + 4);  // E pairs (src, mult)

  // transient overlays (xbuf region before it's initialized):
  int* cnts = (int*)xbuf;                // 3N
  int* cursor = cnts + 3 * Nn;           // 3N (fits: 2.4MB < 25.6MB)
  int* bsum = cursor + 3 * Nn;           // 147
  const int nridx = in_sizes[6];         // 80000
  const int nleaves = in_sizes[5];       // 50000
  // pool overlays (Abuf is dead by readout):
  int* pcnt = (int*)Abuf;                // 256 (becomes offsets)
  int* pcur = pcnt + 256;                // 256
  int* sorted = pcur + 256;              // nridx
  float* P = (float*)(sorted + nridx);   // G*D

  dim3 blk(256);
  hipMemsetAsync(stats, 0, 2048 * sizeof(float), stream);
  hipMemsetAsync(tcountf, 0, 8 * sizeof(float), stream);
  wsplit_kernel<<<512, blk, 0, stream>>>(W1, W2, dW1, dW2, wsT);

  // ---- CSR build ----
  hipMemsetAsync(cnts, 0, 3 * Nn * sizeof(int), stream);
  deg_count_kernel<<<2344, blk, 0, stream>>>(dst, lmask, cnts);
  for (int l = 0; l < Ll; ++l)
    tcount_kernel<<<391, blk, 0, stream>>>(cnts + l * Nn, tcountf + l);
  scan1_kernel<<<147, blk, 0, stream>>>(cnts, offs, bsum, 3 * Nn);
  scan2_kernel<<<1, blk, 0, stream>>>(bsum, 147);
  scan3_kernel<<<1172, blk, 0, stream>>>(offs, cursor, bsum, 3 * Nn, Ee);
  csr_fill_kernel<<<2344, blk, 0, stream>>>(src, dst, mult, lmask, cursor, pairs);

  // ---- node feature transform ----
  gemm_f32a<<<782, blk, 0, stream>>>(dag_x, wsT, wsT + 16384, b1, Abuf, stats, Nn);
  scaleshift_kernel<<<1, 128, 0, stream>>>(stats, g1, be1, ss, (float)Nn, nullptr);
  gemm_bf16<true, false><<<782, blk, 0, stream>>>(
      Abuf, wsT + 32768, wsT + 32768 + 16384, b2, ss, nullptr, Abuf, stats, Nn);
  scaleshift_kernel<<<1, 128, 0, stream>>>(stats, g2, be2, ss, (float)Nn, nullptr);
  normrelu_kernel<<<12500, blk, 0, stream>>>(Abuf, ss, feat);

  hipMemsetAsync(xbuf, 0, ND * sizeof(ushort), stream);
  scatter_leaves_kernel<<<6250, blk, 0, stream>>>(leaves, feat, xbuf, nleaves);

  // ---- DAG layers ----
  for (int layer = 0; layer < Ll; ++layer) {
    agg_kernel<<<25000, blk, 0, stream>>>(offs, pairs, xbuf, feat, deps, layer,
                                          Abuf, tmask);
    const int so1 = (2 + layer) * 32768;
    const int so2 = (5 + layer) * 32768;
    const int po = layer * Dd;
    gemm_bf16<false, true><<<782, blk, 0, stream>>>(
        Abuf, wsT + so1, wsT + so1 + 16384, db1 + po, nullptr, tmask, Abuf,
        stats, Nn);
    scaleshift_kernel<<<1, 128, 0, stream>>>(stats, dg1 + po, dbe1 + po, ss,
                                             -1.f, tcountf + layer);
    gemm_bf16<true, true><<<782, blk, 0, stream>>>(
        Abuf, wsT + so2, wsT + so2 + 16384, db2 + po, ss, tmask, Abuf, stats,
        Nn);
    scaleshift_kernel<<<1, 128, 0, stream>>>(stats, dg2 + po, dbe2 + po, ss,
                                             -1.f, tcountf + layer);
    normrelu_acc_kernel<<<12500, blk, 0, stream>>>(Abuf, ss, tmask, xbuf);
  }

  // ---- readout (counting sort, no float atomics) ----
  hipMemsetAsync(pcnt, 0, 512 * sizeof(int), stream);
  const int gIdx = (nridx + 255) / 256;
  phist_kernel<<<gIdx, blk, 0, stream>>>(readouts, batch, pcnt, nridx);
  pscan_kernel<<<1, blk, 0, stream>>>(pcnt, pcur);
  pfill_kernel<<<gIdx, blk, 0, stream>>>(readouts, batch, pcur, sorted, nridx);
  ppool_kernel<<<Gg, blk, 0, stream>>>(sorted, pcnt, xbuf, P, nridx);
  out_kernel<<<10, blk, 0, stream>>>(P, Wl, bl, out);
}

// Round 6
// 658.267 us; speedup vs baseline: 3.4599x; 1.0795x over previous
//
#include <hip/hip_runtime.h>

constexpr int Nn = 100000;   // nodes
constexpr int Ee = 600000;   // edges
constexpr int Dd = 128;      // hidden dim
constexpr int Ll = 3;        // DAG layers
constexpr int Gg = 256;      // graphs
constexpr int Tt = 10;       // outputs per graph
constexpr float BN_EPS = 1e-5f;

typedef __attribute__((ext_vector_type(8))) short short8v;
typedef __attribute__((ext_vector_type(4))) float f32x4;

__device__ inline ushort bf_hi(float f) {
  unsigned u = __float_as_uint(f);
  unsigned r = (u + 0x7FFFu + ((u >> 16) & 1u)) >> 16;
  return (ushort)r;
}
__device__ inline float bf_f(ushort h) {
  return __uint_as_float(((unsigned)h) << 16);
}

// Compute BN scale/shift from a stats slot into LDS ssS[256] (threads 0..127).
__device__ inline void compute_ss_lds(const float* __restrict__ stats,
                                      const float* __restrict__ g,
                                      const float* __restrict__ be, float cnt,
                                      float* ssS) {
  const int c = threadIdx.x;
  if (c < 128) {
    const float S = stats[c * 8];
    const float Q = stats[(128 + c) * 8];
    const float m = S / cnt;
    const float v = Q / cnt - m * m;
    const float sc = g[c] * rsqrtf(v + BN_EPS);
    ssS[c] = sc;
    ssS[128 + c] = be[c] - m * sc;
  }
}

// ---------------------------------------------------------------------------
// B-resident barrier-free GEMM (bf16 A): C[N][64-slice] = op(A)@W + bias.
// Tile 128 rows x 64 cols; grid = 782*2 (rt,ct). B (hi/lo) staged ONCE into
// XOR-swizzled LDS; zero barriers in K-loop; A fragments prefetched to regs.
// NORM_A: BN scale/shift computed in prologue from statsIn, applied + relu.
// Epilogue: +bias, bf16 store, (masked) col stats -> statsOut (strided x8).
// NOT in-place safe (column-split): C must differ from A.
// ---------------------------------------------------------------------------
template <bool NORM_A, bool MASKED>
__global__ __launch_bounds__(256, 4) void gemm_bf16(
    const ushort* __restrict__ A, const ushort* __restrict__ WTh,
    const ushort* __restrict__ WTl, const float* __restrict__ bias,
    const float* __restrict__ statsIn, const float* __restrict__ gN,
    const float* __restrict__ beN, const float* __restrict__ cntPtr,
    const int* __restrict__ tmask, ushort* __restrict__ C,
    float* __restrict__ statsOut, int nrows) {
  __shared__ ushort Bh[64 * 128];
  __shared__ ushort Bl[64 * 128];
  __shared__ float ssS[256];
  const int tid = threadIdx.x;
  const int w = tid >> 6, lane = tid & 63, lr = lane & 15, lg = lane >> 4;
  const int rt = blockIdx.x >> 1, ct = blockIdx.x & 1;
  const int rowBase = rt * 128, cBase = ct * 64;

  // ---- stage B once (swizzled: byte ^= (col&7)<<4 within 256B row) ----
  {
    const int cc = tid >> 2;
    const ushort* sH = WTh + (size_t)(cBase + cc) * 128;
    const ushort* sL = WTl + (size_t)(cBase + cc) * 128;
    char* BhB = (char*)Bh;
    char* BlB = (char*)Bl;
#pragma unroll
    for (int i = 0; i < 4; ++i) {
      const int slot = (tid & 3) * 4 + i;
      const int off = (cc * 256 + slot * 16) ^ ((cc & 7) << 4);
      *(short8v*)(BhB + off) = *(const short8v*)(sH + slot * 8);
      *(short8v*)(BlB + off) = *(const short8v*)(sL + slot * 8);
    }
  }
  if (NORM_A) {
    const float cnt = cntPtr ? fmaxf(cntPtr[0], 1.f) : (float)nrows;
    compute_ss_lds(statsIn, gN, beN, cnt, ssS);
  }

  // ---- prefetch all A fragments (8 x 16B per lane) ----
  const int row0 = rowBase + w * 32 + lr;
  const int row1 = row0 + 16;
  const bool ok0 = row0 < nrows, ok1 = row1 < nrows;
  const short8v szero = {0, 0, 0, 0, 0, 0, 0, 0};
  const ushort* aP0 = A + (size_t)row0 * 128 + lg * 8;
  const ushort* aP1 = A + (size_t)row1 * 128 + lg * 8;
  short8v ar0[4], ar1[4];
#pragma unroll
  for (int c = 0; c < 4; ++c) {
    ar0[c] = ok0 ? *(const short8v*)(aP0 + c * 32) : szero;
    ar1[c] = ok1 ? *(const short8v*)(aP1 + c * 32) : szero;
  }
  __syncthreads();

  const f32x4 fzero = {0.f, 0.f, 0.f, 0.f};
  f32x4 acc[2][4];
#pragma unroll
  for (int i = 0; i < 2; ++i)
#pragma unroll
    for (int j = 0; j < 4; ++j) acc[i][j] = fzero;

  const char* BhB = (const char*)Bh;
  const char* BlB = (const char*)Bl;
#pragma unroll
  for (int c = 0; c < 4; ++c) {
    short8v a0 = ar0[c], a1 = ar1[c];
    if (NORM_A) {
      const int kb = c * 32 + lg * 8;
      const float4 s0 = *(const float4*)&ssS[kb];
      const float4 s1 = *(const float4*)&ssS[kb + 4];
      const float4 h0 = *(const float4*)&ssS[128 + kb];
      const float4 h1 = *(const float4*)&ssS[128 + kb + 4];
      const float sv[8] = {s0.x, s0.y, s0.z, s0.w, s1.x, s1.y, s1.z, s1.w};
      const float hv[8] = {h0.x, h0.y, h0.z, h0.w, h1.x, h1.y, h1.z, h1.w};
#pragma unroll
      for (int j = 0; j < 8; ++j) {
        a0[j] = (short)bf_hi(fmaxf(fmaf(bf_f((ushort)a0[j]), sv[j], hv[j]), 0.f));
        a1[j] = (short)bf_hi(fmaxf(fmaf(bf_f((ushort)a1[j]), sv[j], hv[j]), 0.f));
      }
    }
#pragma unroll
    for (int nf = 0; nf < 4; ++nf) {
      const int brow = nf * 16 + lr;
      const int off = (brow * 256 + (c * 4 + lg) * 16) ^ ((lr & 7) << 4);
      const short8v bh = *(const short8v*)(BhB + off);
      const short8v bl = *(const short8v*)(BlB + off);
      acc[0][nf] = __builtin_amdgcn_mfma_f32_16x16x32_bf16(a0, bh, acc[0][nf], 0, 0, 0);
      acc[1][nf] = __builtin_amdgcn_mfma_f32_16x16x32_bf16(a1, bh, acc[1][nf], 0, 0, 0);
      acc[0][nf] = __builtin_amdgcn_mfma_f32_16x16x32_bf16(a0, bl, acc[0][nf], 0, 0, 0);
      acc[1][nf] = __builtin_amdgcn_mfma_f32_16x16x32_bf16(a1, bl, acc[1][nf], 0, 0, 0);
    }
  }

  // ---- epilogue ----
  float mrow[2][4];
#pragma unroll
  for (int mf = 0; mf < 2; ++mf)
#pragma unroll
    for (int rr = 0; rr < 4; ++rr) {
      const int row = rowBase + w * 32 + mf * 16 + lg * 4 + rr;
      float m = 0.f;
      if (row < nrows) m = MASKED ? ((tmask[row] > 0) ? 1.f : 0.f) : 1.f;
      mrow[mf][rr] = m;
    }
  __syncthreads();  // B no longer needed; reuse as reduce scratch
  float* Sred = (float*)Bh;   // [4][64]
  float* Sq = Sred + 256;     // [4][64]
#pragma unroll
  for (int nf = 0; nf < 4; ++nf) {
    const int col = cBase + nf * 16 + lr;
    const float bcol = bias[col];
    float ps = 0.f, pq = 0.f;
#pragma unroll
    for (int mf = 0; mf < 2; ++mf) {
      const f32x4 vv = acc[mf][nf];
#pragma unroll
      for (int rr = 0; rr < 4; ++rr) {
        const float o = vv[rr] + bcol;
        const int row = rowBase + w * 32 + mf * 16 + lg * 4 + rr;
        if (row < nrows) C[(size_t)row * 128 + col] = bf_hi(o);
        const float mo = mrow[mf][rr] * o;
        ps += mo;
        pq += mo * o;
      }
    }
    ps += __shfl_xor(ps, 16);
    ps += __shfl_xor(ps, 32);
    pq += __shfl_xor(pq, 16);
    pq += __shfl_xor(pq, 32);
    if (lg == 0) {
      Sred[w * 64 + nf * 16 + lr] = ps;
      Sq[w * 64 + nf * 16 + lr] = pq;
    }
  }
  __syncthreads();
  if (tid < 64) {
    float s = 0.f;
#pragma unroll
    for (int q = 0; q < 4; ++q) s += Sred[q * 64 + tid];
    atomicAdd(&statsOut[(cBase + tid) * 8], s);
  } else if (tid < 128) {
    float s = 0.f;
#pragma unroll
    for (int q = 0; q < 4; ++q) s += Sq[q * 64 + tid - 64];
    atomicAdd(&statsOut[(128 + cBase + tid - 64) * 8], s);
  }
}

// ---------------------------------------------------------------------------
// GEMM #1: fp32 A (dag_x), K=64, hi/lo-split A (3 MFMAs). Same structure.
// ---------------------------------------------------------------------------
__global__ __launch_bounds__(256, 4) void gemm_f32a(
    const float* __restrict__ A, const ushort* __restrict__ WTh,
    const ushort* __restrict__ WTl, const float* __restrict__ bias,
    ushort* __restrict__ C, float* __restrict__ statsOut, int nrows) {
  __shared__ ushort Bh[64 * 64];
  __shared__ ushort Bl[64 * 64];
  const int tid = threadIdx.x;
  const int w = tid >> 6, lane = tid & 63, lr = lane & 15, lg = lane >> 4;
  const int rt = blockIdx.x >> 1, ct = blockIdx.x & 1;
  const int rowBase = rt * 128, cBase = ct * 64;

  // stage B once (row stride 128B, swizzle byte ^= (col&7)<<4)
  {
    const int cc = tid >> 2;
    const ushort* sH = WTh + (size_t)(cBase + cc) * 64;
    const ushort* sL = WTl + (size_t)(cBase + cc) * 64;
    char* BhB = (char*)Bh;
    char* BlB = (char*)Bl;
#pragma unroll
    for (int i = 0; i < 2; ++i) {
      const int slot = (tid & 3) * 2 + i;
      const int off = (cc * 128 + slot * 16) ^ ((cc & 7) << 4);
      *(short8v*)(BhB + off) = *(const short8v*)(sH + slot * 8);
      *(short8v*)(BlB + off) = *(const short8v*)(sL + slot * 8);
    }
  }

  const int row0 = rowBase + w * 32 + lr;
  const int row1 = row0 + 16;
  const bool ok0 = row0 < nrows, ok1 = row1 < nrows;
  const float4 fz4 = make_float4(0.f, 0.f, 0.f, 0.f);
  const float* aP0 = A + (size_t)row0 * 64 + lg * 8;
  const float* aP1 = A + (size_t)row1 * 64 + lg * 8;
  float4 ar0[2][2], ar1[2][2];
#pragma unroll
  for (int c = 0; c < 2; ++c) {
    ar0[c][0] = ok0 ? *(const float4*)(aP0 + c * 32) : fz4;
    ar0[c][1] = ok0 ? *(const float4*)(aP0 + c * 32 + 4) : fz4;
    ar1[c][0] = ok1 ? *(const float4*)(aP1 + c * 32) : fz4;
    ar1[c][1] = ok1 ? *(const float4*)(aP1 + c * 32 + 4) : fz4;
  }
  __syncthreads();

  const f32x4 fzero = {0.f, 0.f, 0.f, 0.f};
  f32x4 acc[2][4];
#pragma unroll
  for (int i = 0; i < 2; ++i)
#pragma unroll
    for (int j = 0; j < 4; ++j) acc[i][j] = fzero;

  const char* BhB = (const char*)Bh;
  const char* BlB = (const char*)Bl;
#pragma unroll
  for (int c = 0; c < 2; ++c) {
    const float v0[8] = {ar0[c][0].x, ar0[c][0].y, ar0[c][0].z, ar0[c][0].w,
                         ar0[c][1].x, ar0[c][1].y, ar0[c][1].z, ar0[c][1].w};
    const float v1[8] = {ar1[c][0].x, ar1[c][0].y, ar1[c][0].z, ar1[c][0].w,
                         ar1[c][1].x, ar1[c][1].y, ar1[c][1].z, ar1[c][1].w};
    short8v a0h, a0l, a1h, a1l;
#pragma unroll
    for (int j = 0; j < 8; ++j) {
      ushort hh = bf_hi(v0[j]);
      a0h[j] = (short)hh;
      a0l[j] = (short)bf_hi(v0[j] - bf_f(hh));
      hh = bf_hi(v1[j]);
      a1h[j] = (short)hh;
      a1l[j] = (short)bf_hi(v1[j] - bf_f(hh));
    }
#pragma unroll
    for (int nf = 0; nf < 4; ++nf) {
      const int brow = nf * 16 + lr;
      const int off = (brow * 128 + (c * 4 + lg) * 16) ^ ((lr & 7) << 4);
      const short8v bh = *(const short8v*)(BhB + off);
      const short8v bl = *(const short8v*)(BlB + off);
      acc[0][nf] = __builtin_amdgcn_mfma_f32_16x16x32_bf16(a0h, bh, acc[0][nf], 0, 0, 0);
      acc[1][nf] = __builtin_amdgcn_mfma_f32_16x16x32_bf16(a1h, bh, acc[1][nf], 0, 0, 0);
      acc[0][nf] = __builtin_amdgcn_mfma_f32_16x16x32_bf16(a0l, bh, acc[0][nf], 0, 0, 0);
      acc[1][nf] = __builtin_amdgcn_mfma_f32_16x16x32_bf16(a1l, bh, acc[1][nf], 0, 0, 0);
      acc[0][nf] = __builtin_amdgcn_mfma_f32_16x16x32_bf16(a0h, bl, acc[0][nf], 0, 0, 0);
      acc[1][nf] = __builtin_amdgcn_mfma_f32_16x16x32_bf16(a1h, bl, acc[1][nf], 0, 0, 0);
    }
  }

  __syncthreads();
  float* Sred = (float*)Bh;  // [4][64]
  float* Sq = Sred + 256;
#pragma unroll
  for (int nf = 0; nf < 4; ++nf) {
    const int col = cBase + nf * 16 + lr;
    const float bcol = bias[col];
    float ps = 0.f, pq = 0.f;
#pragma unroll
    for (int mf = 0; mf < 2; ++mf) {
      const f32x4 vv = acc[mf][nf];
#pragma unroll
      for (int rr = 0; rr < 4; ++rr) {
        const float o = vv[rr] + bcol;
        const int row = rowBase + w * 32 + mf * 16 + lg * 4 + rr;
        if (row < nrows) {
          C[(size_t)row * 128 + col] = bf_hi(o);
          ps += o;
          pq += o * o;
        }
      }
    }
    ps += __shfl_xor(ps, 16);
    ps += __shfl_xor(ps, 32);
    pq += __shfl_xor(pq, 16);
    pq += __shfl_xor(pq, 32);
    if (lg == 0) {
      Sred[w * 64 + nf * 16 + lr] = ps;
      Sq[w * 64 + nf * 16 + lr] = pq;
    }
  }
  __syncthreads();
  if (tid < 64) {
    float s = 0.f;
#pragma unroll
    for (int q = 0; q < 4; ++q) s += Sred[q * 64 + tid];
    atomicAdd(&statsOut[(cBase + tid) * 8], s);
  } else if (tid < 128) {
    float s = 0.f;
#pragma unroll
    for (int q = 0; q < 4; ++q) s += Sq[q * 64 + tid - 64];
    atomicAdd(&statsOut[(128 + cBase + tid - 64) * 8], s);
  }
}

// Weight transpose + hi/lo split: 8 slots of 32768 ushorts (hi, lo@+16384)
__global__ __launch_bounds__(256) void wsplit_kernel(
    const float* __restrict__ W1, const float* __restrict__ W2,
    const float* __restrict__ dW1, const float* __restrict__ dW2,
    ushort* __restrict__ wsT) {
  const int t = blockIdx.x * 256 + threadIdx.x;
  const int slot = t >> 14;
  const int idx = t & 16383;
  if (slot >= 8) return;
  const int Ks = (slot == 0) ? 64 : 128;
  if (idx >= 128 * Ks) return;
  const int c = idx / Ks;
  const int k = idx - c * Ks;
  float v;
  if (slot == 0) v = W1[k * 128 + c];
  else if (slot == 1) v = W2[k * 128 + c];
  else if (slot < 5) v = dW1[(slot - 2) * 16384 + k * 128 + c];
  else v = dW2[(slot - 5) * 16384 + k * 128 + c];
  const ushort h = bf_hi(v);
  const ushort l = bf_hi(v - bf_f(h));
  wsT[slot * 32768 + c * Ks + k] = h;
  wsT[slot * 32768 + 16384 + c * Ks + k] = l;
}

// feat = relu(y*sc+sh); ss computed per block. 64 rows/block.
__global__ __launch_bounds__(256) void normrelu_kernel(
    const ushort* __restrict__ in, const float* __restrict__ stats,
    const float* __restrict__ g, const float* __restrict__ be, float cntFixed,
    ushort* __restrict__ outp) {
  __shared__ float ssS[256];
  compute_ss_lds(stats, g, be, cntFixed, ssS);
  __syncthreads();
  const int tid = threadIdx.x;
  const int c4 = (tid & 31) * 4;
  const float4 sc = *(const float4*)&ssS[c4];
  const float4 sh = *(const float4*)&ssS[128 + c4];
  const int rowBase = blockIdx.x * 64;
#pragma unroll
  for (int it = 0; it < 8; ++it) {
    const int row = rowBase + it * 8 + (tid >> 5);
    if (row >= Nn) continue;
    const size_t idx = (size_t)row * 32 + (tid & 31);
    const ushort4 v = ((const ushort4*)in)[idx];
    ushort4 o;
    o.x = bf_hi(fmaxf(fmaf(bf_f(v.x), sc.x, sh.x), 0.f));
    o.y = bf_hi(fmaxf(fmaf(bf_f(v.y), sc.y, sh.y), 0.f));
    o.z = bf_hi(fmaxf(fmaf(bf_f(v.z), sc.z, sh.z), 0.f));
    o.w = bf_hi(fmaxf(fmaf(bf_f(v.w), sc.w, sh.w), 0.f));
    ((ushort4*)outp)[idx] = o;
  }
}

// x += (tmask>0) * relu(y*sc+sh); ss per block; cnt from pointer.
__global__ __launch_bounds__(256) void normrelu_acc_kernel(
    const ushort* __restrict__ in, const float* __restrict__ stats,
    const float* __restrict__ g, const float* __restrict__ be,
    const float* __restrict__ cntPtr, const int* __restrict__ tmask,
    ushort* __restrict__ x) {
  __shared__ float ssS[256];
  compute_ss_lds(stats, g, be, fmaxf(cntPtr[0], 1.f), ssS);
  __syncthreads();
  const int tid = threadIdx.x;
  const int c4 = (tid & 31) * 4;
  const float4 sc = *(const float4*)&ssS[c4];
  const float4 sh = *(const float4*)&ssS[128 + c4];
  const int rowBase = blockIdx.x * 64;
#pragma unroll
  for (int it = 0; it < 8; ++it) {
    const int row = rowBase + it * 8 + (tid >> 5);
    if (row >= Nn || tmask[row] <= 0) continue;
    const size_t idx = (size_t)row * 32 + (tid & 31);
    const ushort4 v = ((const ushort4*)in)[idx];
    ushort4 xo = ((const ushort4*)x)[idx];
    xo.x = bf_hi(bf_f(xo.x) + fmaxf(fmaf(bf_f(v.x), sc.x, sh.x), 0.f));
    xo.y = bf_hi(bf_f(xo.y) + fmaxf(fmaf(bf_f(v.y), sc.y, sh.y), 0.f));
    xo.z = bf_hi(bf_f(xo.z) + fmaxf(fmaf(bf_f(v.z), sc.z, sh.z), 0.f));
    xo.w = bf_hi(bf_f(xo.w) + fmaxf(fmaf(bf_f(v.w), sc.w, sh.w), 0.f));
    ((ushort4*)x)[idx] = xo;
  }
}

__global__ __launch_bounds__(256) void scatter_leaves_kernel(
    const int* __restrict__ leaves, const ushort* __restrict__ feat,
    ushort* __restrict__ x, int nl) {
  const int gid = blockIdx.x * 256 + threadIdx.x;
  const int j = gid >> 5;
  if (j >= nl) return;
  const int node = leaves[j];
  const int c4 = (gid & 31) * 4;
  *(ushort4*)&x[(size_t)node * 128 + c4] =
      *(const ushort4*)&feat[(size_t)node * 128 + c4];
}

// ---------------- CSR build ----------------
__global__ __launch_bounds__(256) void deg_count_kernel(
    const int* __restrict__ dst, const int* __restrict__ lmask,
    int* __restrict__ cnts) {
  const int e = blockIdx.x * 256 + threadIdx.x;
  if (e >= Ee) return;
  atomicAdd(&cnts[lmask[e] * Nn + dst[e]], 1);
}

__global__ __launch_bounds__(256) void scan1_kernel(const int* __restrict__ in,
                                                    int* __restrict__ out,
                                                    int* __restrict__ bsum,
                                                    int n) {
  __shared__ int lds[256];
  const int tid = threadIdx.x;
  const int base = blockIdx.x * 2048 + tid * 8;
  int vals[8];
  int tsum = 0;
#pragma unroll
  for (int j = 0; j < 8; ++j) {
    const int v = (base + j < n) ? in[base + j] : 0;
    vals[j] = tsum;
    tsum += v;
  }
  lds[tid] = tsum;
  __syncthreads();
  for (int off = 1; off < 256; off <<= 1) {
    const int y = (tid >= off) ? lds[tid - off] : 0;
    __syncthreads();
    lds[tid] += y;
    __syncthreads();
  }
  const int texcl = (tid > 0) ? lds[tid - 1] : 0;
#pragma unroll
  for (int j = 0; j < 8; ++j)
    if (base + j < n) out[base + j] = texcl + vals[j];
  if (tid == 255) bsum[blockIdx.x] = lds[255];
}

__global__ void scan2_kernel(int* __restrict__ bsum, int nb) {
  __shared__ int lds[256];
  const int tid = threadIdx.x;
  const int v = (tid < nb) ? bsum[tid] : 0;
  lds[tid] = v;
  __syncthreads();
  for (int off = 1; off < 256; off <<= 1) {
    const int y = (tid >= off) ? lds[tid - off] : 0;
    __syncthreads();
    lds[tid] += y;
    __syncthreads();
  }
  if (tid < nb) bsum[tid] = lds[tid] - v;  // exclusive
}

__global__ __launch_bounds__(256) void scan3_kernel(int* __restrict__ out,
                                                    int* __restrict__ cursor,
                                                    const int* __restrict__ bsum,
                                                    int n, int etot) {
  const int i = blockIdx.x * 256 + threadIdx.x;
  if (i >= n) return;
  const int v = out[i] + bsum[i >> 11];
  out[i] = v;
  cursor[i] = v;
  if (i == n - 1) out[n] = etot;
}

__global__ __launch_bounds__(256) void csr_fill_kernel(
    const int* __restrict__ src, const int* __restrict__ dst,
    const float* __restrict__ mult, const int* __restrict__ lmask,
    int* __restrict__ cursor, int2* __restrict__ pairs) {
  const int e = blockIdx.x * 256 + threadIdx.x;
  if (e >= Ee) return;
  const int slot = atomicAdd(&cursor[lmask[e] * Nn + dst[e]], 1);
  pairs[slot] = make_int2(src[e], __float_as_int(mult[e]));
}

__global__ __launch_bounds__(256) void tcount_kernel(
    const int* __restrict__ degBase, float* __restrict__ tslot) {
  const int i = blockIdx.x * 256 + threadIdx.x;
  float v = (i < Nn && degBase[i] > 0) ? 1.f : 0.f;
  __shared__ float l[256];
  l[threadIdx.x] = v;
  __syncthreads();
  for (int s = 128; s > 0; s >>= 1) {
    if (threadIdx.x < s) l[threadIdx.x] += l[threadIdx.x + s];
    __syncthreads();
  }
  if (threadIdx.x == 0 && l[0] != 0.f) atomicAdd(tslot, l[0]);
}

// CSR aggregation (bf16); emits tmask.
__global__ __launch_bounds__(256) void agg_kernel(
    const int* __restrict__ offs, const int2* __restrict__ pairs,
    const ushort* __restrict__ x, const ushort* __restrict__ feat,
    const float* __restrict__ deps, int layer, ushort* __restrict__ sbuf,
    int* __restrict__ tmask) {
  const int node = blockIdx.x * 4 + (threadIdx.x >> 6);
  const int lane = threadIdx.x & 63;
  const int gi = layer * Nn + node;
  const int o0 = offs[gi];
  const int o1 = offs[gi + 1];
  ushort2 fv = make_ushort2(0, 0);
  if (o1 > o0) fv = *(const ushort2*)&feat[(size_t)node * 128 + lane * 2];
  float ax = 0.f, ay = 0.f;
  for (int p = o0; p < o1; p += 2) {
    const int2 pr0 = pairs[p];
    const int2 pr1 = (p + 1 < o1) ? pairs[p + 1] : make_int2(0, 0);
    const ushort2 x0 = *(const ushort2*)&x[(size_t)pr0.x * 128 + lane * 2];
    const ushort2 x1 = *(const ushort2*)&x[(size_t)pr1.x * 128 + lane * 2];
    const float w0 = __int_as_float(pr0.y);
    const float w1 = __int_as_float(pr1.y);
    ax = fmaf(w0, bf_f(x0.x), ax);
    ay = fmaf(w0, bf_f(x0.y), ay);
    ax = fmaf(w1, bf_f(x1.x), ax);
    ay = fmaf(w1, bf_f(x1.y), ay);
  }
  if (o1 > o0) {
    const float c = 1.f + deps[layer];
    ax = fmaf(c, bf_f(fv.x), ax);
    ay = fmaf(c, bf_f(fv.y), ay);
  }
  ushort2 o;
  o.x = bf_hi(ax);
  o.y = bf_hi(ay);
  *(ushort2*)&sbuf[(size_t)node * 128 + lane * 2] = o;
  if (lane == 0) tmask[node] = (o1 > o0) ? 1 : 0;
}

// ---------------- readout: counting-sort pool ----------------
__global__ __launch_bounds__(256) void phist_kernel(const int* __restrict__ ridx,
                                                    const int* __restrict__ batch,
                                                    int* __restrict__ cnt, int n) {
  const int i = blockIdx.x * 256 + threadIdx.x;
  if (i >= n) return;
  atomicAdd(&cnt[batch[ridx[i]]], 1);
}

__global__ void pscan_kernel(int* __restrict__ cnt, int* __restrict__ cur) {
  __shared__ int l[256];
  const int t = threadIdx.x;
  const int v = cnt[t];
  l[t] = v;
  __syncthreads();
  for (int off = 1; off < 256; off <<= 1) {
    const int y = (t >= off) ? l[t - off] : 0;
    __syncthreads();
    l[t] += y;
    __syncthreads();
  }
  const int e = l[t] - v;  // exclusive
  cnt[t] = e;
  cur[t] = e;
}

__global__ __launch_bounds__(256) void pfill_kernel(const int* __restrict__ ridx,
                                                    const int* __restrict__ batch,
                                                    int* __restrict__ cur,
                                                    int* __restrict__ sorted,
                                                    int n) {
  const int i = blockIdx.x * 256 + threadIdx.x;
  if (i >= n) return;
  const int node = ridx[i];
  const int slot = atomicAdd(&cur[batch[node]], 1);
  sorted[slot] = node;
}

__global__ __launch_bounds__(256) void ppool_kernel(const int* __restrict__ sorted,
                                                    const int* __restrict__ offs,
                                                    const ushort* __restrict__ x,
                                                    float* __restrict__ P, int n) {
  __shared__ float part[4][256];
  const int g = blockIdx.x;
  const int w = threadIdx.x >> 6;
  const int lane = threadIdx.x & 63;
  const int o0 = offs[g];
  const int o1 = (g < Gg - 1) ? offs[g + 1] : n;
  float ax = 0.f, ay = 0.f;
  for (int p = o0 + w; p < o1; p += 4) {
    const int node = sorted[p];
    const ushort2 xv = *(const ushort2*)&x[(size_t)node * 128 + lane * 2];
    ax += bf_f(xv.x);
    ay += bf_f(xv.y);
  }
  part[w][lane * 2] = ax;
  part[w][lane * 2 + 1] = ay;
  __syncthreads();
  if (threadIdx.x < 128) {
    const int c = threadIdx.x;
    P[(size_t)g * 128 + c] = part[0][c] + part[1][c] + part[2][c] + part[3][c];
  }
}

__global__ void out_kernel(const float* __restrict__ P,
                           const float* __restrict__ Wl,
                           const float* __restrict__ bl,
                           float* __restrict__ out) {
  const int gid = blockIdx.x * blockDim.x + threadIdx.x;
  if (gid >= Gg * Tt) return;
  const int g = gid / Tt;
  const int t = gid - g * Tt;
  float acc = 0.f;
  for (int c = 0; c < 128; ++c) acc += P[g * 128 + c] * Wl[c * Tt + t];
  out[gid] = acc * 0.25f + bl[t];
}

extern "C" void kernel_launch(void* const* d_in, const int* in_sizes, int n_in,
                              void* d_out, int out_size, void* d_ws,
                              size_t ws_size, hipStream_t stream) {
  const float* dag_x = (const float*)d_in[0];
  const int* eidx = (const int*)d_in[1];
  const int* src = eidx;
  const int* dst = eidx + Ee;
  const float* mult = (const float*)d_in[2];
  const int* lmask = (const int*)d_in[3];
  const int* batch = (const int*)d_in[4];
  const int* leaves = (const int*)d_in[5];
  const int* readouts = (const int*)d_in[6];
  const float* W1 = (const float*)d_in[7];
  const float* b1 = (const float*)d_in[8];
  const float* g1 = (const float*)d_in[9];
  const float* be1 = (const float*)d_in[10];
  const float* W2 = (const float*)d_in[11];
  const float* b2 = (const float*)d_in[12];
  const float* g2 = (const float*)d_in[13];
  const float* be2 = (const float*)d_in[14];
  const float* dW1 = (const float*)d_in[15];
  const float* db1 = (const float*)d_in[16];
  const float* dg1 = (const float*)d_in[17];
  const float* dbe1 = (const float*)d_in[18];
  const float* dW2 = (const float*)d_in[19];
  const float* db2 = (const float*)d_in[20];
  const float* dg2 = (const float*)d_in[21];
  const float* dbe2 = (const float*)d_in[22];
  const float* deps = (const float*)d_in[23];
  const float* Wl = (const float*)d_in[24];
  const float* bl = (const float*)d_in[25];
  float* out = (float*)d_out;

  const size_t ND = (size_t)Nn * Dd;
  ushort* feat = (ushort*)d_ws;          // ND bf16
  ushort* xbuf = feat + ND;              // ND bf16
  ushort* Abuf = xbuf + ND;              // ND bf16
  ushort* Bbuf = Abuf + ND;              // ND bf16 (gemm ping-pong)
  float* statsAll = (float*)(Bbuf + ND); // 8 slots x 2048
  float* tcountf = statsAll + 8 * 2048;  // 8 (4 used)
  int* tmask = (int*)(tcountf + 8);      // N
  ushort* wsT = (ushort*)(tmask + Nn);   // 262144 (8 weight slots, hi+lo)
  int* offs = (int*)(wsT + 262144);      // 3N+4
  int2* pairs = (int2*)(offs + 3 * Nn + 4);  // E pairs (src, mult)

  // transient overlays (xbuf region before it's initialized):
  int* cnts = (int*)xbuf;                // 3N
  int* cursor = cnts + 3 * Nn;           // 3N
  int* bsum = cursor + 3 * Nn;           // 147
  const int nridx = in_sizes[6];         // 80000
  const int nleaves = in_sizes[5];       // 50000
  // pool overlays (Abuf dead by readout):
  int* pcnt = (int*)Abuf;                // 256 (becomes offsets)
  int* pcur = pcnt + 256;                // 256
  int* sorted = pcur + 256;              // nridx
  float* P = (float*)(sorted + nridx);   // G*D

  dim3 blk(256);
  hipMemsetAsync(statsAll, 0, 8 * 2048 * sizeof(float), stream);
  hipMemsetAsync(tcountf, 0, 8 * sizeof(float), stream);
  wsplit_kernel<<<512, blk, 0, stream>>>(W1, W2, dW1, dW2, wsT);

  // ---- CSR build ----
  hipMemsetAsync(cnts, 0, 3 * Nn * sizeof(int), stream);
  deg_count_kernel<<<2344, blk, 0, stream>>>(dst, lmask, cnts);
  for (int l = 0; l < Ll; ++l)
    tcount_kernel<<<391, blk, 0, stream>>>(cnts + l * Nn, tcountf + l);
  scan1_kernel<<<147, blk, 0, stream>>>(cnts, offs, bsum, 3 * Nn);
  scan2_kernel<<<1, blk, 0, stream>>>(bsum, 147);
  scan3_kernel<<<1172, blk, 0, stream>>>(offs, cursor, bsum, 3 * Nn, Ee);
  csr_fill_kernel<<<2344, blk, 0, stream>>>(src, dst, mult, lmask, cursor, pairs);

  const int gGemm = 782 * 2;
  // ---- node feature transform ----
  // y1 = dag_x@W1+b1 -> Abuf, stats slot0
  gemm_f32a<<<gGemm, blk, 0, stream>>>(dag_x, wsT, wsT + 16384, b1, Abuf,
                                       statsAll + 0 * 2048, Nn);
  // y2 = relu(bn(y1))@W2+b2 -> Bbuf, stats slot1
  gemm_bf16<true, false><<<gGemm, blk, 0, stream>>>(
      Abuf, wsT + 32768, wsT + 32768 + 16384, b2, statsAll + 0 * 2048, g1, be1,
      nullptr, nullptr, Bbuf, statsAll + 1 * 2048, Nn);
  // feat = relu(bn(y2))
  normrelu_kernel<<<1563, blk, 0, stream>>>(Bbuf, statsAll + 1 * 2048, g2, be2,
                                            (float)Nn, feat);

  hipMemsetAsync(xbuf, 0, ND * sizeof(ushort), stream);
  scatter_leaves_kernel<<<6250, blk, 0, stream>>>(leaves, feat, xbuf, nleaves);

  // ---- DAG layers ----
  for (int layer = 0; layer < Ll; ++layer) {
    agg_kernel<<<25000, blk, 0, stream>>>(offs, pairs, xbuf, feat, deps, layer,
                                          Abuf, tmask);
    const int so1 = (2 + layer) * 32768;
    const int so2 = (5 + layer) * 32768;
    const int po = layer * Dd;
    float* st1 = statsAll + (2 + 2 * layer) * 2048;
    float* st2 = statsAll + (3 + 2 * layer) * 2048;
    // y1 = s@dW1+db1 -> Bbuf, masked stats st1
    gemm_bf16<false, true><<<gGemm, blk, 0, stream>>>(
        Abuf, wsT + so1, wsT + so1 + 16384, db1 + po, nullptr, nullptr,
        nullptr, nullptr, tmask, Bbuf, st1, Nn);
    // y2 = relu(bn_masked(y1))@dW2+db2 -> Abuf, masked stats st2
    gemm_bf16<true, true><<<gGemm, blk, 0, stream>>>(
        Bbuf, wsT + so2, wsT + so2 + 16384, db2 + po, st1, dg1 + po, dbe1 + po,
        tcountf + layer, tmask, Abuf, st2, Nn);
    // x += mask * relu(bn_masked(y2))
    normrelu_acc_kernel<<<1563, blk, 0, stream>>>(
        Abuf, st2, dg2 + po, dbe2 + po, tcountf + layer, tmask, xbuf);
  }

  // ---- readout (counting sort, no float atomics) ----
  hipMemsetAsync(pcnt, 0, 512 * sizeof(int), stream);
  const int gIdx = (nridx + 255) / 256;
  phist_kernel<<<gIdx, blk, 0, stream>>>(readouts, batch, pcnt, nridx);
  pscan_kernel<<<1, blk, 0, stream>>>(pcnt, pcur);
  pfill_kernel<<<gIdx, blk, 0, stream>>>(readouts, batch, pcur, sorted, nridx);
  ppool_kernel<<<Gg, blk, 0, stream>>>(sorted, pcnt, xbuf, P, nridx);
  out_kernel<<<10, blk, 0, stream>>>(P, Wl, bl, out);
}

// Round 7
// 598.646 us; speedup vs baseline: 3.8045x; 1.0996x over previous
//
#include <hip/hip_runtime.h>

constexpr int Nn = 100000;   // nodes
constexpr int Ee = 600000;   // edges
constexpr int Dd = 128;      // hidden dim
constexpr int Ll = 3;        // DAG layers
constexpr int Gg = 256;      // graphs
constexpr int Tt = 10;       // outputs per graph
constexpr float BN_EPS = 1e-5f;
constexpr int NREP = 16;     // stats replicas (slot = [16][512] floats)

typedef __attribute__((ext_vector_type(8))) short short8v;
typedef __attribute__((ext_vector_type(4))) float f32x4;

__device__ inline ushort bf_hi(float f) {
  unsigned u = __float_as_uint(f);
  unsigned r = (u + 0x7FFFu + ((u >> 16) & 1u)) >> 16;
  return (ushort)r;
}
__device__ inline float bf_f(ushort h) {
  return __uint_as_float(((unsigned)h) << 16);
}

// BN scale/shift from a replicated stats slot -> LDS ssS[256] (threads 0..127)
__device__ inline void compute_ss_lds(const float* __restrict__ stats,
                                      const float* __restrict__ g,
                                      const float* __restrict__ be, float cnt,
                                      float* ssS) {
  const int c = threadIdx.x;
  if (c < 128) {
    float S = 0.f, Q = 0.f;
#pragma unroll
    for (int r = 0; r < NREP; ++r) {
      S += stats[r * 512 + c];
      Q += stats[r * 512 + 256 + c];
    }
    const float m = S / cnt;
    const float v = Q / cnt - m * m;
    const float sc = g[c] * rsqrtf(v + BN_EPS);
    ssS[c] = sc;
    ssS[128 + c] = be[c] - m * sc;
  }
}

// ---------------------------------------------------------------------------
// B-resident barrier-free GEMM (bf16 A): C[N][64-slice] = op(A)@W + bias.
// Tile 128 rows x 64 cols; grid 782*2. B staged once (XOR-swizzled); A
// prefetched to regs; zero barriers in K-loop. Epilogue: acc->LDS bounce ->
// 16B vector stores; stats partials -> replica atomics.
// ---------------------------------------------------------------------------
template <bool NORM_A, bool MASKED>
__global__ __launch_bounds__(256, 4) void gemm_bf16(
    const ushort* __restrict__ A, const ushort* __restrict__ WTh,
    const ushort* __restrict__ WTl, const float* __restrict__ bias,
    const float* __restrict__ statsIn, const float* __restrict__ gN,
    const float* __restrict__ beN, const float* __restrict__ cntPtr,
    const int* __restrict__ tmask, ushort* __restrict__ C,
    float* __restrict__ statsOut, int nrows) {
  __shared__ ushort SB[16384];  // Bh[8192] | Bl[8192]; reused: Cs[128][72]+red
  __shared__ float ssS[256];
  ushort* Bh = SB;
  ushort* Bl = SB + 8192;
  const int tid = threadIdx.x;
  const int w = tid >> 6, lane = tid & 63, lr = lane & 15, lg = lane >> 4;
  const int rt = blockIdx.x >> 1, ct = blockIdx.x & 1;
  const int rowBase = rt * 128, cBase = ct * 64;
  const int rep = blockIdx.x & (NREP - 1);

  // ---- stage B once (swizzle: byte ^= (col&7)<<4 within 256B row) ----
  {
    const int cc = tid >> 2;
    const ushort* sH = WTh + (size_t)(cBase + cc) * 128;
    const ushort* sL = WTl + (size_t)(cBase + cc) * 128;
    char* BhB = (char*)Bh;
    char* BlB = (char*)Bl;
#pragma unroll
    for (int i = 0; i < 4; ++i) {
      const int slot = (tid & 3) * 4 + i;
      const int off = (cc * 256 + slot * 16) ^ ((cc & 7) << 4);
      *(short8v*)(BhB + off) = *(const short8v*)(sH + slot * 8);
      *(short8v*)(BlB + off) = *(const short8v*)(sL + slot * 8);
    }
  }
  if (NORM_A) {
    const float cnt = cntPtr ? fmaxf(cntPtr[0], 1.f) : (float)nrows;
    compute_ss_lds(statsIn, gN, beN, cnt, ssS);
  }

  // ---- prefetch all A fragments ----
  const int row0 = rowBase + w * 32 + lr;
  const int row1 = row0 + 16;
  const bool ok0 = row0 < nrows, ok1 = row1 < nrows;
  const short8v szero = {0, 0, 0, 0, 0, 0, 0, 0};
  const ushort* aP0 = A + (size_t)row0 * 128 + lg * 8;
  const ushort* aP1 = A + (size_t)row1 * 128 + lg * 8;
  short8v ar0[4], ar1[4];
#pragma unroll
  for (int c = 0; c < 4; ++c) {
    ar0[c] = ok0 ? *(const short8v*)(aP0 + c * 32) : szero;
    ar1[c] = ok1 ? *(const short8v*)(aP1 + c * 32) : szero;
  }
  __syncthreads();

  const f32x4 fzero = {0.f, 0.f, 0.f, 0.f};
  f32x4 acc[2][4];
#pragma unroll
  for (int i = 0; i < 2; ++i)
#pragma unroll
    for (int j = 0; j < 4; ++j) acc[i][j] = fzero;

  const char* BhB = (const char*)Bh;
  const char* BlB = (const char*)Bl;
#pragma unroll
  for (int c = 0; c < 4; ++c) {
    short8v a0 = ar0[c], a1 = ar1[c];
    if (NORM_A) {
      const int kb = c * 32 + lg * 8;
      const float4 s0 = *(const float4*)&ssS[kb];
      const float4 s1 = *(const float4*)&ssS[kb + 4];
      const float4 h0 = *(const float4*)&ssS[128 + kb];
      const float4 h1 = *(const float4*)&ssS[128 + kb + 4];
      const float sv[8] = {s0.x, s0.y, s0.z, s0.w, s1.x, s1.y, s1.z, s1.w};
      const float hv[8] = {h0.x, h0.y, h0.z, h0.w, h1.x, h1.y, h1.z, h1.w};
#pragma unroll
      for (int j = 0; j < 8; ++j) {
        a0[j] = (short)bf_hi(fmaxf(fmaf(bf_f((ushort)a0[j]), sv[j], hv[j]), 0.f));
        a1[j] = (short)bf_hi(fmaxf(fmaf(bf_f((ushort)a1[j]), sv[j], hv[j]), 0.f));
      }
    }
#pragma unroll
    for (int nf = 0; nf < 4; ++nf) {
      const int brow = nf * 16 + lr;
      const int off = (brow * 256 + (c * 4 + lg) * 16) ^ ((lr & 7) << 4);
      const short8v bh = *(const short8v*)(BhB + off);
      const short8v bl = *(const short8v*)(BlB + off);
      acc[0][nf] = __builtin_amdgcn_mfma_f32_16x16x32_bf16(a0, bh, acc[0][nf], 0, 0, 0);
      acc[1][nf] = __builtin_amdgcn_mfma_f32_16x16x32_bf16(a1, bh, acc[1][nf], 0, 0, 0);
      acc[0][nf] = __builtin_amdgcn_mfma_f32_16x16x32_bf16(a0, bl, acc[0][nf], 0, 0, 0);
      acc[1][nf] = __builtin_amdgcn_mfma_f32_16x16x32_bf16(a1, bl, acc[1][nf], 0, 0, 0);
    }
  }

  // ---- epilogue: acc -> LDS bounce; stats partials ----
  float mrow[2][4];
#pragma unroll
  for (int mf = 0; mf < 2; ++mf)
#pragma unroll
    for (int rr = 0; rr < 4; ++rr) {
      const int row = rowBase + w * 32 + mf * 16 + lg * 4 + rr;
      float m = 0.f;
      if (row < nrows) m = MASKED ? ((tmask[row] > 0) ? 1.f : 0.f) : 1.f;
      mrow[mf][rr] = m;
    }
  __syncthreads();  // all waves done reading B
  ushort* Cs = SB;                      // [128][72]
  float* Sred = (float*)(SB + 9216);    // [4][64]
  float* Sq = Sred + 256;               // [4][64]
#pragma unroll
  for (int nf = 0; nf < 4; ++nf) {
    const int col = nf * 16 + lr;
    const float bcol = bias[cBase + col];
    float ps = 0.f, pq = 0.f;
#pragma unroll
    for (int mf = 0; mf < 2; ++mf) {
      const f32x4 vv = acc[mf][nf];
#pragma unroll
      for (int rr = 0; rr < 4; ++rr) {
        const float o = vv[rr] + bcol;
        const int rl = w * 32 + mf * 16 + lg * 4 + rr;
        Cs[rl * 72 + col] = bf_hi(o);
        const float mo = mrow[mf][rr] * o;
        ps += mo;
        pq += mo * o;
      }
    }
    ps += __shfl_xor(ps, 16);
    ps += __shfl_xor(ps, 32);
    pq += __shfl_xor(pq, 16);
    pq += __shfl_xor(pq, 32);
    if (lg == 0) {
      Sred[w * 64 + col] = ps;
      Sq[w * 64 + col] = pq;
    }
  }
  __syncthreads();
  {
    const int rl = tid >> 1, half = tid & 1;
    const int grow = rowBase + rl;
    if (grow < nrows) {
      ushort* dstp = C + (size_t)grow * 128 + cBase + half * 32;
      const ushort* srcp = Cs + rl * 72 + half * 32;
#pragma unroll
      for (int j = 0; j < 4; ++j)
        *(short8v*)(dstp + j * 8) = *(const short8v*)(srcp + j * 8);
    }
  }
  if (tid < 64) {
    float s = 0.f;
#pragma unroll
    for (int q = 0; q < 4; ++q) s += Sred[q * 64 + tid];
    atomicAdd(&statsOut[rep * 512 + cBase + tid], s);
  } else if (tid < 128) {
    float s = 0.f;
#pragma unroll
    for (int q = 0; q < 4; ++q) s += Sq[q * 64 + tid - 64];
    atomicAdd(&statsOut[rep * 512 + 256 + cBase + tid - 64], s);
  }
}

// ---------------------------------------------------------------------------
// GEMM #1: fp32 A (dag_x), K=64, hi/lo-split A (3 MFMAs). Same epilogue.
// ---------------------------------------------------------------------------
__global__ __launch_bounds__(256, 4) void gemm_f32a(
    const float* __restrict__ A, const ushort* __restrict__ WTh,
    const ushort* __restrict__ WTl, const float* __restrict__ bias,
    ushort* __restrict__ C, float* __restrict__ statsOut, int nrows) {
  __shared__ ushort SB[11264];  // Bh[4096] | Bl[4096]; reused Cs[128][72]+red
  ushort* Bh = SB;
  ushort* Bl = SB + 4096;
  const int tid = threadIdx.x;
  const int w = tid >> 6, lane = tid & 63, lr = lane & 15, lg = lane >> 4;
  const int rt = blockIdx.x >> 1, ct = blockIdx.x & 1;
  const int rowBase = rt * 128, cBase = ct * 64;
  const int rep = blockIdx.x & (NREP - 1);

  {
    const int cc = tid >> 2;
    const ushort* sH = WTh + (size_t)(cBase + cc) * 64;
    const ushort* sL = WTl + (size_t)(cBase + cc) * 64;
    char* BhB = (char*)Bh;
    char* BlB = (char*)Bl;
#pragma unroll
    for (int i = 0; i < 2; ++i) {
      const int slot = (tid & 3) * 2 + i;
      const int off = (cc * 128 + slot * 16) ^ ((cc & 7) << 4);
      *(short8v*)(BhB + off) = *(const short8v*)(sH + slot * 8);
      *(short8v*)(BlB + off) = *(const short8v*)(sL + slot * 8);
    }
  }

  const int row0 = rowBase + w * 32 + lr;
  const int row1 = row0 + 16;
  const bool ok0 = row0 < nrows, ok1 = row1 < nrows;
  const float4 fz4 = make_float4(0.f, 0.f, 0.f, 0.f);
  const float* aP0 = A + (size_t)row0 * 64 + lg * 8;
  const float* aP1 = A + (size_t)row1 * 64 + lg * 8;
  float4 ar0[2][2], ar1[2][2];
#pragma unroll
  for (int c = 0; c < 2; ++c) {
    ar0[c][0] = ok0 ? *(const float4*)(aP0 + c * 32) : fz4;
    ar0[c][1] = ok0 ? *(const float4*)(aP0 + c * 32 + 4) : fz4;
    ar1[c][0] = ok1 ? *(const float4*)(aP1 + c * 32) : fz4;
    ar1[c][1] = ok1 ? *(const float4*)(aP1 + c * 32 + 4) : fz4;
  }
  __syncthreads();

  const f32x4 fzero = {0.f, 0.f, 0.f, 0.f};
  f32x4 acc[2][4];
#pragma unroll
  for (int i = 0; i < 2; ++i)
#pragma unroll
    for (int j = 0; j < 4; ++j) acc[i][j] = fzero;

  const char* BhB = (const char*)Bh;
  const char* BlB = (const char*)Bl;
#pragma unroll
  for (int c = 0; c < 2; ++c) {
    const float v0[8] = {ar0[c][0].x, ar0[c][0].y, ar0[c][0].z, ar0[c][0].w,
                         ar0[c][1].x, ar0[c][1].y, ar0[c][1].z, ar0[c][1].w};
    const float v1[8] = {ar1[c][0].x, ar1[c][0].y, ar1[c][0].z, ar1[c][0].w,
                         ar1[c][1].x, ar1[c][1].y, ar1[c][1].z, ar1[c][1].w};
    short8v a0h, a0l, a1h, a1l;
#pragma unroll
    for (int j = 0; j < 8; ++j) {
      ushort hh = bf_hi(v0[j]);
      a0h[j] = (short)hh;
      a0l[j] = (short)bf_hi(v0[j] - bf_f(hh));
      hh = bf_hi(v1[j]);
      a1h[j] = (short)hh;
      a1l[j] = (short)bf_hi(v1[j] - bf_f(hh));
    }
#pragma unroll
    for (int nf = 0; nf < 4; ++nf) {
      const int brow = nf * 16 + lr;
      const int off = (brow * 128 + (c * 4 + lg) * 16) ^ ((lr & 7) << 4);
      const short8v bh = *(const short8v*)(BhB + off);
      const short8v bl = *(const short8v*)(BlB + off);
      acc[0][nf] = __builtin_amdgcn_mfma_f32_16x16x32_bf16(a0h, bh, acc[0][nf], 0, 0, 0);
      acc[1][nf] = __builtin_amdgcn_mfma_f32_16x16x32_bf16(a1h, bh, acc[1][nf], 0, 0, 0);
      acc[0][nf] = __builtin_amdgcn_mfma_f32_16x16x32_bf16(a0l, bh, acc[0][nf], 0, 0, 0);
      acc[1][nf] = __builtin_amdgcn_mfma_f32_16x16x32_bf16(a1l, bh, acc[1][nf], 0, 0, 0);
      acc[0][nf] = __builtin_amdgcn_mfma_f32_16x16x32_bf16(a0h, bl, acc[0][nf], 0, 0, 0);
      acc[1][nf] = __builtin_amdgcn_mfma_f32_16x16x32_bf16(a1h, bl, acc[1][nf], 0, 0, 0);
    }
  }

  __syncthreads();
  ushort* Cs = SB;                    // [128][72]
  float* Sred = (float*)(SB + 9216);  // [4][64]
  float* Sq = Sred + 256;
#pragma unroll
  for (int nf = 0; nf < 4; ++nf) {
    const int col = nf * 16 + lr;
    const float bcol = bias[cBase + col];
    float ps = 0.f, pq = 0.f;
#pragma unroll
    for (int mf = 0; mf < 2; ++mf) {
      const f32x4 vv = acc[mf][nf];
#pragma unroll
      for (int rr = 0; rr < 4; ++rr) {
        const float o = vv[rr] + bcol;
        const int rl = w * 32 + mf * 16 + lg * 4 + rr;
        Cs[rl * 72 + col] = bf_hi(o);
        const int row = rowBase + rl;
        const float m = (row < nrows) ? 1.f : 0.f;
        const float mo = m * o;
        ps += mo;
        pq += mo * o;
      }
    }
    ps += __shfl_xor(ps, 16);
    ps += __shfl_xor(ps, 32);
    pq += __shfl_xor(pq, 16);
    pq += __shfl_xor(pq, 32);
    if (lg == 0) {
      Sred[w * 64 + col] = ps;
      Sq[w * 64 + col] = pq;
    }
  }
  __syncthreads();
  {
    const int rl = tid >> 1, half = tid & 1;
    const int grow = rowBase + rl;
    if (grow < nrows) {
      ushort* dstp = C + (size_t)grow * 128 + cBase + half * 32;
      const ushort* srcp = Cs + rl * 72 + half * 32;
#pragma unroll
      for (int j = 0; j < 4; ++j)
        *(short8v*)(dstp + j * 8) = *(const short8v*)(srcp + j * 8);
    }
  }
  if (tid < 64) {
    float s = 0.f;
#pragma unroll
    for (int q = 0; q < 4; ++q) s += Sred[q * 64 + tid];
    atomicAdd(&statsOut[rep * 512 + cBase + tid], s);
  } else if (tid < 128) {
    float s = 0.f;
#pragma unroll
    for (int q = 0; q < 4; ++q) s += Sq[q * 64 + tid - 64];
    atomicAdd(&statsOut[rep * 512 + 256 + cBase + tid - 64], s);
  }
}

// Weight transpose + hi/lo split: 8 slots of 32768 ushorts (hi, lo@+16384)
__global__ __launch_bounds__(256) void wsplit_kernel(
    const float* __restrict__ W1, const float* __restrict__ W2,
    const float* __restrict__ dW1, const float* __restrict__ dW2,
    ushort* __restrict__ wsT) {
  const int t = blockIdx.x * 256 + threadIdx.x;
  const int slot = t >> 14;
  const int idx = t & 16383;
  if (slot >= 8) return;
  const int Ks = (slot == 0) ? 64 : 128;
  if (idx >= 128 * Ks) return;
  const int c = idx / Ks;
  const int k = idx - c * Ks;
  float v;
  if (slot == 0) v = W1[k * 128 + c];
  else if (slot == 1) v = W2[k * 128 + c];
  else if (slot < 5) v = dW1[(slot - 2) * 16384 + k * 128 + c];
  else v = dW2[(slot - 5) * 16384 + k * 128 + c];
  const ushort h = bf_hi(v);
  const ushort l = bf_hi(v - bf_f(h));
  wsT[slot * 32768 + c * Ks + k] = h;
  wsT[slot * 32768 + 16384 + c * Ks + k] = l;
}

// feat = relu(y*sc+sh); ss computed per block. 64 rows/block.
__global__ __launch_bounds__(256) void normrelu_kernel(
    const ushort* __restrict__ in, const float* __restrict__ stats,
    const float* __restrict__ g, const float* __restrict__ be, float cntFixed,
    ushort* __restrict__ outp) {
  __shared__ float ssS[256];
  compute_ss_lds(stats, g, be, cntFixed, ssS);
  __syncthreads();
  const int tid = threadIdx.x;
  const int c4 = (tid & 31) * 4;
  const float4 sc = *(const float4*)&ssS[c4];
  const float4 sh = *(const float4*)&ssS[128 + c4];
  const int rowBase = blockIdx.x * 64;
#pragma unroll
  for (int it = 0; it < 8; ++it) {
    const int row = rowBase + it * 8 + (tid >> 5);
    if (row >= Nn) continue;
    const size_t idx = (size_t)row * 32 + (tid & 31);
    const ushort4 v = ((const ushort4*)in)[idx];
    ushort4 o;
    o.x = bf_hi(fmaxf(fmaf(bf_f(v.x), sc.x, sh.x), 0.f));
    o.y = bf_hi(fmaxf(fmaf(bf_f(v.y), sc.y, sh.y), 0.f));
    o.z = bf_hi(fmaxf(fmaf(bf_f(v.z), sc.z, sh.z), 0.f));
    o.w = bf_hi(fmaxf(fmaf(bf_f(v.w), sc.w, sh.w), 0.f));
    ((ushort4*)outp)[idx] = o;
  }
}

// x += (tmask>0) * relu(y*sc+sh)
__global__ __launch_bounds__(256) void normrelu_acc_kernel(
    const ushort* __restrict__ in, const float* __restrict__ stats,
    const float* __restrict__ g, const float* __restrict__ be,
    const float* __restrict__ cntPtr, const int* __restrict__ tmask,
    ushort* __restrict__ x) {
  __shared__ float ssS[256];
  compute_ss_lds(stats, g, be, fmaxf(cntPtr[0], 1.f), ssS);
  __syncthreads();
  const int tid = threadIdx.x;
  const int c4 = (tid & 31) * 4;
  const float4 sc = *(const float4*)&ssS[c4];
  const float4 sh = *(const float4*)&ssS[128 + c4];
  const int rowBase = blockIdx.x * 64;
#pragma unroll
  for (int it = 0; it < 8; ++it) {
    const int row = rowBase + it * 8 + (tid >> 5);
    if (row >= Nn || tmask[row] <= 0) continue;
    const size_t idx = (size_t)row * 32 + (tid & 31);
    const ushort4 v = ((const ushort4*)in)[idx];
    ushort4 xo = ((const ushort4*)x)[idx];
    xo.x = bf_hi(bf_f(xo.x) + fmaxf(fmaf(bf_f(v.x), sc.x, sh.x), 0.f));
    xo.y = bf_hi(bf_f(xo.y) + fmaxf(fmaf(bf_f(v.y), sc.y, sh.y), 0.f));
    xo.z = bf_hi(bf_f(xo.z) + fmaxf(fmaf(bf_f(v.z), sc.z, sh.z), 0.f));
    xo.w = bf_hi(bf_f(xo.w) + fmaxf(fmaf(bf_f(v.w), sc.w, sh.w), 0.f));
    ((ushort4*)x)[idx] = xo;
  }
}

__global__ __launch_bounds__(256) void scatter_leaves_kernel(
    const int* __restrict__ leaves, const ushort* __restrict__ feat,
    ushort* __restrict__ x, int nl) {
  const int gid = blockIdx.x * 256 + threadIdx.x;
  const int j = gid >> 5;
  if (j >= nl) return;
  const int node = leaves[j];
  const int c4 = (gid & 31) * 4;
  *(ushort4*)&x[(size_t)node * 128 + c4] =
      *(const ushort4*)&feat[(size_t)node * 128 + c4];
}

// ---------------- CSR build ----------------
__global__ __launch_bounds__(256) void deg_count_kernel(
    const int* __restrict__ dst, const int* __restrict__ lmask,
    int* __restrict__ cnts) {
  const int e = blockIdx.x * 256 + threadIdx.x;
  if (e >= Ee) return;
  atomicAdd(&cnts[lmask[e] * Nn + dst[e]], 1);
}

__global__ __launch_bounds__(256) void scan1_kernel(const int* __restrict__ in,
                                                    int* __restrict__ out,
                                                    int* __restrict__ bsum,
                                                    int n) {
  __shared__ int lds[256];
  const int tid = threadIdx.x;
  const int base = blockIdx.x * 2048 + tid * 8;
  int vals[8];
  int tsum = 0;
#pragma unroll
  for (int j = 0; j < 8; ++j) {
    const int v = (base + j < n) ? in[base + j] : 0;
    vals[j] = tsum;
    tsum += v;
  }
  lds[tid] = tsum;
  __syncthreads();
  for (int off = 1; off < 256; off <<= 1) {
    const int y = (tid >= off) ? lds[tid - off] : 0;
    __syncthreads();
    lds[tid] += y;
    __syncthreads();
  }
  const int texcl = (tid > 0) ? lds[tid - 1] : 0;
#pragma unroll
  for (int j = 0; j < 8; ++j)
    if (base + j < n) out[base + j] = texcl + vals[j];
  if (tid == 255) bsum[blockIdx.x] = lds[255];
}

__global__ void scan2_kernel(int* __restrict__ bsum, int nb) {
  __shared__ int lds[256];
  const int tid = threadIdx.x;
  const int v = (tid < nb) ? bsum[tid] : 0;
  lds[tid] = v;
  __syncthreads();
  for (int off = 1; off < 256; off <<= 1) {
    const int y = (tid >= off) ? lds[tid - off] : 0;
    __syncthreads();
    lds[tid] += y;
    __syncthreads();
  }
  if (tid < nb) bsum[tid] = lds[tid] - v;  // exclusive
}

__global__ __launch_bounds__(256) void scan3_kernel(int* __restrict__ out,
                                                    int* __restrict__ cursor,
                                                    const int* __restrict__ bsum,
                                                    int n, int etot) {
  const int i = blockIdx.x * 256 + threadIdx.x;
  if (i >= n) return;
  const int v = out[i] + bsum[i >> 11];
  out[i] = v;
  cursor[i] = v;
  if (i == n - 1) out[n] = etot;
}

__global__ __launch_bounds__(256) void csr_fill_kernel(
    const int* __restrict__ src, const int* __restrict__ dst,
    const float* __restrict__ mult, const int* __restrict__ lmask,
    int* __restrict__ cursor, int2* __restrict__ pairs) {
  const int e = blockIdx.x * 256 + threadIdx.x;
  if (e >= Ee) return;
  const int slot = atomicAdd(&cursor[lmask[e] * Nn + dst[e]], 1);
  pairs[slot] = make_int2(src[e], __float_as_int(mult[e]));
}

__global__ __launch_bounds__(256) void tcount_kernel(
    const int* __restrict__ degBase, float* __restrict__ tslot) {
  const int i = blockIdx.x * 256 + threadIdx.x;
  float v = (i < Nn && degBase[i] > 0) ? 1.f : 0.f;
  __shared__ float l[256];
  l[threadIdx.x] = v;
  __syncthreads();
  for (int s = 128; s > 0; s >>= 1) {
    if (threadIdx.x < s) l[threadIdx.x] += l[threadIdx.x + s];
    __syncthreads();
  }
  if (threadIdx.x == 0 && l[0] != 0.f) atomicAdd(tslot, l[0]);
}

// CSR aggregation (bf16); emits tmask.
__global__ __launch_bounds__(256) void agg_kernel(
    const int* __restrict__ offs, const int2* __restrict__ pairs,
    const ushort* __restrict__ x, const ushort* __restrict__ feat,
    const float* __restrict__ deps, int layer, ushort* __restrict__ sbuf,
    int* __restrict__ tmask) {
  const int node = blockIdx.x * 4 + (threadIdx.x >> 6);
  const int lane = threadIdx.x & 63;
  const int gi = layer * Nn + node;
  const int o0 = offs[gi];
  const int o1 = offs[gi + 1];
  ushort2 fv = make_ushort2(0, 0);
  if (o1 > o0) fv = *(const ushort2*)&feat[(size_t)node * 128 + lane * 2];
  float ax = 0.f, ay = 0.f;
  for (int p = o0; p < o1; p += 2) {
    const int2 pr0 = pairs[p];
    const int2 pr1 = (p + 1 < o1) ? pairs[p + 1] : make_int2(0, 0);
    const ushort2 x0 = *(const ushort2*)&x[(size_t)pr0.x * 128 + lane * 2];
    const ushort2 x1 = *(const ushort2*)&x[(size_t)pr1.x * 128 + lane * 2];
    const float w0 = __int_as_float(pr0.y);
    const float w1 = __int_as_float(pr1.y);
    ax = fmaf(w0, bf_f(x0.x), ax);
    ay = fmaf(w0, bf_f(x0.y), ay);
    ax = fmaf(w1, bf_f(x1.x), ax);
    ay = fmaf(w1, bf_f(x1.y), ay);
  }
  if (o1 > o0) {
    const float c = 1.f + deps[layer];
    ax = fmaf(c, bf_f(fv.x), ax);
    ay = fmaf(c, bf_f(fv.y), ay);
  }
  ushort2 o;
  o.x = bf_hi(ax);
  o.y = bf_hi(ay);
  *(ushort2*)&sbuf[(size_t)node * 128 + lane * 2] = o;
  if (lane == 0) tmask[node] = (o1 > o0) ? 1 : 0;
}

// ---------------- readout: counting-sort pool ----------------
__global__ __launch_bounds__(256) void phist_kernel(const int* __restrict__ ridx,
                                                    const int* __restrict__ batch,
                                                    int* __restrict__ cnt, int n) {
  const int i = blockIdx.x * 256 + threadIdx.x;
  if (i >= n) return;
  atomicAdd(&cnt[batch[ridx[i]]], 1);
}

__global__ void pscan_kernel(int* __restrict__ cnt, int* __restrict__ cur) {
  __shared__ int l[256];
  const int t = threadIdx.x;
  const int v = cnt[t];
  l[t] = v;
  __syncthreads();
  for (int off = 1; off < 256; off <<= 1) {
    const int y = (t >= off) ? l[t - off] : 0;
    __syncthreads();
    l[t] += y;
    __syncthreads();
  }
  const int e = l[t] - v;  // exclusive
  cnt[t] = e;
  cur[t] = e;
}

__global__ __launch_bounds__(256) void pfill_kernel(const int* __restrict__ ridx,
                                                    const int* __restrict__ batch,
                                                    int* __restrict__ cur,
                                                    int* __restrict__ sorted,
                                                    int n) {
  const int i = blockIdx.x * 256 + threadIdx.x;
  if (i >= n) return;
  const int node = ridx[i];
  const int slot = atomicAdd(&cur[batch[node]], 1);
  sorted[slot] = node;
}

__global__ __launch_bounds__(256) void ppool_kernel(const int* __restrict__ sorted,
                                                    const int* __restrict__ offs,
                                                    const ushort* __restrict__ x,
                                                    float* __restrict__ P, int n) {
  __shared__ float part[4][256];
  const int g = blockIdx.x;
  const int w = threadIdx.x >> 6;
  const int lane = threadIdx.x & 63;
  const int o0 = offs[g];
  const int o1 = (g < Gg - 1) ? offs[g + 1] : n;
  float ax = 0.f, ay = 0.f;
  for (int p = o0 + w; p < o1; p += 4) {
    const int node = sorted[p];
    const ushort2 xv = *(const ushort2*)&x[(size_t)node * 128 + lane * 2];
    ax += bf_f(xv.x);
    ay += bf_f(xv.y);
  }
  part[w][lane * 2] = ax;
  part[w][lane * 2 + 1] = ay;
  __syncthreads();
  if (threadIdx.x < 128) {
    const int c = threadIdx.x;
    P[(size_t)g * 128 + c] = part[0][c] + part[1][c] + part[2][c] + part[3][c];
  }
}

__global__ void out_kernel(const float* __restrict__ P,
                           const float* __restrict__ Wl,
                           const float* __restrict__ bl,
                           float* __restrict__ out) {
  const int gid = blockIdx.x * blockDim.x + threadIdx.x;
  if (gid >= Gg * Tt) return;
  const int g = gid / Tt;
  const int t = gid - g * Tt;
  float acc = 0.f;
  for (int c = 0; c < 128; ++c) acc += P[g * 128 + c] * Wl[c * Tt + t];
  out[gid] = acc * 0.25f + bl[t];
}

extern "C" void kernel_launch(void* const* d_in, const int* in_sizes, int n_in,
                              void* d_out, int out_size, void* d_ws,
                              size_t ws_size, hipStream_t stream) {
  const float* dag_x = (const float*)d_in[0];
  const int* eidx = (const int*)d_in[1];
  const int* src = eidx;
  const int* dst = eidx + Ee;
  const float* mult = (const float*)d_in[2];
  const int* lmask = (const int*)d_in[3];
  const int* batch = (const int*)d_in[4];
  const int* leaves = (const int*)d_in[5];
  const int* readouts = (const int*)d_in[6];
  const float* W1 = (const float*)d_in[7];
  const float* b1 = (const float*)d_in[8];
  const float* g1 = (const float*)d_in[9];
  const float* be1 = (const float*)d_in[10];
  const float* W2 = (const float*)d_in[11];
  const float* b2 = (const float*)d_in[12];
  const float* g2 = (const float*)d_in[13];
  const float* be2 = (const float*)d_in[14];
  const float* dW1 = (const float*)d_in[15];
  const float* db1 = (const float*)d_in[16];
  const float* dg1 = (const float*)d_in[17];
  const float* dbe1 = (const float*)d_in[18];
  const float* dW2 = (const float*)d_in[19];
  const float* db2 = (const float*)d_in[20];
  const float* dg2 = (const float*)d_in[21];
  const float* dbe2 = (const float*)d_in[22];
  const float* deps = (const float*)d_in[23];
  const float* Wl = (const float*)d_in[24];
  const float* bl = (const float*)d_in[25];
  float* out = (float*)d_out;

  const size_t ND = (size_t)Nn * Dd;
  ushort* feat = (ushort*)d_ws;           // ND bf16
  ushort* xbuf = feat + ND;               // ND bf16
  ushort* Abuf = xbuf + ND;               // ND bf16
  ushort* Bbuf = Abuf + ND;               // ND bf16 (gemm ping-pong)
  float* statsAll = (float*)(Bbuf + ND);  // 8 slots x [16][512]
  float* tcountf = statsAll + 8 * 8192;   // 8 (4 used)
  int* tmask = (int*)(tcountf + 8);       // N
  ushort* wsT = (ushort*)(tmask + Nn);    // 262144 (8 weight slots, hi+lo)
  int* offs = (int*)(wsT + 262144);       // 3N+4
  int2* pairs = (int2*)(offs + 3 * Nn + 4);  // E pairs (src, mult)

  // transient overlays (xbuf region before it's initialized):
  int* cnts = (int*)xbuf;                 // 3N
  int* cursor = cnts + 3 * Nn;            // 3N
  int* bsum = cursor + 3 * Nn;            // 147
  const int nridx = in_sizes[6];          // 80000
  const int nleaves = in_sizes[5];        // 50000
  // pool overlays (Abuf dead by readout):
  int* pcnt = (int*)Abuf;                 // 256 (becomes offsets)
  int* pcur = pcnt + 256;                 // 256
  int* sorted = pcur + 256;               // nridx
  float* P = (float*)(sorted + nridx);    // G*D

  dim3 blk(256);
  hipMemsetAsync(statsAll, 0, 8 * 8192 * sizeof(float), stream);
  hipMemsetAsync(tcountf, 0, 8 * sizeof(float), stream);
  wsplit_kernel<<<512, blk, 0, stream>>>(W1, W2, dW1, dW2, wsT);

  // ---- CSR build ----
  hipMemsetAsync(cnts, 0, 3 * Nn * sizeof(int), stream);
  deg_count_kernel<<<2344, blk, 0, stream>>>(dst, lmask, cnts);
  for (int l = 0; l < Ll; ++l)
    tcount_kernel<<<391, blk, 0, stream>>>(cnts + l * Nn, tcountf + l);
  scan1_kernel<<<147, blk, 0, stream>>>(cnts, offs, bsum, 3 * Nn);
  scan2_kernel<<<1, blk, 0, stream>>>(bsum, 147);
  scan3_kernel<<<1172, blk, 0, stream>>>(offs, cursor, bsum, 3 * Nn, Ee);
  csr_fill_kernel<<<2344, blk, 0, stream>>>(src, dst, mult, lmask, cursor, pairs);

  const int gGemm = 782 * 2;
  // ---- node feature transform ----
  gemm_f32a<<<gGemm, blk, 0, stream>>>(dag_x, wsT, wsT + 16384, b1, Abuf,
                                       statsAll + 0 * 8192, Nn);
  gemm_bf16<true, false><<<gGemm, blk, 0, stream>>>(
      Abuf, wsT + 32768, wsT + 32768 + 16384, b2, statsAll + 0 * 8192, g1, be1,
      nullptr, nullptr, Bbuf, statsAll + 1 * 8192, Nn);
  normrelu_kernel<<<1563, blk, 0, stream>>>(Bbuf, statsAll + 1 * 8192, g2, be2,
                                            (float)Nn, feat);

  hipMemsetAsync(xbuf, 0, ND * sizeof(ushort), stream);
  scatter_leaves_kernel<<<6250, blk, 0, stream>>>(leaves, feat, xbuf, nleaves);

  // ---- DAG layers ----
  for (int layer = 0; layer < Ll; ++layer) {
    agg_kernel<<<25000, blk, 0, stream>>>(offs, pairs, xbuf, feat, deps, layer,
                                          Abuf, tmask);
    const int so1 = (2 + layer) * 32768;
    const int so2 = (5 + layer) * 32768;
    const int po = layer * Dd;
    float* st1 = statsAll + (size_t)(2 + 2 * layer) * 8192;
    float* st2 = statsAll + (size_t)(3 + 2 * layer) * 8192;
    gemm_bf16<false, true><<<gGemm, blk, 0, stream>>>(
        Abuf, wsT + so1, wsT + so1 + 16384, db1 + po, nullptr, nullptr,
        nullptr, nullptr, tmask, Bbuf, st1, Nn);
    gemm_bf16<true, true><<<gGemm, blk, 0, stream>>>(
        Bbuf, wsT + so2, wsT + so2 + 16384, db2 + po, st1, dg1 + po, dbe1 + po,
        tcountf + layer, tmask, Abuf, st2, Nn);
    normrelu_acc_kernel<<<1563, blk, 0, stream>>>(
        Abuf, st2, dg2 + po, dbe2 + po, tcountf + layer, tmask, xbuf);
  }

  // ---- readout (counting sort, no float atomics) ----
  hipMemsetAsync(pcnt, 0, 512 * sizeof(int), stream);
  const int gIdx = (nridx + 255) / 256;
  phist_kernel<<<gIdx, blk, 0, stream>>>(readouts, batch, pcnt, nridx);
  pscan_kernel<<<1, blk, 0, stream>>>(pcnt, pcur);
  pfill_kernel<<<gIdx, blk, 0, stream>>>(readouts, batch, pcur, sorted, nridx);
  ppool_kernel<<<Gg, blk, 0, stream>>>(sorted, pcnt, xbuf, P, nridx);
  out_kernel<<<10, blk, 0, stream>>>(P, Wl, bl, out);
}

// Round 8
// 556.606 us; speedup vs baseline: 4.0919x; 1.0755x over previous
//
#include <hip/hip_runtime.h>

constexpr int Nn = 100000;   // nodes
constexpr int Ee = 600000;   // edges
constexpr int Dd = 128;      // hidden dim
constexpr int Ll = 3;        // DAG layers
constexpr int Gg = 256;      // graphs
constexpr int Tt = 10;       // outputs per graph
constexpr float BN_EPS = 1e-5f;
constexpr int NREP = 16;     // stats replicas (slot = [16][512] floats)
constexpr int PSL = 8;       // pool slices per graph

typedef __attribute__((ext_vector_type(8))) short short8v;
typedef __attribute__((ext_vector_type(4))) float f32x4;

__device__ inline ushort bf_hi(float f) {
  unsigned u = __float_as_uint(f);
  unsigned r = (u + 0x7FFFu + ((u >> 16) & 1u)) >> 16;
  return (ushort)r;
}
__device__ inline float bf_f(ushort h) {
  return __uint_as_float(((unsigned)h) << 16);
}

// BN scale/shift from a replicated stats slot -> LDS ssS[256] (threads 0..127)
__device__ inline void compute_ss_lds(const float* __restrict__ stats,
                                      const float* __restrict__ g,
                                      const float* __restrict__ be, float cnt,
                                      float* ssS) {
  const int c = threadIdx.x;
  if (c < 128) {
    float S = 0.f, Q = 0.f;
#pragma unroll
    for (int r = 0; r < NREP; ++r) {
      S += stats[r * 512 + c];
      Q += stats[r * 512 + 256 + c];
    }
    const float m = S / cnt;
    const float v = Q / cnt - m * m;
    const float sc = g[c] * rsqrtf(v + BN_EPS);
    ssS[c] = sc;
    ssS[128 + c] = be[c] - m * sc;
  }
}

// ---------------------------------------------------------------------------
// B-resident barrier-free GEMM (bf16 A): C[N][64-slice] = op(A)@W + bias.
// Tile 128 rows x 64 cols; grid 782*2. B staged once (XOR-swizzled); A
// prefetched to regs; zero barriers in K-loop. Epilogue: acc->LDS bounce ->
// 16B vector stores; stats partials -> replica atomics.
// ---------------------------------------------------------------------------
template <bool NORM_A, bool MASKED>
__global__ __launch_bounds__(256, 4) void gemm_bf16(
    const ushort* __restrict__ A, const ushort* __restrict__ WTh,
    const ushort* __restrict__ WTl, const float* __restrict__ bias,
    const float* __restrict__ statsIn, const float* __restrict__ gN,
    const float* __restrict__ beN, const float* __restrict__ cntPtr,
    const int* __restrict__ tmask, ushort* __restrict__ C,
    float* __restrict__ statsOut, int nrows) {
  __shared__ ushort SB[16384];  // Bh[8192] | Bl[8192]; reused: Cs[128][72]+red
  __shared__ float ssS[256];
  ushort* Bh = SB;
  ushort* Bl = SB + 8192;
  const int tid = threadIdx.x;
  const int w = tid >> 6, lane = tid & 63, lr = lane & 15, lg = lane >> 4;
  const int rt = blockIdx.x >> 1, ct = blockIdx.x & 1;
  const int rowBase = rt * 128, cBase = ct * 64;
  const int rep = blockIdx.x & (NREP - 1);

  // ---- stage B once (swizzle: byte ^= (col&7)<<4 within 256B row) ----
  {
    const int cc = tid >> 2;
    const ushort* sH = WTh + (size_t)(cBase + cc) * 128;
    const ushort* sL = WTl + (size_t)(cBase + cc) * 128;
    char* BhB = (char*)Bh;
    char* BlB = (char*)Bl;
#pragma unroll
    for (int i = 0; i < 4; ++i) {
      const int slot = (tid & 3) * 4 + i;
      const int off = (cc * 256 + slot * 16) ^ ((cc & 7) << 4);
      *(short8v*)(BhB + off) = *(const short8v*)(sH + slot * 8);
      *(short8v*)(BlB + off) = *(const short8v*)(sL + slot * 8);
    }
  }
  if (NORM_A) {
    const float cnt = cntPtr ? fmaxf(cntPtr[0], 1.f) : (float)nrows;
    compute_ss_lds(statsIn, gN, beN, cnt, ssS);
  }

  // ---- prefetch all A fragments ----
  const int row0 = rowBase + w * 32 + lr;
  const int row1 = row0 + 16;
  const bool ok0 = row0 < nrows, ok1 = row1 < nrows;
  const short8v szero = {0, 0, 0, 0, 0, 0, 0, 0};
  const ushort* aP0 = A + (size_t)row0 * 128 + lg * 8;
  const ushort* aP1 = A + (size_t)row1 * 128 + lg * 8;
  short8v ar0[4], ar1[4];
#pragma unroll
  for (int c = 0; c < 4; ++c) {
    ar0[c] = ok0 ? *(const short8v*)(aP0 + c * 32) : szero;
    ar1[c] = ok1 ? *(const short8v*)(aP1 + c * 32) : szero;
  }
  __syncthreads();

  const f32x4 fzero = {0.f, 0.f, 0.f, 0.f};
  f32x4 acc[2][4];
#pragma unroll
  for (int i = 0; i < 2; ++i)
#pragma unroll
    for (int j = 0; j < 4; ++j) acc[i][j] = fzero;

  const char* BhB = (const char*)Bh;
  const char* BlB = (const char*)Bl;
  __builtin_amdgcn_s_setprio(1);
#pragma unroll
  for (int c = 0; c < 4; ++c) {
    short8v a0 = ar0[c], a1 = ar1[c];
    if (NORM_A) {
      const int kb = c * 32 + lg * 8;
      const float4 s0 = *(const float4*)&ssS[kb];
      const float4 s1 = *(const float4*)&ssS[kb + 4];
      const float4 h0 = *(const float4*)&ssS[128 + kb];
      const float4 h1 = *(const float4*)&ssS[128 + kb + 4];
      const float sv[8] = {s0.x, s0.y, s0.z, s0.w, s1.x, s1.y, s1.z, s1.w};
      const float hv[8] = {h0.x, h0.y, h0.z, h0.w, h1.x, h1.y, h1.z, h1.w};
#pragma unroll
      for (int j = 0; j < 8; ++j) {
        a0[j] = (short)bf_hi(fmaxf(fmaf(bf_f((ushort)a0[j]), sv[j], hv[j]), 0.f));
        a1[j] = (short)bf_hi(fmaxf(fmaf(bf_f((ushort)a1[j]), sv[j], hv[j]), 0.f));
      }
    }
#pragma unroll
    for (int nf = 0; nf < 4; ++nf) {
      const int brow = nf * 16 + lr;
      const int off = (brow * 256 + (c * 4 + lg) * 16) ^ ((lr & 7) << 4);
      const short8v bh = *(const short8v*)(BhB + off);
      const short8v bl = *(const short8v*)(BlB + off);
      acc[0][nf] = __builtin_amdgcn_mfma_f32_16x16x32_bf16(a0, bh, acc[0][nf], 0, 0, 0);
      acc[1][nf] = __builtin_amdgcn_mfma_f32_16x16x32_bf16(a1, bh, acc[1][nf], 0, 0, 0);
      acc[0][nf] = __builtin_amdgcn_mfma_f32_16x16x32_bf16(a0, bl, acc[0][nf], 0, 0, 0);
      acc[1][nf] = __builtin_amdgcn_mfma_f32_16x16x32_bf16(a1, bl, acc[1][nf], 0, 0, 0);
    }
  }
  __builtin_amdgcn_s_setprio(0);

  // ---- epilogue: acc -> LDS bounce; stats partials ----
  float mrow[2][4];
#pragma unroll
  for (int mf = 0; mf < 2; ++mf)
#pragma unroll
    for (int rr = 0; rr < 4; ++rr) {
      const int row = rowBase + w * 32 + mf * 16 + lg * 4 + rr;
      float m = 0.f;
      if (row < nrows) m = MASKED ? ((tmask[row] > 0) ? 1.f : 0.f) : 1.f;
      mrow[mf][rr] = m;
    }
  __syncthreads();  // all waves done reading B
  ushort* Cs = SB;                      // [128][72]
  float* Sred = (float*)(SB + 9216);    // [4][64]
  float* Sq = Sred + 256;               // [4][64]
#pragma unroll
  for (int nf = 0; nf < 4; ++nf) {
    const int col = nf * 16 + lr;
    const float bcol = bias[cBase + col];
    float ps = 0.f, pq = 0.f;
#pragma unroll
    for (int mf = 0; mf < 2; ++mf) {
      const f32x4 vv = acc[mf][nf];
#pragma unroll
      for (int rr = 0; rr < 4; ++rr) {
        const float o = vv[rr] + bcol;
        const int rl = w * 32 + mf * 16 + lg * 4 + rr;
        Cs[rl * 72 + col] = bf_hi(o);
        const float mo = mrow[mf][rr] * o;
        ps += mo;
        pq += mo * o;
      }
    }
    ps += __shfl_xor(ps, 16);
    ps += __shfl_xor(ps, 32);
    pq += __shfl_xor(pq, 16);
    pq += __shfl_xor(pq, 32);
    if (lg == 0) {
      Sred[w * 64 + col] = ps;
      Sq[w * 64 + col] = pq;
    }
  }
  __syncthreads();
  {
    const int rl = tid >> 1, half = tid & 1;
    const int grow = rowBase + rl;
    if (grow < nrows) {
      ushort* dstp = C + (size_t)grow * 128 + cBase + half * 32;
      const ushort* srcp = Cs + rl * 72 + half * 32;
#pragma unroll
      for (int j = 0; j < 4; ++j)
        *(short8v*)(dstp + j * 8) = *(const short8v*)(srcp + j * 8);
    }
  }
  if (tid < 64) {
    float s = 0.f;
#pragma unroll
    for (int q = 0; q < 4; ++q) s += Sred[q * 64 + tid];
    atomicAdd(&statsOut[rep * 512 + cBase + tid], s);
  } else if (tid < 128) {
    float s = 0.f;
#pragma unroll
    for (int q = 0; q < 4; ++q) s += Sq[q * 64 + tid - 64];
    atomicAdd(&statsOut[rep * 512 + 256 + cBase + tid - 64], s);
  }
}

// ---------------------------------------------------------------------------
// GEMM #1: fp32 A (dag_x), K=64, hi/lo-split A (3 MFMAs). Same epilogue.
// ---------------------------------------------------------------------------
__global__ __launch_bounds__(256, 4) void gemm_f32a(
    const float* __restrict__ A, const ushort* __restrict__ WTh,
    const ushort* __restrict__ WTl, const float* __restrict__ bias,
    ushort* __restrict__ C, float* __restrict__ statsOut, int nrows) {
  __shared__ ushort SB[11264];  // Bh[4096] | Bl[4096]; reused Cs[128][72]+red
  ushort* Bh = SB;
  ushort* Bl = SB + 4096;
  const int tid = threadIdx.x;
  const int w = tid >> 6, lane = tid & 63, lr = lane & 15, lg = lane >> 4;
  const int rt = blockIdx.x >> 1, ct = blockIdx.x & 1;
  const int rowBase = rt * 128, cBase = ct * 64;
  const int rep = blockIdx.x & (NREP - 1);

  {
    const int cc = tid >> 2;
    const ushort* sH = WTh + (size_t)(cBase + cc) * 64;
    const ushort* sL = WTl + (size_t)(cBase + cc) * 64;
    char* BhB = (char*)Bh;
    char* BlB = (char*)Bl;
#pragma unroll
    for (int i = 0; i < 2; ++i) {
      const int slot = (tid & 3) * 2 + i;
      const int off = (cc * 128 + slot * 16) ^ ((cc & 7) << 4);
      *(short8v*)(BhB + off) = *(const short8v*)(sH + slot * 8);
      *(short8v*)(BlB + off) = *(const short8v*)(sL + slot * 8);
    }
  }

  const int row0 = rowBase + w * 32 + lr;
  const int row1 = row0 + 16;
  const bool ok0 = row0 < nrows, ok1 = row1 < nrows;
  const float4 fz4 = make_float4(0.f, 0.f, 0.f, 0.f);
  const float* aP0 = A + (size_t)row0 * 64 + lg * 8;
  const float* aP1 = A + (size_t)row1 * 64 + lg * 8;
  float4 ar0[2][2], ar1[2][2];
#pragma unroll
  for (int c = 0; c < 2; ++c) {
    ar0[c][0] = ok0 ? *(const float4*)(aP0 + c * 32) : fz4;
    ar0[c][1] = ok0 ? *(const float4*)(aP0 + c * 32 + 4) : fz4;
    ar1[c][0] = ok1 ? *(const float4*)(aP1 + c * 32) : fz4;
    ar1[c][1] = ok1 ? *(const float4*)(aP1 + c * 32 + 4) : fz4;
  }
  __syncthreads();

  const f32x4 fzero = {0.f, 0.f, 0.f, 0.f};
  f32x4 acc[2][4];
#pragma unroll
  for (int i = 0; i < 2; ++i)
#pragma unroll
    for (int j = 0; j < 4; ++j) acc[i][j] = fzero;

  const char* BhB = (const char*)Bh;
  const char* BlB = (const char*)Bl;
  __builtin_amdgcn_s_setprio(1);
#pragma unroll
  for (int c = 0; c < 2; ++c) {
    const float v0[8] = {ar0[c][0].x, ar0[c][0].y, ar0[c][0].z, ar0[c][0].w,
                         ar0[c][1].x, ar0[c][1].y, ar0[c][1].z, ar0[c][1].w};
    const float v1[8] = {ar1[c][0].x, ar1[c][0].y, ar1[c][0].z, ar1[c][0].w,
                         ar1[c][1].x, ar1[c][1].y, ar1[c][1].z, ar1[c][1].w};
    short8v a0h, a0l, a1h, a1l;
#pragma unroll
    for (int j = 0; j < 8; ++j) {
      ushort hh = bf_hi(v0[j]);
      a0h[j] = (short)hh;
      a0l[j] = (short)bf_hi(v0[j] - bf_f(hh));
      hh = bf_hi(v1[j]);
      a1h[j] = (short)hh;
      a1l[j] = (short)bf_hi(v1[j] - bf_f(hh));
    }
#pragma unroll
    for (int nf = 0; nf < 4; ++nf) {
      const int brow = nf * 16 + lr;
      const int off = (brow * 128 + (c * 4 + lg) * 16) ^ ((lr & 7) << 4);
      const short8v bh = *(const short8v*)(BhB + off);
      const short8v bl = *(const short8v*)(BlB + off);
      acc[0][nf] = __builtin_amdgcn_mfma_f32_16x16x32_bf16(a0h, bh, acc[0][nf], 0, 0, 0);
      acc[1][nf] = __builtin_amdgcn_mfma_f32_16x16x32_bf16(a1h, bh, acc[1][nf], 0, 0, 0);
      acc[0][nf] = __builtin_amdgcn_mfma_f32_16x16x32_bf16(a0l, bh, acc[0][nf], 0, 0, 0);
      acc[1][nf] = __builtin_amdgcn_mfma_f32_16x16x32_bf16(a1l, bh, acc[1][nf], 0, 0, 0);
      acc[0][nf] = __builtin_amdgcn_mfma_f32_16x16x32_bf16(a0h, bl, acc[0][nf], 0, 0, 0);
      acc[1][nf] = __builtin_amdgcn_mfma_f32_16x16x32_bf16(a1h, bl, acc[1][nf], 0, 0, 0);
    }
  }
  __builtin_amdgcn_s_setprio(0);

  __syncthreads();
  ushort* Cs = SB;                    // [128][72]
  float* Sred = (float*)(SB + 9216);  // [4][64]
  float* Sq = Sred + 256;
#pragma unroll
  for (int nf = 0; nf < 4; ++nf) {
    const int col = nf * 16 + lr;
    const float bcol = bias[cBase + col];
    float ps = 0.f, pq = 0.f;
#pragma unroll
    for (int mf = 0; mf < 2; ++mf) {
      const f32x4 vv = acc[mf][nf];
#pragma unroll
      for (int rr = 0; rr < 4; ++rr) {
        const float o = vv[rr] + bcol;
        const int rl = w * 32 + mf * 16 + lg * 4 + rr;
        Cs[rl * 72 + col] = bf_hi(o);
        const int row = rowBase + rl;
        const float m = (row < nrows) ? 1.f : 0.f;
        const float mo = m * o;
        ps += mo;
        pq += mo * o;
      }
    }
    ps += __shfl_xor(ps, 16);
    ps += __shfl_xor(ps, 32);
    pq += __shfl_xor(pq, 16);
    pq += __shfl_xor(pq, 32);
    if (lg == 0) {
      Sred[w * 64 + col] = ps;
      Sq[w * 64 + col] = pq;
    }
  }
  __syncthreads();
  {
    const int rl = tid >> 1, half = tid & 1;
    const int grow = rowBase + rl;
    if (grow < nrows) {
      ushort* dstp = C + (size_t)grow * 128 + cBase + half * 32;
      const ushort* srcp = Cs + rl * 72 + half * 32;
#pragma unroll
      for (int j = 0; j < 4; ++j)
        *(short8v*)(dstp + j * 8) = *(const short8v*)(srcp + j * 8);
    }
  }
  if (tid < 64) {
    float s = 0.f;
#pragma unroll
    for (int q = 0; q < 4; ++q) s += Sred[q * 64 + tid];
    atomicAdd(&statsOut[rep * 512 + cBase + tid], s);
  } else if (tid < 128) {
    float s = 0.f;
#pragma unroll
    for (int q = 0; q < 4; ++q) s += Sq[q * 64 + tid - 64];
    atomicAdd(&statsOut[rep * 512 + 256 + cBase + tid - 64], s);
  }
}

// Weight transpose + hi/lo split: 8 slots of 32768 ushorts (hi, lo@+16384)
__global__ __launch_bounds__(256) void wsplit_kernel(
    const float* __restrict__ W1, const float* __restrict__ W2,
    const float* __restrict__ dW1, const float* __restrict__ dW2,
    ushort* __restrict__ wsT) {
  const int t = blockIdx.x * 256 + threadIdx.x;
  const int slot = t >> 14;
  const int idx = t & 16383;
  if (slot >= 8) return;
  const int Ks = (slot == 0) ? 64 : 128;
  if (idx >= 128 * Ks) return;
  const int c = idx / Ks;
  const int k = idx - c * Ks;
  float v;
  if (slot == 0) v = W1[k * 128 + c];
  else if (slot == 1) v = W2[k * 128 + c];
  else if (slot < 5) v = dW1[(slot - 2) * 16384 + k * 128 + c];
  else v = dW2[(slot - 5) * 16384 + k * 128 + c];
  const ushort h = bf_hi(v);
  const ushort l = bf_hi(v - bf_f(h));
  wsT[slot * 32768 + c * Ks + k] = h;
  wsT[slot * 32768 + 16384 + c * Ks + k] = l;
}

// feat = relu(y*sc+sh); ss computed per block. 64 rows/block.
__global__ __launch_bounds__(256) void normrelu_kernel(
    const ushort* __restrict__ in, const float* __restrict__ stats,
    const float* __restrict__ g, const float* __restrict__ be, float cntFixed,
    ushort* __restrict__ outp) {
  __shared__ float ssS[256];
  compute_ss_lds(stats, g, be, cntFixed, ssS);
  __syncthreads();
  const int tid = threadIdx.x;
  const int c4 = (tid & 31) * 4;
  const float4 sc = *(const float4*)&ssS[c4];
  const float4 sh = *(const float4*)&ssS[128 + c4];
  const int rowBase = blockIdx.x * 64;
#pragma unroll
  for (int it = 0; it < 8; ++it) {
    const int row = rowBase + it * 8 + (tid >> 5);
    if (row >= Nn) continue;
    const size_t idx = (size_t)row * 32 + (tid & 31);
    const ushort4 v = ((const ushort4*)in)[idx];
    ushort4 o;
    o.x = bf_hi(fmaxf(fmaf(bf_f(v.x), sc.x, sh.x), 0.f));
    o.y = bf_hi(fmaxf(fmaf(bf_f(v.y), sc.y, sh.y), 0.f));
    o.z = bf_hi(fmaxf(fmaf(bf_f(v.z), sc.z, sh.z), 0.f));
    o.w = bf_hi(fmaxf(fmaf(bf_f(v.w), sc.w, sh.w), 0.f));
    ((ushort4*)outp)[idx] = o;
  }
}

// x += (tmask>0) * relu(y*sc+sh)
__global__ __launch_bounds__(256) void normrelu_acc_kernel(
    const ushort* __restrict__ in, const float* __restrict__ stats,
    const float* __restrict__ g, const float* __restrict__ be,
    const float* __restrict__ cntPtr, const int* __restrict__ tmask,
    ushort* __restrict__ x) {
  __shared__ float ssS[256];
  compute_ss_lds(stats, g, be, fmaxf(cntPtr[0], 1.f), ssS);
  __syncthreads();
  const int tid = threadIdx.x;
  const int c4 = (tid & 31) * 4;
  const float4 sc = *(const float4*)&ssS[c4];
  const float4 sh = *(const float4*)&ssS[128 + c4];
  const int rowBase = blockIdx.x * 64;
#pragma unroll
  for (int it = 0; it < 8; ++it) {
    const int row = rowBase + it * 8 + (tid >> 5);
    if (row >= Nn || tmask[row] <= 0) continue;
    const size_t idx = (size_t)row * 32 + (tid & 31);
    const ushort4 v = ((const ushort4*)in)[idx];
    ushort4 xo = ((const ushort4*)x)[idx];
    xo.x = bf_hi(bf_f(xo.x) + fmaxf(fmaf(bf_f(v.x), sc.x, sh.x), 0.f));
    xo.y = bf_hi(bf_f(xo.y) + fmaxf(fmaf(bf_f(v.y), sc.y, sh.y), 0.f));
    xo.z = bf_hi(bf_f(xo.z) + fmaxf(fmaf(bf_f(v.z), sc.z, sh.z), 0.f));
    xo.w = bf_hi(bf_f(xo.w) + fmaxf(fmaf(bf_f(v.w), sc.w, sh.w), 0.f));
    ((ushort4*)x)[idx] = xo;
  }
}

__global__ __launch_bounds__(256) void scatter_leaves_kernel(
    const int* __restrict__ leaves, const ushort* __restrict__ feat,
    ushort* __restrict__ x, int nl) {
  const int gid = blockIdx.x * 256 + threadIdx.x;
  const int j = gid >> 5;
  if (j >= nl) return;
  const int node = leaves[j];
  const int c4 = (gid & 31) * 4;
  *(ushort4*)&x[(size_t)node * 128 + c4] =
      *(const ushort4*)&feat[(size_t)node * 128 + c4];
}

// ---------------- CSR build ----------------
__global__ __launch_bounds__(256) void deg_count_kernel(
    const int* __restrict__ dst, const int* __restrict__ lmask,
    int* __restrict__ cnts) {
  const int e = blockIdx.x * 256 + threadIdx.x;
  if (e >= Ee) return;
  atomicAdd(&cnts[lmask[e] * Nn + dst[e]], 1);
}

// scan1 + fused per-layer target count (nodes with deg>0) -> tcountf[0..2]
__global__ __launch_bounds__(256) void scan1_kernel(const int* __restrict__ in,
                                                    int* __restrict__ out,
                                                    int* __restrict__ bsum,
                                                    float* __restrict__ tcountf,
                                                    int n) {
  __shared__ int lds[256];
  __shared__ float tcS[3];
  const int tid = threadIdx.x;
  const int base = blockIdx.x * 2048 + tid * 8;
  int vals[8];
  int tsum = 0;
  float t0 = 0.f, t1 = 0.f, t2 = 0.f;
#pragma unroll
  for (int j = 0; j < 8; ++j) {
    const int i = base + j;
    const int v = (i < n) ? in[i] : 0;
    if (v > 0) {
      if (i < Nn) t0 += 1.f;
      else if (i < 2 * Nn) t1 += 1.f;
      else t2 += 1.f;
    }
    vals[j] = tsum;
    tsum += v;
  }
  lds[tid] = tsum;
  if (tid < 3) tcS[tid] = 0.f;
  __syncthreads();
  if (t0 != 0.f) atomicAdd(&tcS[0], t0);
  if (t1 != 0.f) atomicAdd(&tcS[1], t1);
  if (t2 != 0.f) atomicAdd(&tcS[2], t2);
  for (int off = 1; off < 256; off <<= 1) {
    const int y = (tid >= off) ? lds[tid - off] : 0;
    __syncthreads();
    lds[tid] += y;
    __syncthreads();
  }
  const int texcl = (tid > 0) ? lds[tid - 1] : 0;
#pragma unroll
  for (int j = 0; j < 8; ++j)
    if (base + j < n) out[base + j] = texcl + vals[j];
  if (tid == 255) bsum[blockIdx.x] = lds[255];
  __syncthreads();
  if (tid < 3 && tcS[tid] != 0.f) atomicAdd(&tcountf[tid], tcS[tid]);
}

__global__ void scan2_kernel(int* __restrict__ bsum, int nb) {
  __shared__ int lds[256];
  const int tid = threadIdx.x;
  const int v = (tid < nb) ? bsum[tid] : 0;
  lds[tid] = v;
  __syncthreads();
  for (int off = 1; off < 256; off <<= 1) {
    const int y = (tid >= off) ? lds[tid - off] : 0;
    __syncthreads();
    lds[tid] += y;
    __syncthreads();
  }
  if (tid < nb) bsum[tid] = lds[tid] - v;  // exclusive
}

__global__ __launch_bounds__(256) void scan3_kernel(int* __restrict__ out,
                                                    int* __restrict__ cursor,
                                                    const int* __restrict__ bsum,
                                                    int n, int etot) {
  const int i = blockIdx.x * 256 + threadIdx.x;
  if (i >= n) return;
  const int v = out[i] + bsum[i >> 11];
  out[i] = v;
  cursor[i] = v;
  if (i == n - 1) out[n] = etot;
}

__global__ __launch_bounds__(256) void csr_fill_kernel(
    const int* __restrict__ src, const int* __restrict__ dst,
    const float* __restrict__ mult, const int* __restrict__ lmask,
    int* __restrict__ cursor, int2* __restrict__ pairs) {
  const int e = blockIdx.x * 256 + threadIdx.x;
  if (e >= Ee) return;
  const int slot = atomicAdd(&cursor[lmask[e] * Nn + dst[e]], 1);
  pairs[slot] = make_int2(src[e], __float_as_int(mult[e]));
}

// CSR aggregation (bf16); emits tmask.
__global__ __launch_bounds__(256) void agg_kernel(
    const int* __restrict__ offs, const int2* __restrict__ pairs,
    const ushort* __restrict__ x, const ushort* __restrict__ feat,
    const float* __restrict__ deps, int layer, ushort* __restrict__ sbuf,
    int* __restrict__ tmask) {
  const int node = blockIdx.x * 4 + (threadIdx.x >> 6);
  const int lane = threadIdx.x & 63;
  const int gi = layer * Nn + node;
  const int o0 = offs[gi];
  const int o1 = offs[gi + 1];
  ushort2 fv = make_ushort2(0, 0);
  if (o1 > o0) fv = *(const ushort2*)&feat[(size_t)node * 128 + lane * 2];
  float ax = 0.f, ay = 0.f;
  for (int p = o0; p < o1; p += 2) {
    const int2 pr0 = pairs[p];
    const int2 pr1 = (p + 1 < o1) ? pairs[p + 1] : make_int2(0, 0);
    const ushort2 x0 = *(const ushort2*)&x[(size_t)pr0.x * 128 + lane * 2];
    const ushort2 x1 = *(const ushort2*)&x[(size_t)pr1.x * 128 + lane * 2];
    const float w0 = __int_as_float(pr0.y);
    const float w1 = __int_as_float(pr1.y);
    ax = fmaf(w0, bf_f(x0.x), ax);
    ay = fmaf(w0, bf_f(x0.y), ay);
    ax = fmaf(w1, bf_f(x1.x), ax);
    ay = fmaf(w1, bf_f(x1.y), ay);
  }
  if (o1 > o0) {
    const float c = 1.f + deps[layer];
    ax = fmaf(c, bf_f(fv.x), ax);
    ay = fmaf(c, bf_f(fv.y), ay);
  }
  ushort2 o;
  o.x = bf_hi(ax);
  o.y = bf_hi(ay);
  *(ushort2*)&sbuf[(size_t)node * 128 + lane * 2] = o;
  if (lane == 0) tmask[node] = (o1 > o0) ? 1 : 0;
}

// ---------------- readout: counting-sort pool ----------------
__global__ __launch_bounds__(256) void phist_kernel(const int* __restrict__ ridx,
                                                    const int* __restrict__ batch,
                                                    int* __restrict__ cnt, int n) {
  const int i = blockIdx.x * 256 + threadIdx.x;
  if (i >= n) return;
  atomicAdd(&cnt[batch[ridx[i]]], 1);
}

__global__ void pscan_kernel(int* __restrict__ cnt, int* __restrict__ cur) {
  __shared__ int l[256];
  const int t = threadIdx.x;
  const int v = cnt[t];
  l[t] = v;
  __syncthreads();
  for (int off = 1; off < 256; off <<= 1) {
    const int y = (t >= off) ? l[t - off] : 0;
    __syncthreads();
    l[t] += y;
    __syncthreads();
  }
  const int e = l[t] - v;  // exclusive
  cnt[t] = e;
  cur[t] = e;
}

__global__ __launch_bounds__(256) void pfill_kernel(const int* __restrict__ ridx,
                                                    const int* __restrict__ batch,
                                                    int* __restrict__ cur,
                                                    int* __restrict__ sorted,
                                                    int n) {
  const int i = blockIdx.x * 256 + threadIdx.x;
  if (i >= n) return;
  const int node = ridx[i];
  const int slot = atomicAdd(&cur[batch[node]], 1);
  sorted[slot] = node;
}

// Parallel pool: 8 slices per graph -> Ppart[g*8+slice][128] (no atomics)
__global__ __launch_bounds__(256) void ppool_kernel(const int* __restrict__ sorted,
                                                    const int* __restrict__ offs,
                                                    const ushort* __restrict__ x,
                                                    float* __restrict__ Ppart,
                                                    int n) {
  __shared__ float part[4][256];
  const int bid = blockIdx.x;
  const int g = bid >> 3, slice = bid & (PSL - 1);
  const int w = threadIdx.x >> 6;
  const int lane = threadIdx.x & 63;
  const int o0 = offs[g];
  const int o1 = (g < Gg - 1) ? offs[g + 1] : n;
  float ax = 0.f, ay = 0.f;
  for (int p = o0 + slice * 4 + w; p < o1; p += 32) {
    const int node = sorted[p];
    const ushort2 xv = *(const ushort2*)&x[(size_t)node * 128 + lane * 2];
    ax += bf_f(xv.x);
    ay += bf_f(xv.y);
  }
  part[w][lane * 2] = ax;
  part[w][lane * 2 + 1] = ay;
  __syncthreads();
  if (threadIdx.x < 128) {
    const int c = threadIdx.x;
    Ppart[(size_t)bid * 128 + c] =
        part[0][c] + part[1][c] + part[2][c] + part[3][c];
  }
}

// P[g][c] = sum over 8 slices
__global__ __launch_bounds__(256) void preduce_kernel(
    const float* __restrict__ Ppart, float* __restrict__ P) {
  const int gid = blockIdx.x * 256 + threadIdx.x;  // 32768
  const int g = gid >> 7, c = gid & 127;
  float s = 0.f;
#pragma unroll
  for (int t = 0; t < PSL; ++t) s += Ppart[(size_t)(g * PSL + t) * 128 + c];
  P[gid] = s;
}

__global__ void out_kernel(const float* __restrict__ P,
                           const float* __restrict__ Wl,
                           const float* __restrict__ bl,
                           float* __restrict__ out) {
  const int gid = blockIdx.x * blockDim.x + threadIdx.x;
  if (gid >= Gg * Tt) return;
  const int g = gid / Tt;
  const int t = gid - g * Tt;
  float acc = 0.f;
  for (int c = 0; c < 128; ++c) acc += P[g * 128 + c] * Wl[c * Tt + t];
  out[gid] = acc * 0.25f + bl[t];
}

extern "C" void kernel_launch(void* const* d_in, const int* in_sizes, int n_in,
                              void* d_out, int out_size, void* d_ws,
                              size_t ws_size, hipStream_t stream) {
  const float* dag_x = (const float*)d_in[0];
  const int* eidx = (const int*)d_in[1];
  const int* src = eidx;
  const int* dst = eidx + Ee;
  const float* mult = (const float*)d_in[2];
  const int* lmask = (const int*)d_in[3];
  const int* batch = (const int*)d_in[4];
  const int* leaves = (const int*)d_in[5];
  const int* readouts = (const int*)d_in[6];
  const float* W1 = (const float*)d_in[7];
  const float* b1 = (const float*)d_in[8];
  const float* g1 = (const float*)d_in[9];
  const float* be1 = (const float*)d_in[10];
  const float* W2 = (const float*)d_in[11];
  const float* b2 = (const float*)d_in[12];
  const float* g2 = (const float*)d_in[13];
  const float* be2 = (const float*)d_in[14];
  const float* dW1 = (const float*)d_in[15];
  const float* db1 = (const float*)d_in[16];
  const float* dg1 = (const float*)d_in[17];
  const float* dbe1 = (const float*)d_in[18];
  const float* dW2 = (const float*)d_in[19];
  const float* db2 = (const float*)d_in[20];
  const float* dg2 = (const float*)d_in[21];
  const float* dbe2 = (const float*)d_in[22];
  const float* deps = (const float*)d_in[23];
  const float* Wl = (const float*)d_in[24];
  const float* bl = (const float*)d_in[25];
  float* out = (float*)d_out;

  const size_t ND = (size_t)Nn * Dd;
  ushort* feat = (ushort*)d_ws;           // ND bf16
  ushort* xbuf = feat + ND;               // ND bf16
  ushort* Abuf = xbuf + ND;               // ND bf16
  ushort* Bbuf = Abuf + ND;               // ND bf16 (gemm ping-pong)
  float* statsAll = (float*)(Bbuf + ND);  // 8 slots x [16][512]
  float* tcountf = statsAll + 8 * 8192;   // 8 (4 used) -- adjacent for memset
  int* tmask = (int*)(tcountf + 8);       // N
  ushort* wsT = (ushort*)(tmask + Nn);    // 262144 (8 weight slots, hi+lo)
  int* offs = (int*)(wsT + 262144);       // 3N+4
  int2* pairs = (int2*)(offs + 3 * Nn + 4);  // E pairs (src, mult)

  // transient overlays (xbuf region before it's initialized):
  int* cnts = (int*)xbuf;                 // 3N
  int* cursor = cnts + 3 * Nn;            // 3N
  int* bsum = cursor + 3 * Nn;            // 147
  const int nridx = in_sizes[6];          // 80000
  const int nleaves = in_sizes[5];        // 50000
  // pool overlays (Abuf dead by readout):
  int* pcnt = (int*)Abuf;                 // 256 (becomes offsets)
  int* pcur = pcnt + 256;                 // 256
  int* sorted = pcur + 256;               // nridx
  float* Ppart = (float*)(sorted + nridx);  // 2048*128
  float* P = Ppart + Gg * PSL * 128;        // 256*128

  dim3 blk(256);
  hipMemsetAsync(statsAll, 0, (8 * 8192 + 8) * sizeof(float), stream);
  wsplit_kernel<<<512, blk, 0, stream>>>(W1, W2, dW1, dW2, wsT);

  // ---- CSR build (tcount fused into scan1) ----
  hipMemsetAsync(cnts, 0, 3 * Nn * sizeof(int), stream);
  deg_count_kernel<<<2344, blk, 0, stream>>>(dst, lmask, cnts);
  scan1_kernel<<<147, blk, 0, stream>>>(cnts, offs, bsum, tcountf, 3 * Nn);
  scan2_kernel<<<1, blk, 0, stream>>>(bsum, 147);
  scan3_kernel<<<1172, blk, 0, stream>>>(offs, cursor, bsum, 3 * Nn, Ee);
  csr_fill_kernel<<<2344, blk, 0, stream>>>(src, dst, mult, lmask, cursor, pairs);

  const int gGemm = 782 * 2;
  // ---- node feature transform ----
  gemm_f32a<<<gGemm, blk, 0, stream>>>(dag_x, wsT, wsT + 16384, b1, Abuf,
                                       statsAll + 0 * 8192, Nn);
  gemm_bf16<true, false><<<gGemm, blk, 0, stream>>>(
      Abuf, wsT + 32768, wsT + 32768 + 16384, b2, statsAll + 0 * 8192, g1, be1,
      nullptr, nullptr, Bbuf, statsAll + 1 * 8192, Nn);
  normrelu_kernel<<<1563, blk, 0, stream>>>(Bbuf, statsAll + 1 * 8192, g2, be2,
                                            (float)Nn, feat);

  hipMemsetAsync(xbuf, 0, ND * sizeof(ushort), stream);
  scatter_leaves_kernel<<<6250, blk, 0, stream>>>(leaves, feat, xbuf, nleaves);

  // ---- DAG layers ----
  for (int layer = 0; layer < Ll; ++layer) {
    agg_kernel<<<25000, blk, 0, stream>>>(offs, pairs, xbuf, feat, deps, layer,
                                          Abuf, tmask);
    const int so1 = (2 + layer) * 32768;
    const int so2 = (5 + layer) * 32768;
    const int po = layer * Dd;
    float* st1 = statsAll + (size_t)(2 + 2 * layer) * 8192;
    float* st2 = statsAll + (size_t)(3 + 2 * layer) * 8192;
    gemm_bf16<false, true><<<gGemm, blk, 0, stream>>>(
        Abuf, wsT + so1, wsT + so1 + 16384, db1 + po, nullptr, nullptr,
        nullptr, nullptr, tmask, Bbuf, st1, Nn);
    gemm_bf16<true, true><<<gGemm, blk, 0, stream>>>(
        Bbuf, wsT + so2, wsT + so2 + 16384, db2 + po, st1, dg1 + po, dbe1 + po,
        tcountf + layer, tmask, Abuf, st2, Nn);
    normrelu_acc_kernel<<<1563, blk, 0, stream>>>(
        Abuf, st2, dg2 + po, dbe2 + po, tcountf + layer, tmask, xbuf);
  }

  // ---- readout (counting sort + parallel pool, no float atomics) ----
  hipMemsetAsync(pcnt, 0, 512 * sizeof(int), stream);
  const int gIdx = (nridx + 255) / 256;
  phist_kernel<<<gIdx, blk, 0, stream>>>(readouts, batch, pcnt, nridx);
  pscan_kernel<<<1, blk, 0, stream>>>(pcnt, pcur);
  pfill_kernel<<<gIdx, blk, 0, stream>>>(readouts, batch, pcur, sorted, nridx);
  ppool_kernel<<<Gg * PSL, blk, 0, stream>>>(sorted, pcnt, xbuf, Ppart, nridx);
  preduce_kernel<<<Gg * 128 / 256, blk, 0, stream>>>(Ppart, P);
  out_kernel<<<10, blk, 0, stream>>>(P, Wl, bl, out);
}

// Round 9
// 498.194 us; speedup vs baseline: 4.5716x; 1.1172x over previous
//
#include <hip/hip_runtime.h>

constexpr int Nn = 100000;   // nodes
constexpr int Ee = 600000;   // edges
constexpr int Dd = 128;      // hidden dim
constexpr int Ll = 3;        // DAG layers
constexpr int Gg = 256;      // graphs
constexpr int Tt = 10;       // outputs per graph
constexpr float BN_EPS = 1e-5f;
constexpr int NREP = 16;     // stats replicas (slot = [16][512] floats)
constexpr int PSL = 8;       // pool slices per graph
constexpr int PR = 32;       // counting-sort bucket replicas per graph

typedef __attribute__((ext_vector_type(8))) short short8v;
typedef __attribute__((ext_vector_type(4))) float f32x4;

__device__ inline ushort bf_hi(float f) {
  unsigned u = __float_as_uint(f);
  unsigned r = (u + 0x7FFFu + ((u >> 16) & 1u)) >> 16;
  return (ushort)r;
}
__device__ inline float bf_f(ushort h) {
  return __uint_as_float(((unsigned)h) << 16);
}

// BN scale/shift from a replicated stats slot -> LDS ssS[256] (threads 0..127)
__device__ inline void compute_ss_lds(const float* __restrict__ stats,
                                      const float* __restrict__ g,
                                      const float* __restrict__ be, float cnt,
                                      float* ssS) {
  const int c = threadIdx.x;
  if (c < 128) {
    float S = 0.f, Q = 0.f;
#pragma unroll
    for (int r = 0; r < NREP; ++r) {
      S += stats[r * 512 + c];
      Q += stats[r * 512 + 256 + c];
    }
    const float m = S / cnt;
    const float v = Q / cnt - m * m;
    const float sc = g[c] * rsqrtf(v + BN_EPS);
    ssS[c] = sc;
    ssS[128 + c] = be[c] - m * sc;
  }
}

// ---------------------------------------------------------------------------
// B-resident barrier-free GEMM (bf16 A): C[N][64-slice] = op(A)@W + bias.
// ---------------------------------------------------------------------------
template <bool NORM_A, bool MASKED>
__global__ __launch_bounds__(256, 4) void gemm_bf16(
    const ushort* __restrict__ A, const ushort* __restrict__ WTh,
    const ushort* __restrict__ WTl, const float* __restrict__ bias,
    const float* __restrict__ statsIn, const float* __restrict__ gN,
    const float* __restrict__ beN, const float* __restrict__ cntPtr,
    const int* __restrict__ tmask, ushort* __restrict__ C,
    float* __restrict__ statsOut, int nrows) {
  __shared__ ushort SB[16384];  // Bh[8192] | Bl[8192]; reused: Cs[128][72]+red
  __shared__ float ssS[256];
  ushort* Bh = SB;
  ushort* Bl = SB + 8192;
  const int tid = threadIdx.x;
  const int w = tid >> 6, lane = tid & 63, lr = lane & 15, lg = lane >> 4;
  const int rt = blockIdx.x >> 1, ct = blockIdx.x & 1;
  const int rowBase = rt * 128, cBase = ct * 64;
  const int rep = blockIdx.x & (NREP - 1);

  // ---- stage B once (swizzle: byte ^= (col&7)<<4 within 256B row) ----
  {
    const int cc = tid >> 2;
    const ushort* sH = WTh + (size_t)(cBase + cc) * 128;
    const ushort* sL = WTl + (size_t)(cBase + cc) * 128;
    char* BhB = (char*)Bh;
    char* BlB = (char*)Bl;
#pragma unroll
    for (int i = 0; i < 4; ++i) {
      const int slot = (tid & 3) * 4 + i;
      const int off = (cc * 256 + slot * 16) ^ ((cc & 7) << 4);
      *(short8v*)(BhB + off) = *(const short8v*)(sH + slot * 8);
      *(short8v*)(BlB + off) = *(const short8v*)(sL + slot * 8);
    }
  }
  if (NORM_A) {
    const float cnt = cntPtr ? fmaxf(cntPtr[0], 1.f) : (float)nrows;
    compute_ss_lds(statsIn, gN, beN, cnt, ssS);
  }

  // ---- prefetch all A fragments ----
  const int row0 = rowBase + w * 32 + lr;
  const int row1 = row0 + 16;
  const bool ok0 = row0 < nrows, ok1 = row1 < nrows;
  const short8v szero = {0, 0, 0, 0, 0, 0, 0, 0};
  const ushort* aP0 = A + (size_t)row0 * 128 + lg * 8;
  const ushort* aP1 = A + (size_t)row1 * 128 + lg * 8;
  short8v ar0[4], ar1[4];
#pragma unroll
  for (int c = 0; c < 4; ++c) {
    ar0[c] = ok0 ? *(const short8v*)(aP0 + c * 32) : szero;
    ar1[c] = ok1 ? *(const short8v*)(aP1 + c * 32) : szero;
  }
  __syncthreads();

  const f32x4 fzero = {0.f, 0.f, 0.f, 0.f};
  f32x4 acc[2][4];
#pragma unroll
  for (int i = 0; i < 2; ++i)
#pragma unroll
    for (int j = 0; j < 4; ++j) acc[i][j] = fzero;

  const char* BhB = (const char*)Bh;
  const char* BlB = (const char*)Bl;
  __builtin_amdgcn_s_setprio(1);
#pragma unroll
  for (int c = 0; c < 4; ++c) {
    short8v a0 = ar0[c], a1 = ar1[c];
    if (NORM_A) {
      const int kb = c * 32 + lg * 8;
      const float4 s0 = *(const float4*)&ssS[kb];
      const float4 s1 = *(const float4*)&ssS[kb + 4];
      const float4 h0 = *(const float4*)&ssS[128 + kb];
      const float4 h1 = *(const float4*)&ssS[128 + kb + 4];
      const float sv[8] = {s0.x, s0.y, s0.z, s0.w, s1.x, s1.y, s1.z, s1.w};
      const float hv[8] = {h0.x, h0.y, h0.z, h0.w, h1.x, h1.y, h1.z, h1.w};
#pragma unroll
      for (int j = 0; j < 8; ++j) {
        a0[j] = (short)bf_hi(fmaxf(fmaf(bf_f((ushort)a0[j]), sv[j], hv[j]), 0.f));
        a1[j] = (short)bf_hi(fmaxf(fmaf(bf_f((ushort)a1[j]), sv[j], hv[j]), 0.f));
      }
    }
#pragma unroll
    for (int nf = 0; nf < 4; ++nf) {
      const int brow = nf * 16 + lr;
      const int off = (brow * 256 + (c * 4 + lg) * 16) ^ ((lr & 7) << 4);
      const short8v bh = *(const short8v*)(BhB + off);
      const short8v bl = *(const short8v*)(BlB + off);
      acc[0][nf] = __builtin_amdgcn_mfma_f32_16x16x32_bf16(a0, bh, acc[0][nf], 0, 0, 0);
      acc[1][nf] = __builtin_amdgcn_mfma_f32_16x16x32_bf16(a1, bh, acc[1][nf], 0, 0, 0);
      acc[0][nf] = __builtin_amdgcn_mfma_f32_16x16x32_bf16(a0, bl, acc[0][nf], 0, 0, 0);
      acc[1][nf] = __builtin_amdgcn_mfma_f32_16x16x32_bf16(a1, bl, acc[1][nf], 0, 0, 0);
    }
  }
  __builtin_amdgcn_s_setprio(0);

  // ---- epilogue: acc -> LDS bounce; stats partials ----
  float mrow[2][4];
#pragma unroll
  for (int mf = 0; mf < 2; ++mf)
#pragma unroll
    for (int rr = 0; rr < 4; ++rr) {
      const int row = rowBase + w * 32 + mf * 16 + lg * 4 + rr;
      float m = 0.f;
      if (row < nrows) m = MASKED ? ((tmask[row] > 0) ? 1.f : 0.f) : 1.f;
      mrow[mf][rr] = m;
    }
  __syncthreads();  // all waves done reading B
  ushort* Cs = SB;                      // [128][72]
  float* Sred = (float*)(SB + 9216);    // [4][64]
  float* Sq = Sred + 256;               // [4][64]
#pragma unroll
  for (int nf = 0; nf < 4; ++nf) {
    const int col = nf * 16 + lr;
    const float bcol = bias[cBase + col];
    float ps = 0.f, pq = 0.f;
#pragma unroll
    for (int mf = 0; mf < 2; ++mf) {
      const f32x4 vv = acc[mf][nf];
#pragma unroll
      for (int rr = 0; rr < 4; ++rr) {
        const float o = vv[rr] + bcol;
        const int rl = w * 32 + mf * 16 + lg * 4 + rr;
        Cs[rl * 72 + col] = bf_hi(o);
        const float mo = mrow[mf][rr] * o;
        ps += mo;
        pq += mo * o;
      }
    }
    ps += __shfl_xor(ps, 16);
    ps += __shfl_xor(ps, 32);
    pq += __shfl_xor(pq, 16);
    pq += __shfl_xor(pq, 32);
    if (lg == 0) {
      Sred[w * 64 + col] = ps;
      Sq[w * 64 + col] = pq;
    }
  }
  __syncthreads();
  {
    const int rl = tid >> 1, half = tid & 1;
    const int grow = rowBase + rl;
    if (grow < nrows) {
      ushort* dstp = C + (size_t)grow * 128 + cBase + half * 32;
      const ushort* srcp = Cs + rl * 72 + half * 32;
#pragma unroll
      for (int j = 0; j < 4; ++j)
        *(short8v*)(dstp + j * 8) = *(const short8v*)(srcp + j * 8);
    }
  }
  if (tid < 64) {
    float s = 0.f;
#pragma unroll
    for (int q = 0; q < 4; ++q) s += Sred[q * 64 + tid];
    atomicAdd(&statsOut[rep * 512 + cBase + tid], s);
  } else if (tid < 128) {
    float s = 0.f;
#pragma unroll
    for (int q = 0; q < 4; ++q) s += Sq[q * 64 + tid - 64];
    atomicAdd(&statsOut[rep * 512 + 256 + cBase + tid - 64], s);
  }
}

// ---------------------------------------------------------------------------
// GEMM #1: fp32 A (dag_x), K=64, hi/lo-split A (3 MFMAs). Same epilogue.
// ---------------------------------------------------------------------------
__global__ __launch_bounds__(256, 4) void gemm_f32a(
    const float* __restrict__ A, const ushort* __restrict__ WTh,
    const ushort* __restrict__ WTl, const float* __restrict__ bias,
    ushort* __restrict__ C, float* __restrict__ statsOut, int nrows) {
  __shared__ ushort SB[11264];  // Bh[4096] | Bl[4096]; reused Cs[128][72]+red
  ushort* Bh = SB;
  ushort* Bl = SB + 4096;
  const int tid = threadIdx.x;
  const int w = tid >> 6, lane = tid & 63, lr = lane & 15, lg = lane >> 4;
  const int rt = blockIdx.x >> 1, ct = blockIdx.x & 1;
  const int rowBase = rt * 128, cBase = ct * 64;
  const int rep = blockIdx.x & (NREP - 1);

  {
    const int cc = tid >> 2;
    const ushort* sH = WTh + (size_t)(cBase + cc) * 64;
    const ushort* sL = WTl + (size_t)(cBase + cc) * 64;
    char* BhB = (char*)Bh;
    char* BlB = (char*)Bl;
#pragma unroll
    for (int i = 0; i < 2; ++i) {
      const int slot = (tid & 3) * 2 + i;
      const int off = (cc * 128 + slot * 16) ^ ((cc & 7) << 4);
      *(short8v*)(BhB + off) = *(const short8v*)(sH + slot * 8);
      *(short8v*)(BlB + off) = *(const short8v*)(sL + slot * 8);
    }
  }

  const int row0 = rowBase + w * 32 + lr;
  const int row1 = row0 + 16;
  const bool ok0 = row0 < nrows, ok1 = row1 < nrows;
  const float4 fz4 = make_float4(0.f, 0.f, 0.f, 0.f);
  const float* aP0 = A + (size_t)row0 * 64 + lg * 8;
  const float* aP1 = A + (size_t)row1 * 64 + lg * 8;
  float4 ar0[2][2], ar1[2][2];
#pragma unroll
  for (int c = 0; c < 2; ++c) {
    ar0[c][0] = ok0 ? *(const float4*)(aP0 + c * 32) : fz4;
    ar0[c][1] = ok0 ? *(const float4*)(aP0 + c * 32 + 4) : fz4;
    ar1[c][0] = ok1 ? *(const float4*)(aP1 + c * 32) : fz4;
    ar1[c][1] = ok1 ? *(const float4*)(aP1 + c * 32 + 4) : fz4;
  }
  __syncthreads();

  const f32x4 fzero = {0.f, 0.f, 0.f, 0.f};
  f32x4 acc[2][4];
#pragma unroll
  for (int i = 0; i < 2; ++i)
#pragma unroll
    for (int j = 0; j < 4; ++j) acc[i][j] = fzero;

  const char* BhB = (const char*)Bh;
  const char* BlB = (const char*)Bl;
  __builtin_amdgcn_s_setprio(1);
#pragma unroll
  for (int c = 0; c < 2; ++c) {
    const float v0[8] = {ar0[c][0].x, ar0[c][0].y, ar0[c][0].z, ar0[c][0].w,
                         ar0[c][1].x, ar0[c][1].y, ar0[c][1].z, ar0[c][1].w};
    const float v1[8] = {ar1[c][0].x, ar1[c][0].y, ar1[c][0].z, ar1[c][0].w,
                         ar1[c][1].x, ar1[c][1].y, ar1[c][1].z, ar1[c][1].w};
    short8v a0h, a0l, a1h, a1l;
#pragma unroll
    for (int j = 0; j < 8; ++j) {
      ushort hh = bf_hi(v0[j]);
      a0h[j] = (short)hh;
      a0l[j] = (short)bf_hi(v0[j] - bf_f(hh));
      hh = bf_hi(v1[j]);
      a1h[j] = (short)hh;
      a1l[j] = (short)bf_hi(v1[j] - bf_f(hh));
    }
#pragma unroll
    for (int nf = 0; nf < 4; ++nf) {
      const int brow = nf * 16 + lr;
      const int off = (brow * 128 + (c * 4 + lg) * 16) ^ ((lr & 7) << 4);
      const short8v bh = *(const short8v*)(BhB + off);
      const short8v bl = *(const short8v*)(BlB + off);
      acc[0][nf] = __builtin_amdgcn_mfma_f32_16x16x32_bf16(a0h, bh, acc[0][nf], 0, 0, 0);
      acc[1][nf] = __builtin_amdgcn_mfma_f32_16x16x32_bf16(a1h, bh, acc[1][nf], 0, 0, 0);
      acc[0][nf] = __builtin_amdgcn_mfma_f32_16x16x32_bf16(a0l, bh, acc[0][nf], 0, 0, 0);
      acc[1][nf] = __builtin_amdgcn_mfma_f32_16x16x32_bf16(a1l, bh, acc[1][nf], 0, 0, 0);
      acc[0][nf] = __builtin_amdgcn_mfma_f32_16x16x32_bf16(a0h, bl, acc[0][nf], 0, 0, 0);
      acc[1][nf] = __builtin_amdgcn_mfma_f32_16x16x32_bf16(a1h, bl, acc[1][nf], 0, 0, 0);
    }
  }
  __builtin_amdgcn_s_setprio(0);

  __syncthreads();
  ushort* Cs = SB;                    // [128][72]
  float* Sred = (float*)(SB + 9216);  // [4][64]
  float* Sq = Sred + 256;
#pragma unroll
  for (int nf = 0; nf < 4; ++nf) {
    const int col = nf * 16 + lr;
    const float bcol = bias[cBase + col];
    float ps = 0.f, pq = 0.f;
#pragma unroll
    for (int mf = 0; mf < 2; ++mf) {
      const f32x4 vv = acc[mf][nf];
#pragma unroll
      for (int rr = 0; rr < 4; ++rr) {
        const float o = vv[rr] + bcol;
        const int rl = w * 32 + mf * 16 + lg * 4 + rr;
        Cs[rl * 72 + col] = bf_hi(o);
        const int row = rowBase + rl;
        const float m = (row < nrows) ? 1.f : 0.f;
        const float mo = m * o;
        ps += mo;
        pq += mo * o;
      }
    }
    ps += __shfl_xor(ps, 16);
    ps += __shfl_xor(ps, 32);
    pq += __shfl_xor(pq, 16);
    pq += __shfl_xor(pq, 32);
    if (lg == 0) {
      Sred[w * 64 + col] = ps;
      Sq[w * 64 + col] = pq;
    }
  }
  __syncthreads();
  {
    const int rl = tid >> 1, half = tid & 1;
    const int grow = rowBase + rl;
    if (grow < nrows) {
      ushort* dstp = C + (size_t)grow * 128 + cBase + half * 32;
      const ushort* srcp = Cs + rl * 72 + half * 32;
#pragma unroll
      for (int j = 0; j < 4; ++j)
        *(short8v*)(dstp + j * 8) = *(const short8v*)(srcp + j * 8);
    }
  }
  if (tid < 64) {
    float s = 0.f;
#pragma unroll
    for (int q = 0; q < 4; ++q) s += Sred[q * 64 + tid];
    atomicAdd(&statsOut[rep * 512 + cBase + tid], s);
  } else if (tid < 128) {
    float s = 0.f;
#pragma unroll
    for (int q = 0; q < 4; ++q) s += Sq[q * 64 + tid - 64];
    atomicAdd(&statsOut[rep * 512 + 256 + cBase + tid - 64], s);
  }
}

// Weight transpose + hi/lo split: 8 slots of 32768 ushorts (hi, lo@+16384)
__global__ __launch_bounds__(256) void wsplit_kernel(
    const float* __restrict__ W1, const float* __restrict__ W2,
    const float* __restrict__ dW1, const float* __restrict__ dW2,
    ushort* __restrict__ wsT) {
  const int t = blockIdx.x * 256 + threadIdx.x;
  const int slot = t >> 14;
  const int idx = t & 16383;
  if (slot >= 8) return;
  const int Ks = (slot == 0) ? 64 : 128;
  if (idx >= 128 * Ks) return;
  const int c = idx / Ks;
  const int k = idx - c * Ks;
  float v;
  if (slot == 0) v = W1[k * 128 + c];
  else if (slot == 1) v = W2[k * 128 + c];
  else if (slot < 5) v = dW1[(slot - 2) * 16384 + k * 128 + c];
  else v = dW2[(slot - 5) * 16384 + k * 128 + c];
  const ushort h = bf_hi(v);
  const ushort l = bf_hi(v - bf_f(h));
  wsT[slot * 32768 + c * Ks + k] = h;
  wsT[slot * 32768 + 16384 + c * Ks + k] = l;
}

// feat = relu(y*sc+sh); ss computed per block. 64 rows/block.
__global__ __launch_bounds__(256) void normrelu_kernel(
    const ushort* __restrict__ in, const float* __restrict__ stats,
    const float* __restrict__ g, const float* __restrict__ be, float cntFixed,
    ushort* __restrict__ outp) {
  __shared__ float ssS[256];
  compute_ss_lds(stats, g, be, cntFixed, ssS);
  __syncthreads();
  const int tid = threadIdx.x;
  const int c4 = (tid & 31) * 4;
  const float4 sc = *(const float4*)&ssS[c4];
  const float4 sh = *(const float4*)&ssS[128 + c4];
  const int rowBase = blockIdx.x * 64;
#pragma unroll
  for (int it = 0; it < 8; ++it) {
    const int row = rowBase + it * 8 + (tid >> 5);
    if (row >= Nn) continue;
    const size_t idx = (size_t)row * 32 + (tid & 31);
    const ushort4 v = ((const ushort4*)in)[idx];
    ushort4 o;
    o.x = bf_hi(fmaxf(fmaf(bf_f(v.x), sc.x, sh.x), 0.f));
    o.y = bf_hi(fmaxf(fmaf(bf_f(v.y), sc.y, sh.y), 0.f));
    o.z = bf_hi(fmaxf(fmaf(bf_f(v.z), sc.z, sh.z), 0.f));
    o.w = bf_hi(fmaxf(fmaf(bf_f(v.w), sc.w, sh.w), 0.f));
    ((ushort4*)outp)[idx] = o;
  }
}

// x += (tmask>0) * relu(y*sc+sh)
__global__ __launch_bounds__(256) void normrelu_acc_kernel(
    const ushort* __restrict__ in, const float* __restrict__ stats,
    const float* __restrict__ g, const float* __restrict__ be,
    const float* __restrict__ cntPtr, const int* __restrict__ tmask,
    ushort* __restrict__ x) {
  __shared__ float ssS[256];
  compute_ss_lds(stats, g, be, fmaxf(cntPtr[0], 1.f), ssS);
  __syncthreads();
  const int tid = threadIdx.x;
  const int c4 = (tid & 31) * 4;
  const float4 sc = *(const float4*)&ssS[c4];
  const float4 sh = *(const float4*)&ssS[128 + c4];
  const int rowBase = blockIdx.x * 64;
#pragma unroll
  for (int it = 0; it < 8; ++it) {
    const int row = rowBase + it * 8 + (tid >> 5);
    if (row >= Nn || tmask[row] <= 0) continue;
    const size_t idx = (size_t)row * 32 + (tid & 31);
    const ushort4 v = ((const ushort4*)in)[idx];
    ushort4 xo = ((const ushort4*)x)[idx];
    xo.x = bf_hi(bf_f(xo.x) + fmaxf(fmaf(bf_f(v.x), sc.x, sh.x), 0.f));
    xo.y = bf_hi(bf_f(xo.y) + fmaxf(fmaf(bf_f(v.y), sc.y, sh.y), 0.f));
    xo.z = bf_hi(bf_f(xo.z) + fmaxf(fmaf(bf_f(v.z), sc.z, sh.z), 0.f));
    xo.w = bf_hi(bf_f(xo.w) + fmaxf(fmaf(bf_f(v.w), sc.w, sh.w), 0.f));
    ((ushort4*)x)[idx] = xo;
  }
}

__global__ __launch_bounds__(256) void scatter_leaves_kernel(
    const int* __restrict__ leaves, const ushort* __restrict__ feat,
    ushort* __restrict__ x, int nl) {
  const int gid = blockIdx.x * 256 + threadIdx.x;
  const int j = gid >> 5;
  if (j >= nl) return;
  const int node = leaves[j];
  const int c4 = (gid & 31) * 4;
  *(ushort4*)&x[(size_t)node * 128 + c4] =
      *(const ushort4*)&feat[(size_t)node * 128 + c4];
}

// ---------------- CSR build ----------------
__global__ __launch_bounds__(256) void deg_count_kernel(
    const int* __restrict__ dst, const int* __restrict__ lmask,
    int* __restrict__ cnts) {
  const int e = blockIdx.x * 256 + threadIdx.x;
  if (e >= Ee) return;
  atomicAdd(&cnts[lmask[e] * Nn + dst[e]], 1);
}

// scan1 + fused per-layer target count (nodes with deg>0) -> tcountf[0..2]
__global__ __launch_bounds__(256) void scan1_kernel(const int* __restrict__ in,
                                                    int* __restrict__ out,
                                                    int* __restrict__ bsum,
                                                    float* __restrict__ tcountf,
                                                    int n) {
  __shared__ int lds[256];
  __shared__ float tcS[3];
  const int tid = threadIdx.x;
  const int base = blockIdx.x * 2048 + tid * 8;
  int vals[8];
  int tsum = 0;
  float t0 = 0.f, t1 = 0.f, t2 = 0.f;
#pragma unroll
  for (int j = 0; j < 8; ++j) {
    const int i = base + j;
    const int v = (i < n) ? in[i] : 0;
    if (v > 0) {
      if (i < Nn) t0 += 1.f;
      else if (i < 2 * Nn) t1 += 1.f;
      else t2 += 1.f;
    }
    vals[j] = tsum;
    tsum += v;
  }
  lds[tid] = tsum;
  if (tid < 3) tcS[tid] = 0.f;
  __syncthreads();
  if (t0 != 0.f) atomicAdd(&tcS[0], t0);
  if (t1 != 0.f) atomicAdd(&tcS[1], t1);
  if (t2 != 0.f) atomicAdd(&tcS[2], t2);
  for (int off = 1; off < 256; off <<= 1) {
    const int y = (tid >= off) ? lds[tid - off] : 0;
    __syncthreads();
    lds[tid] += y;
    __syncthreads();
  }
  const int texcl = (tid > 0) ? lds[tid - 1] : 0;
#pragma unroll
  for (int j = 0; j < 8; ++j)
    if (base + j < n) out[base + j] = texcl + vals[j];
  if (tid == 255) bsum[blockIdx.x] = lds[255];
  __syncthreads();
  if (tid < 3 && tcS[tid] != 0.f) atomicAdd(&tcountf[tid], tcS[tid]);
}

__global__ void scan2_kernel(int* __restrict__ bsum, int nb) {
  __shared__ int lds[256];
  const int tid = threadIdx.x;
  const int v = (tid < nb) ? bsum[tid] : 0;
  lds[tid] = v;
  __syncthreads();
  for (int off = 1; off < 256; off <<= 1) {
    const int y = (tid >= off) ? lds[tid - off] : 0;
    __syncthreads();
    lds[tid] += y;
    __syncthreads();
  }
  if (tid < nb) bsum[tid] = lds[tid] - v;  // exclusive
}

__global__ __launch_bounds__(256) void scan3_kernel(int* __restrict__ out,
                                                    int* __restrict__ cursor,
                                                    const int* __restrict__ bsum,
                                                    int n, int etot) {
  const int i = blockIdx.x * 256 + threadIdx.x;
  if (i >= n) return;
  const int v = out[i] + bsum[i >> 11];
  out[i] = v;
  cursor[i] = v;
  if (i == n - 1) out[n] = etot;
}

__global__ __launch_bounds__(256) void csr_fill_kernel(
    const int* __restrict__ src, const int* __restrict__ dst,
    const float* __restrict__ mult, const int* __restrict__ lmask,
    int* __restrict__ cursor, int2* __restrict__ pairs) {
  const int e = blockIdx.x * 256 + threadIdx.x;
  if (e >= Ee) return;
  const int slot = atomicAdd(&cursor[lmask[e] * Nn + dst[e]], 1);
  pairs[slot] = make_int2(src[e], __float_as_int(mult[e]));
}

// CSR aggregation (bf16); emits tmask.
__global__ __launch_bounds__(256) void agg_kernel(
    const int* __restrict__ offs, const int2* __restrict__ pairs,
    const ushort* __restrict__ x, const ushort* __restrict__ feat,
    const float* __restrict__ deps, int layer, ushort* __restrict__ sbuf,
    int* __restrict__ tmask) {
  const int node = blockIdx.x * 4 + (threadIdx.x >> 6);
  const int lane = threadIdx.x & 63;
  const int gi = layer * Nn + node;
  const int o0 = offs[gi];
  const int o1 = offs[gi + 1];
  ushort2 fv = make_ushort2(0, 0);
  if (o1 > o0) fv = *(const ushort2*)&feat[(size_t)node * 128 + lane * 2];
  float ax = 0.f, ay = 0.f;
  for (int p = o0; p < o1; p += 2) {
    const int2 pr0 = pairs[p];
    const int2 pr1 = (p + 1 < o1) ? pairs[p + 1] : make_int2(0, 0);
    const ushort2 x0 = *(const ushort2*)&x[(size_t)pr0.x * 128 + lane * 2];
    const ushort2 x1 = *(const ushort2*)&x[(size_t)pr1.x * 128 + lane * 2];
    const float w0 = __int_as_float(pr0.y);
    const float w1 = __int_as_float(pr1.y);
    ax = fmaf(w0, bf_f(x0.x), ax);
    ay = fmaf(w0, bf_f(x0.y), ay);
    ax = fmaf(w1, bf_f(x1.x), ax);
    ay = fmaf(w1, bf_f(x1.y), ay);
  }
  if (o1 > o0) {
    const float c = 1.f + deps[layer];
    ax = fmaf(c, bf_f(fv.x), ax);
    ay = fmaf(c, bf_f(fv.y), ay);
  }
  ushort2 o;
  o.x = bf_hi(ax);
  o.y = bf_hi(ay);
  *(ushort2*)&sbuf[(size_t)node * 128 + lane * 2] = o;
  if (lane == 0) tmask[node] = (o1 > o0) ? 1 : 0;
}

// ---------------- readout: replicated-bucket counting-sort pool -----------
// Buckets: [graph][PR] with rep = i & (PR-1), deterministic in index i.
__global__ __launch_bounds__(256) void phist_kernel(const int* __restrict__ ridx,
                                                    const int* __restrict__ batch,
                                                    int* __restrict__ cnt, int n) {
  const int i = blockIdx.x * 256 + threadIdx.x;
  if (i >= n) return;
  atomicAdd(&cnt[batch[ridx[i]] * PR + (i & (PR - 1))], 1);
}

// exclusive scan over 256*PR = 8192 buckets (single block, 32 elems/thread)
__global__ void pscan_kernel(int* __restrict__ cnt, int* __restrict__ cur) {
  __shared__ int l[256];
  const int t = threadIdx.x;
  const int base = t * 32;
  int vals[32];
  int tsum = 0;
#pragma unroll
  for (int j = 0; j < 32; ++j) {
    const int v = cnt[base + j];
    vals[j] = tsum;
    tsum += v;
  }
  l[t] = tsum;
  __syncthreads();
  for (int off = 1; off < 256; off <<= 1) {
    const int y = (t >= off) ? l[t - off] : 0;
    __syncthreads();
    l[t] += y;
    __syncthreads();
  }
  const int excl = (t > 0) ? l[t - 1] : 0;
#pragma unroll
  for (int j = 0; j < 32; ++j) {
    const int v = excl + vals[j];
    cnt[base + j] = v;
    cur[base + j] = v;
  }
}

__global__ __launch_bounds__(256) void pfill_kernel(const int* __restrict__ ridx,
                                                    const int* __restrict__ batch,
                                                    int* __restrict__ cur,
                                                    int* __restrict__ sorted,
                                                    int n) {
  const int i = blockIdx.x * 256 + threadIdx.x;
  if (i >= n) return;
  const int node = ridx[i];
  const int slot = atomicAdd(&cur[batch[node] * PR + (i & (PR - 1))], 1);
  sorted[slot] = node;
}

// Parallel pool: 8 slices per graph -> Ppart[g*8+slice][128] (no atomics)
__global__ __launch_bounds__(256) void ppool_kernel(const int* __restrict__ sorted,
                                                    const int* __restrict__ offs,
                                                    const ushort* __restrict__ x,
                                                    float* __restrict__ Ppart,
                                                    int n) {
  __shared__ float part[4][256];
  const int bid = blockIdx.x;
  const int g = bid >> 3, slice = bid & (PSL - 1);
  const int w = threadIdx.x >> 6;
  const int lane = threadIdx.x & 63;
  const int o0 = offs[g * PR];
  const int o1 = (g < Gg - 1) ? offs[(g + 1) * PR] : n;
  float ax = 0.f, ay = 0.f;
  for (int p = o0 + slice * 4 + w; p < o1; p += 32) {
    const int node = sorted[p];
    const ushort2 xv = *(const ushort2*)&x[(size_t)node * 128 + lane * 2];
    ax += bf_f(xv.x);
    ay += bf_f(xv.y);
  }
  part[w][lane * 2] = ax;
  part[w][lane * 2 + 1] = ay;
  __syncthreads();
  if (threadIdx.x < 128) {
    const int c = threadIdx.x;
    Ppart[(size_t)bid * 128 + c] =
        part[0][c] + part[1][c] + part[2][c] + part[3][c];
  }
}

// P[g][c] = sum over 8 slices
__global__ __launch_bounds__(256) void preduce_kernel(
    const float* __restrict__ Ppart, float* __restrict__ P) {
  const int gid = blockIdx.x * 256 + threadIdx.x;  // 32768
  const int g = gid >> 7, c = gid & 127;
  float s = 0.f;
#pragma unroll
  for (int t = 0; t < PSL; ++t) s += Ppart[(size_t)(g * PSL + t) * 128 + c];
  P[gid] = s;
}

__global__ void out_kernel(const float* __restrict__ P,
                           const float* __restrict__ Wl,
                           const float* __restrict__ bl,
                           float* __restrict__ out) {
  const int gid = blockIdx.x * blockDim.x + threadIdx.x;
  if (gid >= Gg * Tt) return;
  const int g = gid / Tt;
  const int t = gid - g * Tt;
  float acc = 0.f;
  for (int c = 0; c < 128; ++c) acc += P[g * 128 + c] * Wl[c * Tt + t];
  out[gid] = acc * 0.25f + bl[t];
}

extern "C" void kernel_launch(void* const* d_in, const int* in_sizes, int n_in,
                              void* d_out, int out_size, void* d_ws,
                              size_t ws_size, hipStream_t stream) {
  const float* dag_x = (const float*)d_in[0];
  const int* eidx = (const int*)d_in[1];
  const int* src = eidx;
  const int* dst = eidx + Ee;
  const float* mult = (const float*)d_in[2];
  const int* lmask = (const int*)d_in[3];
  const int* batch = (const int*)d_in[4];
  const int* leaves = (const int*)d_in[5];
  const int* readouts = (const int*)d_in[6];
  const float* W1 = (const float*)d_in[7];
  const float* b1 = (const float*)d_in[8];
  const float* g1 = (const float*)d_in[9];
  const float* be1 = (const float*)d_in[10];
  const float* W2 = (const float*)d_in[11];
  const float* b2 = (const float*)d_in[12];
  const float* g2 = (const float*)d_in[13];
  const float* be2 = (const float*)d_in[14];
  const float* dW1 = (const float*)d_in[15];
  const float* db1 = (const float*)d_in[16];
  const float* dg1 = (const float*)d_in[17];
  const float* dbe1 = (const float*)d_in[18];
  const float* dW2 = (const float*)d_in[19];
  const float* db2 = (const float*)d_in[20];
  const float* dg2 = (const float*)d_in[21];
  const float* dbe2 = (const float*)d_in[22];
  const float* deps = (const float*)d_in[23];
  const float* Wl = (const float*)d_in[24];
  const float* bl = (const float*)d_in[25];
  float* out = (float*)d_out;

  const size_t ND = (size_t)Nn * Dd;
  ushort* feat = (ushort*)d_ws;           // ND bf16
  ushort* xbuf = feat + ND;               // ND bf16
  ushort* Abuf = xbuf + ND;               // ND bf16
  ushort* Bbuf = Abuf + ND;               // ND bf16 (gemm ping-pong)
  float* statsAll = (float*)(Bbuf + ND);  // 8 slots x [16][512]
  float* tcountf = statsAll + 8 * 8192;   // 8 (4 used) -- adjacent for memset
  int* tmask = (int*)(tcountf + 8);       // N
  ushort* wsT = (ushort*)(tmask + Nn);    // 262144 (8 weight slots, hi+lo)
  int* offs = (int*)(wsT + 262144);       // 3N+4
  int2* pairs = (int2*)(offs + 3 * Nn + 4);  // E pairs (src, mult)

  // transient overlays (xbuf region before it's initialized):
  int* cnts = (int*)xbuf;                 // 3N
  int* cursor = cnts + 3 * Nn;            // 3N
  int* bsum = cursor + 3 * Nn;            // 147
  const int nridx = in_sizes[6];          // 80000
  const int nleaves = in_sizes[5];        // 50000
  // pool overlays (Abuf dead by readout):
  int* pcnt = (int*)Abuf;                 // 256*PR (becomes offsets)
  int* pcur = pcnt + Gg * PR;             // 256*PR
  int* sorted = pcur + Gg * PR;           // nridx
  float* Ppart = (float*)(sorted + nridx);  // 2048*128
  float* P = Ppart + Gg * PSL * 128;        // 256*128

  dim3 blk(256);
  hipMemsetAsync(statsAll, 0, (8 * 8192 + 8) * sizeof(float), stream);
  wsplit_kernel<<<512, blk, 0, stream>>>(W1, W2, dW1, dW2, wsT);

  // ---- CSR build (tcount fused into scan1) ----
  hipMemsetAsync(cnts, 0, 3 * Nn * sizeof(int), stream);
  deg_count_kernel<<<2344, blk, 0, stream>>>(dst, lmask, cnts);
  scan1_kernel<<<147, blk, 0, stream>>>(cnts, offs, bsum, tcountf, 3 * Nn);
  scan2_kernel<<<1, blk, 0, stream>>>(bsum, 147);
  scan3_kernel<<<1172, blk, 0, stream>>>(offs, cursor, bsum, 3 * Nn, Ee);
  csr_fill_kernel<<<2344, blk, 0, stream>>>(src, dst, mult, lmask, cursor, pairs);

  const int gGemm = 782 * 2;
  // ---- node feature transform ----
  gemm_f32a<<<gGemm, blk, 0, stream>>>(dag_x, wsT, wsT + 16384, b1, Abuf,
                                       statsAll + 0 * 8192, Nn);
  gemm_bf16<true, false><<<gGemm, blk, 0, stream>>>(
      Abuf, wsT + 32768, wsT + 32768 + 16384, b2, statsAll + 0 * 8192, g1, be1,
      nullptr, nullptr, Bbuf, statsAll + 1 * 8192, Nn);
  normrelu_kernel<<<1563, blk, 0, stream>>>(Bbuf, statsAll + 1 * 8192, g2, be2,
                                            (float)Nn, feat);

  hipMemsetAsync(xbuf, 0, ND * sizeof(ushort), stream);
  scatter_leaves_kernel<<<6250, blk, 0, stream>>>(leaves, feat, xbuf, nleaves);

  // ---- DAG layers ----
  for (int layer = 0; layer < Ll; ++layer) {
    agg_kernel<<<25000, blk, 0, stream>>>(offs, pairs, xbuf, feat, deps, layer,
                                          Abuf, tmask);
    const int so1 = (2 + layer) * 32768;
    const int so2 = (5 + layer) * 32768;
    const int po = layer * Dd;
    float* st1 = statsAll + (size_t)(2 + 2 * layer) * 8192;
    float* st2 = statsAll + (size_t)(3 + 2 * layer) * 8192;
    gemm_bf16<false, true><<<gGemm, blk, 0, stream>>>(
        Abuf, wsT + so1, wsT + so1 + 16384, db1 + po, nullptr, nullptr,
        nullptr, nullptr, tmask, Bbuf, st1, Nn);
    gemm_bf16<true, true><<<gGemm, blk, 0, stream>>>(
        Bbuf, wsT + so2, wsT + so2 + 16384, db2 + po, st1, dg1 + po, dbe1 + po,
        tcountf + layer, tmask, Abuf, st2, Nn);
    normrelu_acc_kernel<<<1563, blk, 0, stream>>>(
        Abuf, st2, dg2 + po, dbe2 + po, tcountf + layer, tmask, xbuf);
  }

  // ---- readout (replicated-bucket counting sort, no float atomics) ----
  hipMemsetAsync(pcnt, 0, Gg * PR * sizeof(int), stream);
  const int gIdx = (nridx + 255) / 256;
  phist_kernel<<<gIdx, blk, 0, stream>>>(readouts, batch, pcnt, nridx);
  pscan_kernel<<<1, blk, 0, stream>>>(pcnt, pcur);
  pfill_kernel<<<gIdx, blk, 0, stream>>>(readouts, batch, pcur, sorted, nridx);
  ppool_kernel<<<Gg * PSL, blk, 0, stream>>>(sorted, pcnt, xbuf, Ppart, nridx);
  preduce_kernel<<<Gg * 128 / 256, blk, 0, stream>>>(Ppart, P);
  out_kernel<<<10, blk, 0, stream>>>(P, Wl, bl, out);
}

// Round 10
// 460.710 us; speedup vs baseline: 4.9436x; 1.0814x over previous
//
#include <hip/hip_runtime.h>

constexpr int Nn = 100000;   // nodes
constexpr int Ee = 600000;   // edges
constexpr int Dd = 128;      // hidden dim
constexpr int Ll = 3;        // DAG layers
constexpr int Gg = 256;      // graphs
constexpr int Tt = 10;       // outputs per graph
constexpr float BN_EPS = 1e-5f;
constexpr int NREP = 16;     // stats replicas (slot = [16][512] floats)
constexpr int PSL = 8;       // pool slices per graph
constexpr int PR = 32;       // counting-sort bucket replicas per graph

typedef __attribute__((ext_vector_type(8))) short short8v;
typedef __attribute__((ext_vector_type(4))) float f32x4;

__device__ inline ushort bf_hi(float f) {
  unsigned u = __float_as_uint(f);
  unsigned r = (u + 0x7FFFu + ((u >> 16) & 1u)) >> 16;
  return (ushort)r;
}
__device__ inline float bf_f(ushort h) {
  return __uint_as_float(((unsigned)h) << 16);
}

// BN scale/shift from a replicated stats slot -> LDS ssS[256] (threads 0..127)
__device__ inline void compute_ss_lds(const float* __restrict__ stats,
                                      const float* __restrict__ g,
                                      const float* __restrict__ be, float cnt,
                                      float* ssS) {
  const int c = threadIdx.x;
  if (c < 128) {
    float S = 0.f, Q = 0.f;
#pragma unroll
    for (int r = 0; r < NREP; ++r) {
      S += stats[r * 512 + c];
      Q += stats[r * 512 + 256 + c];
    }
    const float m = S / cnt;
    const float v = Q / cnt - m * m;
    const float sc = g[c] * rsqrtf(v + BN_EPS);
    ssS[c] = sc;
    ssS[128 + c] = be[c] - m * sc;
  }
}

// ---------------------------------------------------------------------------
// B-resident barrier-free GEMM (bf16 A): C[N][64-slice] = op(A)@W + bias.
// ---------------------------------------------------------------------------
template <bool NORM_A, bool MASKED>
__global__ __launch_bounds__(256, 4) void gemm_bf16(
    const ushort* __restrict__ A, const ushort* __restrict__ WTh,
    const ushort* __restrict__ WTl, const float* __restrict__ bias,
    const float* __restrict__ statsIn, const float* __restrict__ gN,
    const float* __restrict__ beN, const float* __restrict__ cntPtr,
    const int* __restrict__ tmask, ushort* __restrict__ C,
    float* __restrict__ statsOut, int nrows) {
  __shared__ ushort SB[16384];  // Bh[8192] | Bl[8192]; reused: Cs[128][72]+red
  __shared__ float ssS[256];
  ushort* Bh = SB;
  ushort* Bl = SB + 8192;
  const int tid = threadIdx.x;
  const int w = tid >> 6, lane = tid & 63, lr = lane & 15, lg = lane >> 4;
  const int rt = blockIdx.x >> 1, ct = blockIdx.x & 1;
  const int rowBase = rt * 128, cBase = ct * 64;
  const int rep = blockIdx.x & (NREP - 1);

  // ---- stage B once (swizzle: byte ^= (col&7)<<4 within 256B row) ----
  {
    const int cc = tid >> 2;
    const ushort* sH = WTh + (size_t)(cBase + cc) * 128;
    const ushort* sL = WTl + (size_t)(cBase + cc) * 128;
    char* BhB = (char*)Bh;
    char* BlB = (char*)Bl;
#pragma unroll
    for (int i = 0; i < 4; ++i) {
      const int slot = (tid & 3) * 4 + i;
      const int off = (cc * 256 + slot * 16) ^ ((cc & 7) << 4);
      *(short8v*)(BhB + off) = *(const short8v*)(sH + slot * 8);
      *(short8v*)(BlB + off) = *(const short8v*)(sL + slot * 8);
    }
  }
  if (NORM_A) {
    const float cnt = cntPtr ? fmaxf(cntPtr[0], 1.f) : (float)nrows;
    compute_ss_lds(statsIn, gN, beN, cnt, ssS);
  }

  // ---- prefetch all A fragments ----
  const int row0 = rowBase + w * 32 + lr;
  const int row1 = row0 + 16;
  const bool ok0 = row0 < nrows, ok1 = row1 < nrows;
  const short8v szero = {0, 0, 0, 0, 0, 0, 0, 0};
  const ushort* aP0 = A + (size_t)row0 * 128 + lg * 8;
  const ushort* aP1 = A + (size_t)row1 * 128 + lg * 8;
  short8v ar0[4], ar1[4];
#pragma unroll
  for (int c = 0; c < 4; ++c) {
    ar0[c] = ok0 ? *(const short8v*)(aP0 + c * 32) : szero;
    ar1[c] = ok1 ? *(const short8v*)(aP1 + c * 32) : szero;
  }
  __syncthreads();

  const f32x4 fzero = {0.f, 0.f, 0.f, 0.f};
  f32x4 acc[2][4];
#pragma unroll
  for (int i = 0; i < 2; ++i)
#pragma unroll
    for (int j = 0; j < 4; ++j) acc[i][j] = fzero;

  const char* BhB = (const char*)Bh;
  const char* BlB = (const char*)Bl;
  __builtin_amdgcn_s_setprio(1);
#pragma unroll
  for (int c = 0; c < 4; ++c) {
    short8v a0 = ar0[c], a1 = ar1[c];
    if (NORM_A) {
      const int kb = c * 32 + lg * 8;
      const float4 s0 = *(const float4*)&ssS[kb];
      const float4 s1 = *(const float4*)&ssS[kb + 4];
      const float4 h0 = *(const float4*)&ssS[128 + kb];
      const float4 h1 = *(const float4*)&ssS[128 + kb + 4];
      const float sv[8] = {s0.x, s0.y, s0.z, s0.w, s1.x, s1.y, s1.z, s1.w};
      const float hv[8] = {h0.x, h0.y, h0.z, h0.w, h1.x, h1.y, h1.z, h1.w};
#pragma unroll
      for (int j = 0; j < 8; ++j) {
        a0[j] = (short)bf_hi(fmaxf(fmaf(bf_f((ushort)a0[j]), sv[j], hv[j]), 0.f));
        a1[j] = (short)bf_hi(fmaxf(fmaf(bf_f((ushort)a1[j]), sv[j], hv[j]), 0.f));
      }
    }
#pragma unroll
    for (int nf = 0; nf < 4; ++nf) {
      const int brow = nf * 16 + lr;
      const int off = (brow * 256 + (c * 4 + lg) * 16) ^ ((lr & 7) << 4);
      const short8v bh = *(const short8v*)(BhB + off);
      const short8v bl = *(const short8v*)(BlB + off);
      acc[0][nf] = __builtin_amdgcn_mfma_f32_16x16x32_bf16(a0, bh, acc[0][nf], 0, 0, 0);
      acc[1][nf] = __builtin_amdgcn_mfma_f32_16x16x32_bf16(a1, bh, acc[1][nf], 0, 0, 0);
      acc[0][nf] = __builtin_amdgcn_mfma_f32_16x16x32_bf16(a0, bl, acc[0][nf], 0, 0, 0);
      acc[1][nf] = __builtin_amdgcn_mfma_f32_16x16x32_bf16(a1, bl, acc[1][nf], 0, 0, 0);
    }
  }
  __builtin_amdgcn_s_setprio(0);

  // ---- epilogue: acc -> LDS bounce; stats partials ----
  float mrow[2][4];
#pragma unroll
  for (int mf = 0; mf < 2; ++mf)
#pragma unroll
    for (int rr = 0; rr < 4; ++rr) {
      const int row = rowBase + w * 32 + mf * 16 + lg * 4 + rr;
      float m = 0.f;
      if (row < nrows) m = MASKED ? ((tmask[row] > 0) ? 1.f : 0.f) : 1.f;
      mrow[mf][rr] = m;
    }
  __syncthreads();  // all waves done reading B
  ushort* Cs = SB;                      // [128][72]
  float* Sred = (float*)(SB + 9216);    // [4][64]
  float* Sq = Sred + 256;               // [4][64]
#pragma unroll
  for (int nf = 0; nf < 4; ++nf) {
    const int col = nf * 16 + lr;
    const float bcol = bias[cBase + col];
    float ps = 0.f, pq = 0.f;
#pragma unroll
    for (int mf = 0; mf < 2; ++mf) {
      const f32x4 vv = acc[mf][nf];
#pragma unroll
      for (int rr = 0; rr < 4; ++rr) {
        const float o = vv[rr] + bcol;
        const int rl = w * 32 + mf * 16 + lg * 4 + rr;
        Cs[rl * 72 + col] = bf_hi(o);
        const float mo = mrow[mf][rr] * o;
        ps += mo;
        pq += mo * o;
      }
    }
    ps += __shfl_xor(ps, 16);
    ps += __shfl_xor(ps, 32);
    pq += __shfl_xor(pq, 16);
    pq += __shfl_xor(pq, 32);
    if (lg == 0) {
      Sred[w * 64 + col] = ps;
      Sq[w * 64 + col] = pq;
    }
  }
  __syncthreads();
  {
    const int rl = tid >> 1, half = tid & 1;
    const int grow = rowBase + rl;
    if (grow < nrows) {
      ushort* dstp = C + (size_t)grow * 128 + cBase + half * 32;
      const ushort* srcp = Cs + rl * 72 + half * 32;
#pragma unroll
      for (int j = 0; j < 4; ++j)
        *(short8v*)(dstp + j * 8) = *(const short8v*)(srcp + j * 8);
    }
  }
  if (tid < 64) {
    float s = 0.f;
#pragma unroll
    for (int q = 0; q < 4; ++q) s += Sred[q * 64 + tid];
    atomicAdd(&statsOut[rep * 512 + cBase + tid], s);
  } else if (tid < 128) {
    float s = 0.f;
#pragma unroll
    for (int q = 0; q < 4; ++q) s += Sq[q * 64 + tid - 64];
    atomicAdd(&statsOut[rep * 512 + 256 + cBase + tid - 64], s);
  }
}

// ---------------------------------------------------------------------------
// FUSED agg+GEMM1: A fragments computed on the fly from CSR message passing:
//   s[row] = sum_edges w*x[src] + (deg>0)*(1+eps)*feat[row]  (rounded bf16,
//   bit-identical to the old agg output). Writes tmask; mask via shfl.
// ---------------------------------------------------------------------------
__global__ __launch_bounds__(256, 4) void gemm_agg(
    const ushort* __restrict__ x, const ushort* __restrict__ feat,
    const int* __restrict__ offs, const int2* __restrict__ pairs,
    const float* __restrict__ deps, int layer, const ushort* __restrict__ WTh,
    const ushort* __restrict__ WTl, const float* __restrict__ bias,
    ushort* __restrict__ C, float* __restrict__ statsOut,
    int* __restrict__ tmask, int nrows) {
  __shared__ ushort SB[16384];
  ushort* Bh = SB;
  ushort* Bl = SB + 8192;
  const int tid = threadIdx.x;
  const int w = tid >> 6, lane = tid & 63, lr = lane & 15, lg = lane >> 4;
  const int rt = blockIdx.x >> 1, ct = blockIdx.x & 1;
  const int rowBase = rt * 128, cBase = ct * 64;
  const int rep = blockIdx.x & (NREP - 1);

  // ---- stage B once ----
  {
    const int cc = tid >> 2;
    const ushort* sH = WTh + (size_t)(cBase + cc) * 128;
    const ushort* sL = WTl + (size_t)(cBase + cc) * 128;
    char* BhB = (char*)Bh;
    char* BlB = (char*)Bl;
#pragma unroll
    for (int i = 0; i < 4; ++i) {
      const int slot = (tid & 3) * 4 + i;
      const int off = (cc * 256 + slot * 16) ^ ((cc & 7) << 4);
      *(short8v*)(BhB + off) = *(const short8v*)(sH + slot * 8);
      *(short8v*)(BlB + off) = *(const short8v*)(sL + slot * 8);
    }
  }

  const float ce = 1.f + deps[layer];
  const int row0 = rowBase + w * 32 + lr;
  const int row1 = row0 + 16;
  int o0a = 0, o1a = 0, o0b = 0, o1b = 0;
  if (row0 < nrows) {
    o0a = offs[layer * Nn + row0];
    o1a = offs[layer * Nn + row0 + 1];
  }
  if (row1 < nrows) {
    o0b = offs[layer * Nn + row1];
    o1b = offs[layer * Nn + row1 + 1];
  }
  if (lg == 0) {
    if (row0 < nrows) tmask[row0] = (o1a > o0a) ? 1 : 0;
    if (row1 < nrows) tmask[row1] = (o1b > o0b) ? 1 : 0;
  }

  short8v ar0[4], ar1[4];
  // row0 fragments (cols lg*8 + c*32 .. +7 for c=0..3) in one edge pass
  {
    float a[4][8];
#pragma unroll
    for (int c = 0; c < 4; ++c)
#pragma unroll
      for (int j = 0; j < 8; ++j) a[c][j] = 0.f;
    for (int p = o0a; p < o1a; ++p) {
      const int2 pr = pairs[p];
      const float wgt = __int_as_float(pr.y);
      const ushort* xr = x + (size_t)pr.x * 128 + lg * 8;
#pragma unroll
      for (int c = 0; c < 4; ++c) {
        const short8v xv = *(const short8v*)(xr + c * 32);
#pragma unroll
        for (int j = 0; j < 8; ++j)
          a[c][j] = fmaf(wgt, bf_f((ushort)xv[j]), a[c][j]);
      }
    }
    if (o1a > o0a) {
      const ushort* fr = feat + (size_t)row0 * 128 + lg * 8;
#pragma unroll
      for (int c = 0; c < 4; ++c) {
        const short8v fv = *(const short8v*)(fr + c * 32);
#pragma unroll
        for (int j = 0; j < 8; ++j)
          a[c][j] = fmaf(ce, bf_f((ushort)fv[j]), a[c][j]);
      }
    }
#pragma unroll
    for (int c = 0; c < 4; ++c)
#pragma unroll
      for (int j = 0; j < 8; ++j) ar0[c][j] = (short)bf_hi(a[c][j]);
  }
  // row1 fragments
  {
    float a[4][8];
#pragma unroll
    for (int c = 0; c < 4; ++c)
#pragma unroll
      for (int j = 0; j < 8; ++j) a[c][j] = 0.f;
    for (int p = o0b; p < o1b; ++p) {
      const int2 pr = pairs[p];
      const float wgt = __int_as_float(pr.y);
      const ushort* xr = x + (size_t)pr.x * 128 + lg * 8;
#pragma unroll
      for (int c = 0; c < 4; ++c) {
        const short8v xv = *(const short8v*)(xr + c * 32);
#pragma unroll
        for (int j = 0; j < 8; ++j)
          a[c][j] = fmaf(wgt, bf_f((ushort)xv[j]), a[c][j]);
      }
    }
    if (o1b > o0b) {
      const ushort* fr = feat + (size_t)row1 * 128 + lg * 8;
#pragma unroll
      for (int c = 0; c < 4; ++c) {
        const short8v fv = *(const short8v*)(fr + c * 32);
#pragma unroll
        for (int j = 0; j < 8; ++j)
          a[c][j] = fmaf(ce, bf_f((ushort)fv[j]), a[c][j]);
      }
    }
#pragma unroll
    for (int c = 0; c < 4; ++c)
#pragma unroll
      for (int j = 0; j < 8; ++j) ar1[c][j] = (short)bf_hi(a[c][j]);
  }
  __syncthreads();

  const f32x4 fzero = {0.f, 0.f, 0.f, 0.f};
  f32x4 acc[2][4];
#pragma unroll
  for (int i = 0; i < 2; ++i)
#pragma unroll
    for (int j = 0; j < 4; ++j) acc[i][j] = fzero;

  const char* BhB = (const char*)Bh;
  const char* BlB = (const char*)Bl;
  __builtin_amdgcn_s_setprio(1);
#pragma unroll
  for (int c = 0; c < 4; ++c) {
    const short8v a0 = ar0[c], a1 = ar1[c];
#pragma unroll
    for (int nf = 0; nf < 4; ++nf) {
      const int brow = nf * 16 + lr;
      const int off = (brow * 256 + (c * 4 + lg) * 16) ^ ((lr & 7) << 4);
      const short8v bh = *(const short8v*)(BhB + off);
      const short8v bl = *(const short8v*)(BlB + off);
      acc[0][nf] = __builtin_amdgcn_mfma_f32_16x16x32_bf16(a0, bh, acc[0][nf], 0, 0, 0);
      acc[1][nf] = __builtin_amdgcn_mfma_f32_16x16x32_bf16(a1, bh, acc[1][nf], 0, 0, 0);
      acc[0][nf] = __builtin_amdgcn_mfma_f32_16x16x32_bf16(a0, bl, acc[0][nf], 0, 0, 0);
      acc[1][nf] = __builtin_amdgcn_mfma_f32_16x16x32_bf16(a1, bl, acc[1][nf], 0, 0, 0);
    }
  }
  __builtin_amdgcn_s_setprio(0);

  // ---- epilogue: mask via shfl of per-row deg flags ----
  const float dga = (o1a > o0a) ? 1.f : 0.f;
  const float dgb = (o1b > o0b) ? 1.f : 0.f;
  float mrow[2][4];
#pragma unroll
  for (int rr = 0; rr < 4; ++rr) {
    const int srcl = lg * 4 + rr;  // lane with lr == srcl holds that row's deg
    mrow[0][rr] = __shfl(dga, (w << 6 & 0) + srcl, 64);
    mrow[1][rr] = __shfl(dgb, srcl, 64);
  }
#pragma unroll
  for (int mf = 0; mf < 2; ++mf)
#pragma unroll
    for (int rr = 0; rr < 4; ++rr) {
      const int row = rowBase + w * 32 + mf * 16 + lg * 4 + rr;
      if (row >= nrows) mrow[mf][rr] = 0.f;
    }
  __syncthreads();
  ushort* Cs = SB;                    // [128][72]
  float* Sred = (float*)(SB + 9216);  // [4][64]
  float* Sq = Sred + 256;
#pragma unroll
  for (int nf = 0; nf < 4; ++nf) {
    const int col = nf * 16 + lr;
    const float bcol = bias[cBase + col];
    float ps = 0.f, pq = 0.f;
#pragma unroll
    for (int mf = 0; mf < 2; ++mf) {
      const f32x4 vv = acc[mf][nf];
#pragma unroll
      for (int rr = 0; rr < 4; ++rr) {
        const float o = vv[rr] + bcol;
        const int rl = w * 32 + mf * 16 + lg * 4 + rr;
        Cs[rl * 72 + col] = bf_hi(o);
        const float mo = mrow[mf][rr] * o;
        ps += mo;
        pq += mo * o;
      }
    }
    ps += __shfl_xor(ps, 16);
    ps += __shfl_xor(ps, 32);
    pq += __shfl_xor(pq, 16);
    pq += __shfl_xor(pq, 32);
    if (lg == 0) {
      Sred[w * 64 + col] = ps;
      Sq[w * 64 + col] = pq;
    }
  }
  __syncthreads();
  {
    const int rl = tid >> 1, half = tid & 1;
    const int grow = rowBase + rl;
    if (grow < nrows) {
      ushort* dstp = C + (size_t)grow * 128 + cBase + half * 32;
      const ushort* srcp = Cs + rl * 72 + half * 32;
#pragma unroll
      for (int j = 0; j < 4; ++j)
        *(short8v*)(dstp + j * 8) = *(const short8v*)(srcp + j * 8);
    }
  }
  if (tid < 64) {
    float s = 0.f;
#pragma unroll
    for (int q = 0; q < 4; ++q) s += Sred[q * 64 + tid];
    atomicAdd(&statsOut[rep * 512 + cBase + tid], s);
  } else if (tid < 128) {
    float s = 0.f;
#pragma unroll
    for (int q = 0; q < 4; ++q) s += Sq[q * 64 + tid - 64];
    atomicAdd(&statsOut[rep * 512 + 256 + cBase + tid - 64], s);
  }
}

// ---------------------------------------------------------------------------
// GEMM #1: fp32 A (dag_x), K=64, hi/lo-split A (3 MFMAs). Same epilogue.
// ---------------------------------------------------------------------------
__global__ __launch_bounds__(256, 4) void gemm_f32a(
    const float* __restrict__ A, const ushort* __restrict__ WTh,
    const ushort* __restrict__ WTl, const float* __restrict__ bias,
    ushort* __restrict__ C, float* __restrict__ statsOut, int nrows) {
  __shared__ ushort SB[11264];  // Bh[4096] | Bl[4096]; reused Cs[128][72]+red
  ushort* Bh = SB;
  ushort* Bl = SB + 4096;
  const int tid = threadIdx.x;
  const int w = tid >> 6, lane = tid & 63, lr = lane & 15, lg = lane >> 4;
  const int rt = blockIdx.x >> 1, ct = blockIdx.x & 1;
  const int rowBase = rt * 128, cBase = ct * 64;
  const int rep = blockIdx.x & (NREP - 1);

  {
    const int cc = tid >> 2;
    const ushort* sH = WTh + (size_t)(cBase + cc) * 64;
    const ushort* sL = WTl + (size_t)(cBase + cc) * 64;
    char* BhB = (char*)Bh;
    char* BlB = (char*)Bl;
#pragma unroll
    for (int i = 0; i < 2; ++i) {
      const int slot = (tid & 3) * 2 + i;
      const int off = (cc * 128 + slot * 16) ^ ((cc & 7) << 4);
      *(short8v*)(BhB + off) = *(const short8v*)(sH + slot * 8);
      *(short8v*)(BlB + off) = *(const short8v*)(sL + slot * 8);
    }
  }

  const int row0 = rowBase + w * 32 + lr;
  const int row1 = row0 + 16;
  const bool ok0 = row0 < nrows, ok1 = row1 < nrows;
  const float4 fz4 = make_float4(0.f, 0.f, 0.f, 0.f);
  const float* aP0 = A + (size_t)row0 * 64 + lg * 8;
  const float* aP1 = A + (size_t)row1 * 64 + lg * 8;
  float4 ar0[2][2], ar1[2][2];
#pragma unroll
  for (int c = 0; c < 2; ++c) {
    ar0[c][0] = ok0 ? *(const float4*)(aP0 + c * 32) : fz4;
    ar0[c][1] = ok0 ? *(const float4*)(aP0 + c * 32 + 4) : fz4;
    ar1[c][0] = ok1 ? *(const float4*)(aP1 + c * 32) : fz4;
    ar1[c][1] = ok1 ? *(const float4*)(aP1 + c * 32 + 4) : fz4;
  }
  __syncthreads();

  const f32x4 fzero = {0.f, 0.f, 0.f, 0.f};
  f32x4 acc[2][4];
#pragma unroll
  for (int i = 0; i < 2; ++i)
#pragma unroll
    for (int j = 0; j < 4; ++j) acc[i][j] = fzero;

  const char* BhB = (const char*)Bh;
  const char* BlB = (const char*)Bl;
  __builtin_amdgcn_s_setprio(1);
#pragma unroll
  for (int c = 0; c < 2; ++c) {
    const float v0[8] = {ar0[c][0].x, ar0[c][0].y, ar0[c][0].z, ar0[c][0].w,
                         ar0[c][1].x, ar0[c][1].y, ar0[c][1].z, ar0[c][1].w};
    const float v1[8] = {ar1[c][0].x, ar1[c][0].y, ar1[c][0].z, ar1[c][0].w,
                         ar1[c][1].x, ar1[c][1].y, ar1[c][1].z, ar1[c][1].w};
    short8v a0h, a0l, a1h, a1l;
#pragma unroll
    for (int j = 0; j < 8; ++j) {
      ushort hh = bf_hi(v0[j]);
      a0h[j] = (short)hh;
      a0l[j] = (short)bf_hi(v0[j] - bf_f(hh));
      hh = bf_hi(v1[j]);
      a1h[j] = (short)hh;
      a1l[j] = (short)bf_hi(v1[j] - bf_f(hh));
    }
#pragma unroll
    for (int nf = 0; nf < 4; ++nf) {
      const int brow = nf * 16 + lr;
      const int off = (brow * 128 + (c * 4 + lg) * 16) ^ ((lr & 7) << 4);
      const short8v bh = *(const short8v*)(BhB + off);
      const short8v bl = *(const short8v*)(BlB + off);
      acc[0][nf] = __builtin_amdgcn_mfma_f32_16x16x32_bf16(a0h, bh, acc[0][nf], 0, 0, 0);
      acc[1][nf] = __builtin_amdgcn_mfma_f32_16x16x32_bf16(a1h, bh, acc[1][nf], 0, 0, 0);
      acc[0][nf] = __builtin_amdgcn_mfma_f32_16x16x32_bf16(a0l, bh, acc[0][nf], 0, 0, 0);
      acc[1][nf] = __builtin_amdgcn_mfma_f32_16x16x32_bf16(a1l, bh, acc[1][nf], 0, 0, 0);
      acc[0][nf] = __builtin_amdgcn_mfma_f32_16x16x32_bf16(a0h, bl, acc[0][nf], 0, 0, 0);
      acc[1][nf] = __builtin_amdgcn_mfma_f32_16x16x32_bf16(a1h, bl, acc[1][nf], 0, 0, 0);
    }
  }
  __builtin_amdgcn_s_setprio(0);

  __syncthreads();
  ushort* Cs = SB;                    // [128][72]
  float* Sred = (float*)(SB + 9216);  // [4][64]
  float* Sq = Sred + 256;
#pragma unroll
  for (int nf = 0; nf < 4; ++nf) {
    const int col = nf * 16 + lr;
    const float bcol = bias[cBase + col];
    float ps = 0.f, pq = 0.f;
#pragma unroll
    for (int mf = 0; mf < 2; ++mf) {
      const f32x4 vv = acc[mf][nf];
#pragma unroll
      for (int rr = 0; rr < 4; ++rr) {
        const float o = vv[rr] + bcol;
        const int rl = w * 32 + mf * 16 + lg * 4 + rr;
        Cs[rl * 72 + col] = bf_hi(o);
        const int row = rowBase + rl;
        const float m = (row < nrows) ? 1.f : 0.f;
        const float mo = m * o;
        ps += mo;
        pq += mo * o;
      }
    }
    ps += __shfl_xor(ps, 16);
    ps += __shfl_xor(ps, 32);
    pq += __shfl_xor(pq, 16);
    pq += __shfl_xor(pq, 32);
    if (lg == 0) {
      Sred[w * 64 + col] = ps;
      Sq[w * 64 + col] = pq;
    }
  }
  __syncthreads();
  {
    const int rl = tid >> 1, half = tid & 1;
    const int grow = rowBase + rl;
    if (grow < nrows) {
      ushort* dstp = C + (size_t)grow * 128 + cBase + half * 32;
      const ushort* srcp = Cs + rl * 72 + half * 32;
#pragma unroll
      for (int j = 0; j < 4; ++j)
        *(short8v*)(dstp + j * 8) = *(const short8v*)(srcp + j * 8);
    }
  }
  if (tid < 64) {
    float s = 0.f;
#pragma unroll
    for (int q = 0; q < 4; ++q) s += Sred[q * 64 + tid];
    atomicAdd(&statsOut[rep * 512 + cBase + tid], s);
  } else if (tid < 128) {
    float s = 0.f;
#pragma unroll
    for (int q = 0; q < 4; ++q) s += Sq[q * 64 + tid - 64];
    atomicAdd(&statsOut[rep * 512 + 256 + cBase + tid - 64], s);
  }
}

// Weight transpose + hi/lo split: 8 slots of 32768 ushorts (hi, lo@+16384)
__global__ __launch_bounds__(256) void wsplit_kernel(
    const float* __restrict__ W1, const float* __restrict__ W2,
    const float* __restrict__ dW1, const float* __restrict__ dW2,
    ushort* __restrict__ wsT) {
  const int t = blockIdx.x * 256 + threadIdx.x;
  const int slot = t >> 14;
  const int idx = t & 16383;
  if (slot >= 8) return;
  const int Ks = (slot == 0) ? 64 : 128;
  if (idx >= 128 * Ks) return;
  const int c = idx / Ks;
  const int k = idx - c * Ks;
  float v;
  if (slot == 0) v = W1[k * 128 + c];
  else if (slot == 1) v = W2[k * 128 + c];
  else if (slot < 5) v = dW1[(slot - 2) * 16384 + k * 128 + c];
  else v = dW2[(slot - 5) * 16384 + k * 128 + c];
  const ushort h = bf_hi(v);
  const ushort l = bf_hi(v - bf_f(h));
  wsT[slot * 32768 + c * Ks + k] = h;
  wsT[slot * 32768 + 16384 + c * Ks + k] = l;
}

// feat = relu(y*sc+sh); also zeroes x (replaces the xbuf memset dispatch).
__global__ __launch_bounds__(256) void normrelu_kernel(
    const ushort* __restrict__ in, const float* __restrict__ stats,
    const float* __restrict__ g, const float* __restrict__ be, float cntFixed,
    ushort* __restrict__ outp, ushort* __restrict__ xz) {
  __shared__ float ssS[256];
  compute_ss_lds(stats, g, be, cntFixed, ssS);
  __syncthreads();
  const int tid = threadIdx.x;
  const int c4 = (tid & 31) * 4;
  const float4 sc = *(const float4*)&ssS[c4];
  const float4 sh = *(const float4*)&ssS[128 + c4];
  const int rowBase = blockIdx.x * 64;
  const ushort4 z4 = make_ushort4(0, 0, 0, 0);
#pragma unroll
  for (int it = 0; it < 8; ++it) {
    const int row = rowBase + it * 8 + (tid >> 5);
    if (row >= Nn) continue;
    const size_t idx = (size_t)row * 32 + (tid & 31);
    const ushort4 v = ((const ushort4*)in)[idx];
    ushort4 o;
    o.x = bf_hi(fmaxf(fmaf(bf_f(v.x), sc.x, sh.x), 0.f));
    o.y = bf_hi(fmaxf(fmaf(bf_f(v.y), sc.y, sh.y), 0.f));
    o.z = bf_hi(fmaxf(fmaf(bf_f(v.z), sc.z, sh.z), 0.f));
    o.w = bf_hi(fmaxf(fmaf(bf_f(v.w), sc.w, sh.w), 0.f));
    ((ushort4*)outp)[idx] = o;
    ((ushort4*)xz)[idx] = z4;
  }
}

// x += (tmask>0) * relu(y*sc+sh)
__global__ __launch_bounds__(256) void normrelu_acc_kernel(
    const ushort* __restrict__ in, const float* __restrict__ stats,
    const float* __restrict__ g, const float* __restrict__ be,
    const float* __restrict__ cntPtr, const int* __restrict__ tmask,
    ushort* __restrict__ x) {
  __shared__ float ssS[256];
  compute_ss_lds(stats, g, be, fmaxf(cntPtr[0], 1.f), ssS);
  __syncthreads();
  const int tid = threadIdx.x;
  const int c4 = (tid & 31) * 4;
  const float4 sc = *(const float4*)&ssS[c4];
  const float4 sh = *(const float4*)&ssS[128 + c4];
  const int rowBase = blockIdx.x * 64;
#pragma unroll
  for (int it = 0; it < 8; ++it) {
    const int row = rowBase + it * 8 + (tid >> 5);
    if (row >= Nn || tmask[row] <= 0) continue;
    const size_t idx = (size_t)row * 32 + (tid & 31);
    const ushort4 v = ((const ushort4*)in)[idx];
    ushort4 xo = ((const ushort4*)x)[idx];
    xo.x = bf_hi(bf_f(xo.x) + fmaxf(fmaf(bf_f(v.x), sc.x, sh.x), 0.f));
    xo.y = bf_hi(bf_f(xo.y) + fmaxf(fmaf(bf_f(v.y), sc.y, sh.y), 0.f));
    xo.z = bf_hi(bf_f(xo.z) + fmaxf(fmaf(bf_f(v.z), sc.z, sh.z), 0.f));
    xo.w = bf_hi(bf_f(xo.w) + fmaxf(fmaf(bf_f(v.w), sc.w, sh.w), 0.f));
    ((ushort4*)x)[idx] = xo;
  }
}

__global__ __launch_bounds__(256) void scatter_leaves_kernel(
    const int* __restrict__ leaves, const ushort* __restrict__ feat,
    ushort* __restrict__ x, int nl) {
  const int gid = blockIdx.x * 256 + threadIdx.x;
  const int j = gid >> 5;
  if (j >= nl) return;
  const int node = leaves[j];
  const int c4 = (gid & 31) * 4;
  *(ushort4*)&x[(size_t)node * 128 + c4] =
      *(const ushort4*)&feat[(size_t)node * 128 + c4];
}

// ---------------- CSR build ----------------
__global__ __launch_bounds__(256) void deg_count_kernel(
    const int* __restrict__ dst, const int* __restrict__ lmask,
    int* __restrict__ cnts) {
  const int e = blockIdx.x * 256 + threadIdx.x;
  if (e >= Ee) return;
  atomicAdd(&cnts[lmask[e] * Nn + dst[e]], 1);
}

// scan1 + fused per-layer target count (nodes with deg>0) -> tcountf[0..2]
__global__ __launch_bounds__(256) void scan1_kernel(const int* __restrict__ in,
                                                    int* __restrict__ out,
                                                    int* __restrict__ bsum,
                                                    float* __restrict__ tcountf,
                                                    int n) {
  __shared__ int lds[256];
  __shared__ float tcS[3];
  const int tid = threadIdx.x;
  const int base = blockIdx.x * 2048 + tid * 8;
  int vals[8];
  int tsum = 0;
  float t0 = 0.f, t1 = 0.f, t2 = 0.f;
#pragma unroll
  for (int j = 0; j < 8; ++j) {
    const int i = base + j;
    const int v = (i < n) ? in[i] : 0;
    if (v > 0) {
      if (i < Nn) t0 += 1.f;
      else if (i < 2 * Nn) t1 += 1.f;
      else t2 += 1.f;
    }
    vals[j] = tsum;
    tsum += v;
  }
  lds[tid] = tsum;
  if (tid < 3) tcS[tid] = 0.f;
  __syncthreads();
  if (t0 != 0.f) atomicAdd(&tcS[0], t0);
  if (t1 != 0.f) atomicAdd(&tcS[1], t1);
  if (t2 != 0.f) atomicAdd(&tcS[2], t2);
  for (int off = 1; off < 256; off <<= 1) {
    const int y = (tid >= off) ? lds[tid - off] : 0;
    __syncthreads();
    lds[tid] += y;
    __syncthreads();
  }
  const int texcl = (tid > 0) ? lds[tid - 1] : 0;
#pragma unroll
  for (int j = 0; j < 8; ++j)
    if (base + j < n) out[base + j] = texcl + vals[j];
  if (tid == 255) bsum[blockIdx.x] = lds[255];
  __syncthreads();
  if (tid < 3 && tcS[tid] != 0.f) atomicAdd(&tcountf[tid], tcS[tid]);
}

// scan3 with scan2 fused: each block redundantly scans the 147 block sums.
__global__ __launch_bounds__(256) void scan3_kernel(int* __restrict__ out,
                                                    int* __restrict__ cursor,
                                                    const int* __restrict__ bsum,
                                                    int nb, int n, int etot) {
  __shared__ int bs[256];
  const int tid = threadIdx.x;
  const int v = (tid < nb) ? bsum[tid] : 0;
  bs[tid] = v;
  __syncthreads();
  for (int off = 1; off < 256; off <<= 1) {
    const int y = (tid >= off) ? bs[tid - off] : 0;
    __syncthreads();
    bs[tid] += y;
    __syncthreads();
  }
  const int i = blockIdx.x * 256 + tid;
  if (i >= n) return;
  const int b = i >> 11;
  const int excl = (b > 0) ? bs[b - 1] : 0;
  const int val = out[i] + excl;
  out[i] = val;
  cursor[i] = val;
  if (i == n - 1) out[n] = etot;
}

__global__ __launch_bounds__(256) void csr_fill_kernel(
    const int* __restrict__ src, const int* __restrict__ dst,
    const float* __restrict__ mult, const int* __restrict__ lmask,
    int* __restrict__ cursor, int2* __restrict__ pairs) {
  const int e = blockIdx.x * 256 + threadIdx.x;
  if (e >= Ee) return;
  const int slot = atomicAdd(&cursor[lmask[e] * Nn + dst[e]], 1);
  pairs[slot] = make_int2(src[e], __float_as_int(mult[e]));
}

// ---------------- readout: replicated-bucket counting-sort pool -----------
__global__ __launch_bounds__(256) void phist_kernel(const int* __restrict__ ridx,
                                                    const int* __restrict__ batch,
                                                    int* __restrict__ cnt, int n) {
  const int i = blockIdx.x * 256 + threadIdx.x;
  if (i >= n) return;
  atomicAdd(&cnt[batch[ridx[i]] * PR + (i & (PR - 1))], 1);
}

// exclusive scan over 256*PR = 8192 buckets (single block, 32 elems/thread)
__global__ void pscan_kernel(int* __restrict__ cnt, int* __restrict__ cur) {
  __shared__ int l[256];
  const int t = threadIdx.x;
  const int base = t * 32;
  int vals[32];
  int tsum = 0;
#pragma unroll
  for (int j = 0; j < 32; ++j) {
    const int v = cnt[base + j];
    vals[j] = tsum;
    tsum += v;
  }
  l[t] = tsum;
  __syncthreads();
  for (int off = 1; off < 256; off <<= 1) {
    const int y = (t >= off) ? l[t - off] : 0;
    __syncthreads();
    l[t] += y;
    __syncthreads();
  }
  const int excl = (t > 0) ? l[t - 1] : 0;
#pragma unroll
  for (int j = 0; j < 32; ++j) {
    const int v = excl + vals[j];
    cnt[base + j] = v;
    cur[base + j] = v;
  }
}

__global__ __launch_bounds__(256) void pfill_kernel(const int* __restrict__ ridx,
                                                    const int* __restrict__ batch,
                                                    int* __restrict__ cur,
                                                    int* __restrict__ sorted,
                                                    int n) {
  const int i = blockIdx.x * 256 + threadIdx.x;
  if (i >= n) return;
  const int node = ridx[i];
  const int slot = atomicAdd(&cur[batch[node] * PR + (i & (PR - 1))], 1);
  sorted[slot] = node;
}

// Parallel pool: 8 slices per graph -> Ppart[g*8+slice][128] (no atomics)
__global__ __launch_bounds__(256) void ppool_kernel(const int* __restrict__ sorted,
                                                    const int* __restrict__ offs,
                                                    const ushort* __restrict__ x,
                                                    float* __restrict__ Ppart,
                                                    int n) {
  __shared__ float part[4][256];
  const int bid = blockIdx.x;
  const int g = bid >> 3, slice = bid & (PSL - 1);
  const int w = threadIdx.x >> 6;
  const int lane = threadIdx.x & 63;
  const int o0 = offs[g * PR];
  const int o1 = (g < Gg - 1) ? offs[(g + 1) * PR] : n;
  float ax = 0.f, ay = 0.f;
  for (int p = o0 + slice * 4 + w; p < o1; p += 32) {
    const int node = sorted[p];
    const ushort2 xv = *(const ushort2*)&x[(size_t)node * 128 + lane * 2];
    ax += bf_f(xv.x);
    ay += bf_f(xv.y);
  }
  part[w][lane * 2] = ax;
  part[w][lane * 2 + 1] = ay;
  __syncthreads();
  if (threadIdx.x < 128) {
    const int c = threadIdx.x;
    Ppart[(size_t)bid * 128 + c] =
        part[0][c] + part[1][c] + part[2][c] + part[3][c];
  }
}

// Fused preduce + final linear: out[g][t] = 0.25*sum_slices(Ppart)@Wl + bl
__global__ __launch_bounds__(128) void pout_kernel(
    const float* __restrict__ Ppart, const float* __restrict__ Wl,
    const float* __restrict__ bl, float* __restrict__ out) {
  __shared__ float Pl[128];
  const int g = blockIdx.x;
  const int t = threadIdx.x;  // 128
  float s = 0.f;
#pragma unroll
  for (int r = 0; r < PSL; ++r) s += Ppart[(size_t)(g * PSL + r) * 128 + t];
  Pl[t] = s * 0.25f;
  __syncthreads();
  if (t < Tt) {
    float acc = 0.f;
    for (int c = 0; c < 128; ++c) acc += Pl[c] * Wl[c * Tt + t];
    out[g * Tt + t] = acc + bl[t];
  }
}

extern "C" void kernel_launch(void* const* d_in, const int* in_sizes, int n_in,
                              void* d_out, int out_size, void* d_ws,
                              size_t ws_size, hipStream_t stream) {
  const float* dag_x = (const float*)d_in[0];
  const int* eidx = (const int*)d_in[1];
  const int* src = eidx;
  const int* dst = eidx + Ee;
  const float* mult = (const float*)d_in[2];
  const int* lmask = (const int*)d_in[3];
  const int* batch = (const int*)d_in[4];
  const int* leaves = (const int*)d_in[5];
  const int* readouts = (const int*)d_in[6];
  const float* W1 = (const float*)d_in[7];
  const float* b1 = (const float*)d_in[8];
  const float* g1 = (const float*)d_in[9];
  const float* be1 = (const float*)d_in[10];
  const float* W2 = (const float*)d_in[11];
  const float* b2 = (const float*)d_in[12];
  const float* g2 = (const float*)d_in[13];
  const float* be2 = (const float*)d_in[14];
  const float* dW1 = (const float*)d_in[15];
  const float* db1 = (const float*)d_in[16];
  const float* dg1 = (const float*)d_in[17];
  const float* dbe1 = (const float*)d_in[18];
  const float* dW2 = (const float*)d_in[19];
  const float* db2 = (const float*)d_in[20];
  const float* dg2 = (const float*)d_in[21];
  const float* dbe2 = (const float*)d_in[22];
  const float* deps = (const float*)d_in[23];
  const float* Wl = (const float*)d_in[24];
  const float* bl = (const float*)d_in[25];
  float* out = (float*)d_out;

  const size_t ND = (size_t)Nn * Dd;
  ushort* feat = (ushort*)d_ws;           // ND bf16
  ushort* xbuf = feat + ND;               // ND bf16
  ushort* Abuf = xbuf + ND;               // ND bf16
  ushort* Bbuf = Abuf + ND;               // ND bf16 (gemm ping-pong)
  float* statsAll = (float*)(Bbuf + ND);  // 8 slots x [16][512]
  float* tcountf = statsAll + 8 * 8192;   // 8 (4 used) -- adjacent for memset
  int* tmask = (int*)(tcountf + 8);       // N
  ushort* wsT = (ushort*)(tmask + Nn);    // 262144 (8 weight slots, hi+lo)
  int* offs = (int*)(wsT + 262144);       // 3N+4
  int2* pairs = (int2*)(offs + 3 * Nn + 4);  // E pairs (src, mult)

  // transient overlays (xbuf region before it's initialized):
  int* cnts = (int*)xbuf;                 // 3N
  int* cursor = cnts + 3 * Nn;            // 3N
  int* bsum = cursor + 3 * Nn;            // 147
  const int nridx = in_sizes[6];          // 80000
  const int nleaves = in_sizes[5];        // 50000
  // pool overlays (Abuf dead by readout):
  int* pcnt = (int*)Abuf;                 // 256*PR (becomes offsets)
  int* pcur = pcnt + Gg * PR;             // 256*PR
  int* sorted = pcur + Gg * PR;           // nridx
  float* Ppart = (float*)(sorted + nridx);  // 2048*128

  dim3 blk(256);
  hipMemsetAsync(statsAll, 0, (8 * 8192 + 8) * sizeof(float), stream);
  wsplit_kernel<<<512, blk, 0, stream>>>(W1, W2, dW1, dW2, wsT);

  // ---- CSR build (tcount fused into scan1; scan2 fused into scan3) ----
  hipMemsetAsync(cnts, 0, 3 * Nn * sizeof(int), stream);
  deg_count_kernel<<<2344, blk, 0, stream>>>(dst, lmask, cnts);
  scan1_kernel<<<147, blk, 0, stream>>>(cnts, offs, bsum, tcountf, 3 * Nn);
  scan3_kernel<<<1172, blk, 0, stream>>>(offs, cursor, bsum, 147, 3 * Nn, Ee);
  csr_fill_kernel<<<2344, blk, 0, stream>>>(src, dst, mult, lmask, cursor, pairs);

  const int gGemm = 782 * 2;
  // ---- node feature transform ----
  gemm_f32a<<<gGemm, blk, 0, stream>>>(dag_x, wsT, wsT + 16384, b1, Abuf,
                                       statsAll + 0 * 8192, Nn);
  gemm_bf16<true, false><<<gGemm, blk, 0, stream>>>(
      Abuf, wsT + 32768, wsT + 32768 + 16384, b2, statsAll + 0 * 8192, g1, be1,
      nullptr, nullptr, Bbuf, statsAll + 1 * 8192, Nn);
  // feat = relu(bn(y2)); also zeroes xbuf (no memset dispatch)
  normrelu_kernel<<<1563, blk, 0, stream>>>(Bbuf, statsAll + 1 * 8192, g2, be2,
                                            (float)Nn, feat, xbuf);
  scatter_leaves_kernel<<<6250, blk, 0, stream>>>(leaves, feat, xbuf, nleaves);

  // ---- DAG layers (agg fused into gemm1) ----
  for (int layer = 0; layer < Ll; ++layer) {
    const int so1 = (2 + layer) * 32768;
    const int so2 = (5 + layer) * 32768;
    const int po = layer * Dd;
    float* st1 = statsAll + (size_t)(2 + 2 * layer) * 8192;
    float* st2 = statsAll + (size_t)(3 + 2 * layer) * 8192;
    gemm_agg<<<gGemm, blk, 0, stream>>>(xbuf, feat, offs, pairs, deps, layer,
                                        wsT + so1, wsT + so1 + 16384, db1 + po,
                                        Bbuf, st1, tmask, Nn);
    gemm_bf16<true, true><<<gGemm, blk, 0, stream>>>(
        Bbuf, wsT + so2, wsT + so2 + 16384, db2 + po, st1, dg1 + po, dbe1 + po,
        tcountf + layer, tmask, Abuf, st2, Nn);
    normrelu_acc_kernel<<<1563, blk, 0, stream>>>(
        Abuf, st2, dg2 + po, dbe2 + po, tcountf + layer, tmask, xbuf);
  }

  // ---- readout (replicated-bucket counting sort, no float atomics) ----
  hipMemsetAsync(pcnt, 0, Gg * PR * sizeof(int), stream);
  const int gIdx = (nridx + 255) / 256;
  phist_kernel<<<gIdx, blk, 0, stream>>>(readouts, batch, pcnt, nridx);
  pscan_kernel<<<1, blk, 0, stream>>>(pcnt, pcur);
  pfill_kernel<<<gIdx, blk, 0, stream>>>(readouts, batch, pcur, sorted, nridx);
  ppool_kernel<<<Gg * PSL, blk, 0, stream>>>(sorted, pcnt, xbuf, Ppart, nridx);
  pout_kernel<<<Gg, dim3(128), 0, stream>>>(Ppart, Wl, bl, out);
}